// Round 2
// baseline (228.080 us; speedup 1.0000x reference)
//
#include <hip/hip_runtime.h>
#include <math.h>

typedef unsigned int u32;
typedef unsigned long long u64;
typedef unsigned char u8;

#define K_TOT 8382
#define NCH 131      // 131 chunks of 64 rows
#define CAP 1024     // per-source-chunk off-diag entry capacity (global)
#define EC 64        // per-source-chunk entries staged to LDS (1 per lane)
#define DC 8         // per-chunk intra-chunk (diag) suppressor list capacity
#define GCAP 32768   // per-level threshold-bin candidate capacity
#define IMGSZ 800.0f

__device__ __constant__ int LOFF[5] = {0, 120000, 150000, 157500, 159375};
__device__ __constant__ int LCNT[5] = {120000, 30000, 7500, 1875, 507};
__device__ __constant__ int KSEL[5] = {2000, 2000, 2000, 1875, 507};
__device__ __constant__ int SELB[5] = {0, 2000, 4000, 6000, 7875};
__device__ __constant__ int HBS[4] = {0, 118, 148, 156};    // k_hist block starts (levels 0..2)
__device__ __constant__ int GBS[6] = {0, 118, 148, 156, 158, 159};  // k_gather block starts

static __device__ __forceinline__ u32 fkey(float x) {
    u32 u = __float_as_uint(x);
    u32 m = (u32)(((int)u) >> 31) | 0x80000000u;
    return u ^ m;
}

static __device__ __forceinline__ int lvl_of(int s) {
    return (s < 2000) ? 0 : (s < 4000) ? 1 : (s < 6000) ? 2 : (s < 7875) ? 3 : 4;
}

// scalar-path readlanes (uniform lane index -> v_readlane)
static __device__ __forceinline__ u32 rdl32(u32 v, int j) {
    return (u32)__builtin_amdgcn_readlane((int)v, j);
}
static __device__ __forceinline__ u64 rdlane64(u64 v, int j) {
    u32 lo = (u32)__builtin_amdgcn_readlane((int)(u32)v, j);
    u32 hi = (u32)__builtin_amdgcn_readlane((int)(u32)(v >> 32), j);
    return ((u64)hi << 32) | (u64)lo;
}

// Parallel reverse-inclusive scan over hist[0..m-1] (from top bin down);
// finds bin with suffix-cum >= need. Out: sv[0]=bin, sv[1]=remaining ties to take.
static __device__ __forceinline__ void thresh_scan(const u32* hist, u32* scanbuf, int m,
                                                   u32 need, u32* sv, int t) {
    for (int i = t; i < m; i += 1024) scanbuf[i] = hist[m - 1 - i];
    __syncthreads();
    for (int ofs = 1; ofs < m; ofs <<= 1) {
        int i0 = t, i1 = t + 1024;
        u32 a0 = 0, a1 = 0;
        if (i0 < m && i0 >= ofs) a0 = scanbuf[i0 - ofs];
        if (i1 < m && i1 >= ofs) a1 = scanbuf[i1 - ofs];
        __syncthreads();
        if (i0 < m && i0 >= ofs) scanbuf[i0] += a0;
        if (i1 < m && i1 >= ofs) scanbuf[i1] += a1;
        __syncthreads();
    }
    for (int i = t; i < m; i += 1024) {
        u32 inc = scanbuf[i];
        u32 exc = i ? scanbuf[i - 1] : 0;
        if (inc >= need && exc < need) { sv[0] = (u32)(m - 1 - i); sv[1] = need - exc; }
    }
    __syncthreads();
}

// ---------------- K1a: parallel coarse histogram (top 11 key bits), levels 0..2 ----------------
__global__ __launch_bounds__(1024) void k_hist(const float* __restrict__ scores,
                                               u32* __restrict__ hist3) {
    __shared__ u32 lh[2048];
    int t = threadIdx.x;
    lh[t] = 0; lh[t + 1024] = 0;
    __syncthreads();
    int b = blockIdx.x;
    int l = (b < HBS[1]) ? 0 : (b < HBS[2]) ? 1 : 2;
    int i = (b - HBS[l]) * 1024 + t;
    if (i < LCNT[l]) atomicAdd(&lh[fkey(scores[LOFF[l] + i]) >> 21], 1u);
    __syncthreads();
    u32* h = hist3 + l * 2048;
    if (lh[t]) atomicAdd(&h[t], lh[t]);
    if (lh[t + 1024]) atomicAdd(&h[t + 1024], lh[t + 1024]);
}

// ---------------- K1b: coarse threshold per level ----------------
__global__ __launch_bounds__(1024) void k_thresh(const u32* __restrict__ hist3,
                                                 u32* __restrict__ tinfo) {
    __shared__ u32 scanbuf[2048];
    __shared__ u32 sv[2];
    int l = blockIdx.x;
    int t = threadIdx.x;
    thresh_scan(hist3 + l * 2048, scanbuf, 2048, (u32)KSEL[l], sv, t);
    if (t == 0) { tinfo[l * 2] = sv[0]; tinfo[l * 2 + 1] = sv[1]; }
}

// ---------------- K1c: classify; strict-greater -> sel, threshold-bin -> candidate buf ----------------
__global__ __launch_bounds__(1024) void k_gather(const float* __restrict__ scores,
                                                 const u32* __restrict__ tinfo,
                                                 u32* __restrict__ sel, u32* __restrict__ cgt,
                                                 u32* __restrict__ gcnt, u32* __restrict__ gidx,
                                                 u32* __restrict__ gkey) {
    int b = blockIdx.x;
    int l = (b < GBS[1]) ? 0 : (b < GBS[2]) ? 1 : (b < GBS[3]) ? 2 : (b < GBS[4]) ? 3 : 4;
    int i = (b - GBS[l]) * 1024 + threadIdx.x;
    if (i >= LCNT[l]) return;
    int off = LOFF[l], sb = SELB[l];
    if (l >= 3) { sel[sb + i] = (u32)(off + i); return; }  // take-all levels
    u32 ky = fkey(scores[off + i]);
    u32 b1 = tinfo[l * 2];
    u32 top = ky >> 21;
    if (top > b1) {
        u32 p = atomicAdd(&cgt[l], 1u);
        sel[sb + p] = (u32)(off + i);          // set membership only; order fixed by P later
    } else if (top == b1) {
        u32 e = atomicAdd(&gcnt[l], 1u);
        if (e < GCAP) { gidx[l * GCAP + e] = (u32)i; gkey[l * GCAP + e] = ky; }
    }
}

// ---------------- K1d: exact refine within threshold bin (mid 11 + low 10 bits) ----------------
__global__ __launch_bounds__(1024) void k_final(const u32* __restrict__ gidx,
                                                const u32* __restrict__ gkey,
                                                const u32* __restrict__ gcnt,
                                                const u32* __restrict__ tinfo,
                                                u32* __restrict__ sel) {
    __shared__ u32 hist[2048];
    __shared__ u32 scanbuf[2048];
    __shared__ u32 eqbuf[1024];
    __shared__ u32 sv[2];
    __shared__ u32 c2, ceq;
    int l = blockIdx.x;
    int t = threadIdx.x;
    int k = KSEL[l], sb = SELB[l], off = LOFF[l];
    u32 m = gcnt[l]; if (m > GCAP) m = GCAP;
    u32 b1 = tinfo[l * 2];
    u32 need = tinfo[l * 2 + 1];
    const u32* kb = gkey + l * GCAP;
    const u32* ib = gidx + l * GCAP;
    // mid 11 bits
    hist[t] = 0; hist[t + 1024] = 0; __syncthreads();
    for (u32 e = t; e < m; e += 1024) atomicAdd(&hist[(kb[e] >> 10) & 2047u], 1u);
    __syncthreads();
    thresh_scan(hist, scanbuf, 2048, need, sv, t);
    u32 b2 = sv[0], need2 = sv[1];
    __syncthreads();
    // low 10 bits
    hist[t] = 0; __syncthreads();
    for (u32 e = t; e < m; e += 1024) {
        u32 ky = kb[e];
        if (((ky >> 10) & 2047u) == b2) atomicAdd(&hist[ky & 1023u], 1u);
    }
    __syncthreads();
    thresh_scan(hist, scanbuf, 1024, need2, sv, t);
    u32 T = (b1 << 21) | (b2 << 10) | sv[0];
    u32 take = sv[1];
    if (t == 0) { c2 = 0; ceq = 0; }
    __syncthreads();
    u32 nGTbin = need - take;
    u32 base2 = (u32)sb + (u32)k - need;   // after strict-greater-bin entries
    for (u32 e = t; e < m; e += 1024) {
        u32 ky = kb[e];
        if (ky > T) { u32 p = atomicAdd(&c2, 1u); sel[base2 + p] = (u32)off + ib[e]; }
        else if (ky == T) { u32 q = atomicAdd(&ceq, 1u); if (q < 1024) eqbuf[q] = ib[e]; }
    }
    __syncthreads();
    if (t == 0) {
        int n = (ceq > 1024u) ? 1024 : (int)ceq;
        for (int a = 1; a < n; ++a) {  // ascending insertion sort; tie count tiny
            u32 v = eqbuf[a]; int bq = a - 1;
            while (bq >= 0 && eqbuf[bq] > v) { eqbuf[bq + 1] = eqbuf[bq]; --bq; }
            eqbuf[bq + 1] = v;
        }
        for (u32 q = 0; q < take; ++q) sel[base2 + nGTbin + q] = (u32)off + eqbuf[q];
    }
}

// ---------------- K2: decode selected boxes (exact reference op order) ----------------
__global__ void k_decode(const float* __restrict__ scores, const float4* __restrict__ deltas,
                         const float4* __restrict__ anchors, const u32* __restrict__ sel,
                         float4* __restrict__ candB, float* __restrict__ candS,
                         u32* __restrict__ candV, u32* __restrict__ candA) {
    int s = blockIdx.x * 256 + threadIdx.x;
    if (s >= K_TOT) return;
    u32 a = sel[s];
    float4 an = anchors[a];
    float4 dl = deltas[a];
    float sc = scores[a];
    float w = __fsub_rn(an.z, an.x), h = __fsub_rn(an.w, an.y);
    float cx = __fadd_rn(an.x, __fmul_rn(0.5f, w));
    float cy = __fadd_rn(an.y, __fmul_rn(0.5f, h));
    const float CLIPV = (float)4.1351665567423563;  // log(1000/16) as f32
    float dw = fminf(dl.z, CLIPV);
    float dh = fminf(dl.w, CLIPV);
    float px = __fadd_rn(cx, __fmul_rn(dl.x, w));
    float py = __fadd_rn(cy, __fmul_rn(dl.y, h));
    float pw = __fmul_rn((float)exp((double)dw), w);
    float ph = __fmul_rn((float)exp((double)dh), h);
    float x1 = __fsub_rn(px, __fmul_rn(0.5f, pw));
    float y1 = __fsub_rn(py, __fmul_rn(0.5f, ph));
    float x2 = __fadd_rn(px, __fmul_rn(0.5f, pw));
    float y2 = __fadd_rn(py, __fmul_rn(0.5f, ph));
    x1 = fminf(fmaxf(x1, 0.0f), IMGSZ);
    y1 = fminf(fmaxf(y1, 0.0f), IMGSZ);
    x2 = fminf(fmaxf(x2, 0.0f), IMGSZ);
    y2 = fminf(fmaxf(y2, 0.0f), IMGSZ);
    bool valid = (__fsub_rn(x2, x1) >= 0.001f) && (__fsub_rn(y2, y1) >= 0.001f);
    candB[s] = make_float4(x1, y1, x2, y2);
    candS[s] = sc;
    candV[s] = valid ? 1u : 0u;
    candA[s] = a;
}

// ---------------- K3a: within-level rank (tiled pairwise count) ----------------
__global__ __launch_bounds__(256) void k_rank_lvl(const float* __restrict__ candS,
                                                  const u32* __restrict__ candA,
                                                  u32* __restrict__ Praw) {
    __shared__ u64 tile[256];
    int l = blockIdx.z;
    int cnt = KSEL[l], base = SELB[l];
    int tx = blockIdx.x * 256;
    int ty = blockIdx.y * 256;
    if (tx >= cnt || ty >= cnt) return;
    int t = threadIdx.x;
    u64 Aj = ~0ull;  // sentinel: never < any real key
    if (tx + t < cnt) {
        int j = base + tx + t;
        Aj = ((u64)(~fkey(candS[j])) << 32) | (u64)candA[j];
    }
    tile[t] = Aj;
    __syncthreads();
    int si = ty + t;
    if (si >= cnt) return;
    int s = base + si;
    u64 A = ((u64)(~fkey(candS[s])) << 32) | (u64)candA[s];
    int r = 0;
#pragma unroll 8
    for (int q = 0; q < 256; ++q) r += (tile[q] < A);
    if (r) atomicAdd(&Praw[s], (u32)r);
}

// ---------------- K3b: global rank by (masked score desc, position asc) ----------------
__global__ __launch_bounds__(256) void k_rank_glob(const float* __restrict__ candS,
                                                   const u32* __restrict__ candV,
                                                   const u32* __restrict__ Praw,
                                                   u32* __restrict__ rank) {
    __shared__ u64 colB[256];
    int t = threadIdx.x;
    int cj = blockIdx.x * 256 + t;
    u64 B = ~0ull;
    if (cj < K_TOT) {
        u32 smk = candV[cj] ? fkey(candS[cj]) : 0x007FFFFFu;  // fkey(-inf)
        u32 Pj = (u32)SELB[lvl_of(cj)] + Praw[cj];
        B = ((u64)(~smk) << 32) | (u64)Pj;
    }
    colB[t] = B;
    __syncthreads();
    int s = blockIdx.y * 256 + t;
    if (s >= K_TOT) return;
    u32 smk = candV[s] ? fkey(candS[s]) : 0x007FFFFFu;
    u32 Ps = (u32)SELB[lvl_of(s)] + Praw[s];
    u64 myB = ((u64)(~smk) << 32) | (u64)Ps;
    int cnt = 0;
#pragma unroll 8
    for (int j = 0; j < 256; ++j) cnt += (colB[j] < myB);
    if (cnt) atomicAdd(&rank[s], (u32)cnt);
}

// ---------------- K4: scatter into sorted order (+ valid-bit words via atomicOr) ----------------
// Reference's fmask slice is all zeros -> NMS on raw clipped boxes (no level offsets).
__global__ void k_scatter(const float4* __restrict__ candB, const float* __restrict__ candS,
                          const u32* __restrict__ candV, const u32* __restrict__ rank,
                          float4* __restrict__ sB, float* __restrict__ sArea,
                          float* __restrict__ sS, u64* __restrict__ vwords) {
    int s = blockIdx.x * 256 + threadIdx.x;
    if (s >= K_TOT) return;
    u32 r = rank[s];
    float4 b = candB[s];
    float area = __fmul_rn(__fsub_rn(b.z, b.x), __fsub_rn(b.w, b.y));
    sB[r] = b; sArea[r] = area; sS[r] = candS[s];
    if (candV[s]) atomicOr(&vwords[r >> 6], 1ull << (r & 63));
}

// ---------------- K5: suppression bits -> packed entry lists ----------------
// off-diag: bucketed by SOURCE chunk, 16B entries {row|target<<6, bits}.
// diag (intra-chunk): 16B list entries {lane, bits} + dmask; full diag[] kept as fallback.
__global__ __launch_bounds__(256) void k_mask(const float4* __restrict__ sB,
                                              const float* __restrict__ sArea,
                                              u64* __restrict__ diag, u32* __restrict__ ecnt,
                                              ulonglong2* __restrict__ epack,
                                              u32* __restrict__ dcnt, u64* __restrict__ dmask,
                                              ulonglong2* __restrict__ dpack) {
    __shared__ float4 cb[64];
    __shared__ float ca[64];
    int wd = blockIdx.x;   // target word (column chunk)
    int t = threadIdx.x;
    if (t < 64) {
        int j = wd * 64 + t;
        if (j < K_TOT) { cb[t] = sB[j]; ca[t] = sArea[j]; }
        else { cb[t] = make_float4(0.f, 0.f, 0.f, 0.f); ca[t] = 0.f; }
    }
    __syncthreads();
    int i = blockIdx.y * 256 + t;
    if (i >= K_TOT) return;
    int dwr = i >> 6;
    if (wd < dwr) return;  // strictly upper-triangular
    float4 bi = sB[i];
    float ai = sArea[i];
    u64 bits = 0;
    int jbase = wd * 64;
    for (int j2 = 0; j2 < 64; ++j2) {
        int j = jbase + j2;
        if (j > i && j < K_TOT) {
            float4 bj = cb[j2];
            float ltx = fmaxf(bi.x, bj.x), lty = fmaxf(bi.y, bj.y);
            float rbx = fminf(bi.z, bj.z), rby = fminf(bi.w, bj.w);
            float wx = fmaxf(__fsub_rn(rbx, ltx), 0.0f);
            float wy = fmaxf(__fsub_rn(rby, lty), 0.0f);
            float inter = __fmul_rn(wx, wy);
            if (inter > 0.0f) {
                float uni = __fsub_rn(__fadd_rn(ai, ca[j2]), inter);
                float iou = inter / uni;  // IEEE f32 div, matches reference
                if (iou > 0.7f) bits |= (1ull << j2);
            }
        }
    }
    if (wd == dwr) {
        diag[i] = bits;  // always stored (overflow fallback)
        if (bits != 0ull) {
            u32 p = atomicAdd(&dcnt[dwr], 1u);
            if (p < DC) dpack[dwr * DC + p] = make_ulonglong2((u64)(i & 63), bits);
            atomicOr(&dmask[dwr], 1ull << (i & 63));
        }
    } else if (bits != 0ull) {
        u32 p = atomicAdd(&ecnt[dwr], 1u);
        if (p < CAP) epack[dwr * CAP + p] = make_ulonglong2((u64)((i & 63) | (wd << 6)), bits);
    }
}

// ---------------- K6: sequential NMS scan — latency-optimized serial loop ----------------
// Critical-path restructure: sR[c+1] is PRE-read at the top of iteration c (before this
// iteration's atomics); chunk c's own contribution to c+1 is patched in-register via one
// ballot + readlane loop. Static per-chunk data (epack/dpack fragments) is prefetched one
// iteration ahead; per-chunk scalars are readlane-broadcast from staging registers (no LDS).
__global__ __launch_bounds__(64) void k_scan(const u64* __restrict__ diag,
                                             const u64* __restrict__ vwords,
                                             const u32* __restrict__ ecnt,
                                             const ulonglong2* __restrict__ epack,
                                             const u32* __restrict__ dcnt,
                                             const u64* __restrict__ dmask,
                                             const ulonglong2* __restrict__ dpack,
                                             u64* __restrict__ keepw) {
    __shared__ ulonglong2 sEpack[NCH * EC];   // 134 KB
    __shared__ ulonglong2 sDpack[NCH * DC];   // 16.8 KB
    volatile __shared__ u64 sR[NCH];          // accumulated incoming suppression per chunk
    __shared__ u64 sKeep[NCH];
    int lane = threadIdx.x;
    // small arrays: batched loads; values KEPT IN REGISTERS for readlane broadcast later
    u64 v0, v1, v2, m0, m1, m2;
    u32 c0, c1, c2, d0, d1, d2;
    {
        int i0 = lane, i1 = lane + 64, i2 = lane + 128;
        bool p2 = (i2 < NCH);
        v0 = vwords[i0]; v1 = vwords[i1]; v2 = p2 ? vwords[i2] : 0;
        c0 = ecnt[i0]; c1 = ecnt[i1]; c2 = p2 ? ecnt[i2] : 0;
        d0 = dcnt[i0]; d1 = dcnt[i1]; d2 = p2 ? dcnt[i2] : 0;
        m0 = dmask[i0]; m1 = dmask[i1]; m2 = p2 ? dmask[i2] : 0;
        if (c0 > CAP) c0 = CAP;
        if (c1 > CAP) c1 = CAP;
        if (c2 > CAP) c2 = CAP;
        sR[i0] = 0; sR[i1] = 0;
        if (p2) sR[i2] = 0;
    }
    // epack staging: 131 chunk-rounds, 16 independent loads in flight per batch
    for (int base = 0; base < NCH; base += 16) {
        ulonglong2 tmp[16];
        int nb = NCH - base; if (nb > 16) nb = 16;
#pragma unroll
        for (int b = 0; b < 16; ++b)
            if (b < nb) tmp[b] = epack[(size_t)(base + b) * CAP + lane];
#pragma unroll
        for (int b = 0; b < 16; ++b)
            if (b < nb) sEpack[(base + b) * EC + lane] = tmp[b];
    }
    // dpack staging: NCH*DC = 1048 entries (global layout contiguous), batch 8
    for (int base = 0; base < NCH * DC; base += 64 * 8) {
        ulonglong2 tmp[8];
#pragma unroll
        for (int b = 0; b < 8; ++b) {
            int i = base + b * 64 + lane;
            if (i < NCH * DC) tmp[b] = dpack[i];
        }
#pragma unroll
        for (int b = 0; b < 8; ++b) {
            int i = base + b * 64 + lane;
            if (i < NCH * DC) sDpack[i] = tmp[b];
        }
    }
    __syncthreads();
    // serial scan
    u64 r_cur = 0;  // sR[0] is never targeted (entries strictly forward)
    ulonglong2 E = sEpack[lane];
    ulonglong2 DP = (lane < DC) ? sDpack[lane] : make_ulonglong2(~0ull, 0ull);
    u32 cnt = rdl32(c0, 0), dn = rdl32(d0, 0);
    u64 vw = rdlane64(v0, 0), dmw = rdlane64(m0, 0);
    for (int c = 0; c < NCH; ++c) {
        int cn = (c + 1 < NCH) ? (c + 1) : c;
        // pre-read next chunk's accumulated suppression (in-order DS: sees all atomics
        // from iterations < c; this iteration's own contribution patched via `contrib`)
        u64 rpre = sR[cn];
        // prefetch next chunk's static LDS data (off critical path)
        ulonglong2 En = sEpack[cn * EC + lane];
        ulonglong2 DPn = (lane < DC) ? sDpack[cn * DC + lane] : make_ulonglong2(~0ull, 0ull);
        // readlane-broadcast next chunk's scalars (register ops, no LDS latency)
        u32 cntn, dnn; u64 vwn, dmn;
        if (cn < 64)       { cntn = rdl32(c0, cn);       dnn = rdl32(d0, cn);       vwn = rdlane64(v0, cn);       dmn = rdlane64(m0, cn); }
        else if (cn < 128) { cntn = rdl32(c1, cn - 64);  dnn = rdl32(d1, cn - 64);  vwn = rdlane64(v1, cn - 64);  dmn = rdlane64(m1, cn - 64); }
        else               { cntn = rdl32(c2, cn - 128); dnn = rdl32(d2, cn - 128); vwn = rdlane64(v2, cn - 128); dmn = rdlane64(m2, cn - 128); }

        u64 alive = vw & ~r_cur;
        if (dn) {
            if (dn <= (u32)DC) {
                u64 dm = dmw & alive;          // rows dead on entry can never suppress
                u32 ml = ((u32)lane < dn) ? (u32)DP.x : 0xFFu;
                while (dm) {
                    int j = __builtin_ctzll(dm);
                    dm &= dm - 1;
                    if ((alive >> j) & 1ull) { // uniform branch
                        u64 selm = __ballot(ml == (u32)j);
                        int src = __builtin_ctzll(selm);
                        alive &= ~rdlane64(DP.y, src);
                    }
                }
            } else {                            // overflow: read full diag words (rare)
                int r = c * 64 + lane;
                u64 D = (r < K_TOT) ? diag[r] : 0ull;
                u64 nzd = __ballot(D != 0ull);
                nzd &= alive;
                while (nzd) {
                    int j = __builtin_ctzll(nzd);
                    nzd &= nzd - 1;
                    if ((alive >> j) & 1ull) alive &= ~rdlane64(D, j);
                }
            }
        }
        if (lane == 0) sKeep[c] = alive;
        // scatter: entries sourced in this chunk from alive rows -> future chunks' sR
        u32 tc = (u32)E.x >> 6;
        bool act = ((u32)lane < cnt) && (((alive >> ((u32)E.x & 63u)) & 1ull) != 0ull);
        if (act) atomicOr((u64*)&sR[tc], E.y);
        bool redo = false;
        if (cnt > (u32)EC) {                    // rare tail beyond LDS-staged entries
            for (u32 e = (u32)EC + (u32)lane; e < cnt; e += 64u) {
                ulonglong2 Et = epack[(size_t)c * CAP + e];
                u32 pk = (u32)Et.x;
                if ((alive >> (pk & 63u)) & 1ull) atomicOr((u64*)&sR[pk >> 6], Et.y);
            }
            redo = true;
        }
        // in-register contribution of this chunk to the NEXT chunk (patches rpre)
        u64 selm = __ballot(act && (tc == (u32)cn));
        u64 contrib = 0;
        while (selm) {
            int j = __builtin_ctzll(selm);
            selm &= selm - 1;
            contrib |= rdlane64(E.y, j);
        }
        if (redo) rpre = sR[cn];  // re-read after tail atomics (in-order DS, sees them)
        r_cur = rpre | contrib;
        E = En; DP = DPn; cnt = cntn; dn = dnn; vw = vwn; dmw = dmn;
    }
    __syncthreads();
    for (int i = lane; i < NCH; i += 64) keepw[i] = sKeep[i];
}

// ---------------- K7: emit top-1000 (kept in order, then -inf padding) ----------------
__global__ __launch_bounds__(1024) void k_out(const u64* __restrict__ keepw,
                                              const float4* __restrict__ sB,
                                              const float* __restrict__ sS,
                                              float* __restrict__ out) {
    __shared__ u64 skw[NCH];
    __shared__ u32 pc[NCH + 1];   // pc[0]=0; after scan pc[w] = popc of words 0..w-1
    int t = threadIdx.x;
    if (t < NCH) {
        u64 kw = keepw[t];
        skw[t] = kw;
        pc[t + 1] = (u32)__popcll(kw);
    }
    if (t == 0) pc[0] = 0;
    __syncthreads();
    // Hillis-Steele inclusive scan over pc[1..NCH]
    for (int ofs = 1; ofs < NCH; ofs <<= 1) {
        int i = t + 1;
        u32 v = 0;
        bool p = (t < NCH) && (i - ofs >= 1);
        if (p) v = pc[i - ofs];
        __syncthreads();
        if (p) pc[i] += v;
        __syncthreads();
    }
    u32 nk = pc[NCH];
    for (int i = t; i < K_TOT; i += 1024) {
        int w = i >> 6, b = i & 63;
        u64 kw = skw[w];
        u32 kb = pc[w] + (u32)__popcll(kw & ((1ull << b) - 1ull));
        bool kp = (kw >> b) & 1ull;
        if (kp) {
            if (kb < 1000u) {
                float4 bx = sB[i];
                out[kb * 4 + 0] = bx.x; out[kb * 4 + 1] = bx.y;
                out[kb * 4 + 2] = bx.z; out[kb * 4 + 3] = bx.w;
                out[4000 + kb] = sS[i];
            }
        } else {
            u32 q = (u32)i - kb;
            u32 slot = nk + q;
            if (slot < 1000u) {
                float4 bx = sB[i];
                out[slot * 4 + 0] = bx.x; out[slot * 4 + 1] = bx.y;
                out[slot * 4 + 2] = bx.z; out[slot * 4 + 3] = bx.w;
                out[4000 + slot] = -INFINITY;
            }
        }
    }
}

// ---------------- workspace layout ----------------
static constexpr size_t al256(size_t x) { return (x + 255) & ~(size_t)255; }
static constexpr size_t KB4 = (size_t)K_TOT * 4;
static constexpr size_t KB16 = (size_t)K_TOT * 16;
// zeroed region:
static constexpr size_t O_RANK = 0;
static constexpr size_t O_PRAW = al256(O_RANK + KB4);
static constexpr size_t O_ECNT = al256(O_PRAW + KB4);
static constexpr size_t O_DCNT = al256(O_ECNT + (size_t)NCH * 4);
static constexpr size_t O_DMASK = al256(O_DCNT + (size_t)NCH * 4);
static constexpr size_t O_VW = al256(O_DMASK + (size_t)NCH * 8);
static constexpr size_t O_HIST = al256(O_VW + (size_t)NCH * 8);
static constexpr size_t O_CGT = al256(O_HIST + (size_t)3 * 2048 * 4);
static constexpr size_t O_GCNT = al256(O_CGT + 3 * 4);
static constexpr size_t MEMSET_BYTES = al256(O_GCNT + 3 * 4);
// non-zeroed region:
static constexpr size_t O_TINFO = MEMSET_BYTES;
static constexpr size_t O_SEL = al256(O_TINFO + 6 * 4);
static constexpr size_t O_GIDX = al256(O_SEL + KB4);
static constexpr size_t O_GKEY = al256(O_GIDX + (size_t)3 * GCAP * 4);
static constexpr size_t O_CANDB = al256(O_GKEY + (size_t)3 * GCAP * 4);
static constexpr size_t O_CANDS = al256(O_CANDB + KB16);
static constexpr size_t O_CANDV = al256(O_CANDS + KB4);
static constexpr size_t O_CANDA = al256(O_CANDV + KB4);
static constexpr size_t O_SB = al256(O_CANDA + KB4);
static constexpr size_t O_SAREA = al256(O_SB + KB16);
static constexpr size_t O_SS = al256(O_SAREA + KB4);
static constexpr size_t O_KW = al256(O_SS + KB4);
static constexpr size_t O_DIAG = al256(O_KW + (size_t)NCH * 8);
static constexpr size_t O_EPACK = al256(O_DIAG + (size_t)(NCH * 64) * 8);
static constexpr size_t O_DPACK = al256(O_EPACK + (size_t)NCH * CAP * 16);

extern "C" void kernel_launch(void* const* d_in, const int* in_sizes, int n_in,
                              void* d_out, int out_size, void* d_ws, size_t ws_size,
                              hipStream_t stream) {
    const float* scores = (const float*)d_in[0];
    const float4* deltas = (const float4*)d_in[1];
    const float4* anchors = (const float4*)d_in[2];
    float* out = (float*)d_out;
    char* ws = (char*)d_ws;

    u32* rank = (u32*)(ws + O_RANK);
    u32* Praw = (u32*)(ws + O_PRAW);
    u32* ecnt = (u32*)(ws + O_ECNT);
    u32* dcnt = (u32*)(ws + O_DCNT);
    u64* dmask = (u64*)(ws + O_DMASK);
    u64* vwords = (u64*)(ws + O_VW);
    u32* hist3 = (u32*)(ws + O_HIST);
    u32* cgt = (u32*)(ws + O_CGT);
    u32* gcnt = (u32*)(ws + O_GCNT);
    u32* tinfo = (u32*)(ws + O_TINFO);
    u32* sel = (u32*)(ws + O_SEL);
    u32* gidx = (u32*)(ws + O_GIDX);
    u32* gkey = (u32*)(ws + O_GKEY);
    float4* candB = (float4*)(ws + O_CANDB);
    float* candS = (float*)(ws + O_CANDS);
    u32* candV = (u32*)(ws + O_CANDV);
    u32* candA = (u32*)(ws + O_CANDA);
    float4* sB = (float4*)(ws + O_SB);
    float* sArea = (float*)(ws + O_SAREA);
    float* sS = (float*)(ws + O_SS);
    u64* keepw = (u64*)(ws + O_KW);
    u64* diag = (u64*)(ws + O_DIAG);
    ulonglong2* epack = (ulonglong2*)(ws + O_EPACK);
    ulonglong2* dpack = (ulonglong2*)(ws + O_DPACK);

    hipMemsetAsync(ws, 0, MEMSET_BYTES, stream);

    const int NBLK = (K_TOT + 255) / 256;  // 33
    k_hist<<<156, 1024, 0, stream>>>(scores, hist3);
    k_thresh<<<3, 1024, 0, stream>>>(hist3, tinfo);
    k_gather<<<159, 1024, 0, stream>>>(scores, tinfo, sel, cgt, gcnt, gidx, gkey);
    k_final<<<3, 1024, 0, stream>>>(gidx, gkey, gcnt, tinfo, sel);
    k_decode<<<NBLK, 256, 0, stream>>>(scores, deltas, anchors, sel, candB, candS, candV, candA);
    k_rank_lvl<<<dim3(8, 8, 5), 256, 0, stream>>>(candS, candA, Praw);
    k_rank_glob<<<dim3(NBLK, NBLK), 256, 0, stream>>>(candS, candV, Praw, rank);
    k_scatter<<<NBLK, 256, 0, stream>>>(candB, candS, candV, rank, sB, sArea, sS, vwords);
    k_mask<<<dim3(NCH, NBLK), 256, 0, stream>>>(sB, sArea, diag, ecnt, epack, dcnt, dmask, dpack);
    k_scan<<<1, 64, 0, stream>>>(diag, vwords, ecnt, epack, dcnt, dmask, dpack, keepw);
    k_out<<<1, 1024, 0, stream>>>(keepw, sB, sS, out);
}

// Round 3
// 220.577 us; speedup vs baseline: 1.0340x; 1.0340x over previous
//
#include <hip/hip_runtime.h>
#include <math.h>

typedef unsigned int u32;
typedef unsigned long long u64;
typedef unsigned char u8;

#define K_TOT 8382
#define NCH 131      // 131 chunks of 64 rows
#define CAP 1024     // per-TARGET-chunk off-diag entry capacity (global)
#define EC 64        // per-target-chunk entries staged to LDS (1 per lane)
#define DC 8         // per-chunk intra-chunk (diag) suppressor list capacity
#define GCAP 32768   // per-level threshold-bin candidate capacity
#define IMGSZ 800.0f

__device__ __constant__ int LOFF[5] = {0, 120000, 150000, 157500, 159375};
__device__ __constant__ int LCNT[5] = {120000, 30000, 7500, 1875, 507};
__device__ __constant__ int KSEL[5] = {2000, 2000, 2000, 1875, 507};
__device__ __constant__ int SELB[5] = {0, 2000, 4000, 6000, 7875};
__device__ __constant__ int HBS[4] = {0, 118, 148, 156};    // k_hist block starts (levels 0..2)
__device__ __constant__ int GBS[6] = {0, 118, 148, 156, 158, 159};  // k_gather block starts

static __device__ __forceinline__ u32 fkey(float x) {
    u32 u = __float_as_uint(x);
    u32 m = (u32)(((int)u) >> 31) | 0x80000000u;
    return u ^ m;
}

static __device__ __forceinline__ int lvl_of(int s) {
    return (s < 2000) ? 0 : (s < 4000) ? 1 : (s < 6000) ? 2 : (s < 7875) ? 3 : 4;
}

// scalar-path readlanes (uniform lane index -> v_readlane)
static __device__ __forceinline__ u32 rdl32(u32 v, int j) {
    return (u32)__builtin_amdgcn_readlane((int)v, j);
}
static __device__ __forceinline__ u64 rdlane64(u64 v, int j) {
    u32 lo = (u32)__builtin_amdgcn_readlane((int)(u32)v, j);
    u32 hi = (u32)__builtin_amdgcn_readlane((int)(u32)(v >> 32), j);
    return ((u64)hi << 32) | (u64)lo;
}

// wave64 OR-reduce via DPP (row_shr 1/2/4/8 + bcast15 + bcast31); result in lane 63
static __device__ __forceinline__ u32 wor32(u32 x) {
    x |= (u32)__builtin_amdgcn_update_dpp(0, (int)x, 0x111, 0xf, 0xf, true);
    x |= (u32)__builtin_amdgcn_update_dpp(0, (int)x, 0x112, 0xf, 0xf, true);
    x |= (u32)__builtin_amdgcn_update_dpp(0, (int)x, 0x114, 0xf, 0xf, true);
    x |= (u32)__builtin_amdgcn_update_dpp(0, (int)x, 0x118, 0xf, 0xf, true);
    x |= (u32)__builtin_amdgcn_update_dpp(0, (int)x, 0x142, 0xa, 0xf, true);
    x |= (u32)__builtin_amdgcn_update_dpp(0, (int)x, 0x143, 0xc, 0xf, true);
    return x;
}

// fetch keep-word of chunk sch from lane-distributed registers (k0/k1/k2)
static __device__ __forceinline__ u64 pullkeep(u64 k0, u64 k1, u64 k2, u32 sch) {
    int bidx = (int)((sch & 63u) << 2);
    u32 a0l = (u32)__builtin_amdgcn_ds_bpermute(bidx, (int)(u32)k0);
    u32 a0h = (u32)__builtin_amdgcn_ds_bpermute(bidx, (int)(u32)(k0 >> 32));
    u32 a1l = (u32)__builtin_amdgcn_ds_bpermute(bidx, (int)(u32)k1);
    u32 a1h = (u32)__builtin_amdgcn_ds_bpermute(bidx, (int)(u32)(k1 >> 32));
    u32 a2l = (u32)__builtin_amdgcn_ds_bpermute(bidx, (int)(u32)k2);
    u32 a2h = (u32)__builtin_amdgcn_ds_bpermute(bidx, (int)(u32)(k2 >> 32));
    return (sch < 64) ? (((u64)a0h << 32) | (u64)a0l)
         : (sch < 128) ? (((u64)a1h << 32) | (u64)a1l)
                       : (((u64)a2h << 32) | (u64)a2l);
}

// Parallel reverse-inclusive scan over hist[0..m-1] (from top bin down);
// finds bin with suffix-cum >= need. Out: sv[0]=bin, sv[1]=remaining ties to take.
static __device__ __forceinline__ void thresh_scan(const u32* hist, u32* scanbuf, int m,
                                                   u32 need, u32* sv, int t) {
    for (int i = t; i < m; i += 1024) scanbuf[i] = hist[m - 1 - i];
    __syncthreads();
    for (int ofs = 1; ofs < m; ofs <<= 1) {
        int i0 = t, i1 = t + 1024;
        u32 a0 = 0, a1 = 0;
        if (i0 < m && i0 >= ofs) a0 = scanbuf[i0 - ofs];
        if (i1 < m && i1 >= ofs) a1 = scanbuf[i1 - ofs];
        __syncthreads();
        if (i0 < m && i0 >= ofs) scanbuf[i0] += a0;
        if (i1 < m && i1 >= ofs) scanbuf[i1] += a1;
        __syncthreads();
    }
    for (int i = t; i < m; i += 1024) {
        u32 inc = scanbuf[i];
        u32 exc = i ? scanbuf[i - 1] : 0;
        if (inc >= need && exc < need) { sv[0] = (u32)(m - 1 - i); sv[1] = need - exc; }
    }
    __syncthreads();
}

// ---------------- K1a: parallel coarse histogram (top 11 key bits), levels 0..2 ----------------
__global__ __launch_bounds__(1024) void k_hist(const float* __restrict__ scores,
                                               u32* __restrict__ hist3) {
    __shared__ u32 lh[2048];
    int t = threadIdx.x;
    lh[t] = 0; lh[t + 1024] = 0;
    __syncthreads();
    int b = blockIdx.x;
    int l = (b < HBS[1]) ? 0 : (b < HBS[2]) ? 1 : 2;
    int i = (b - HBS[l]) * 1024 + t;
    if (i < LCNT[l]) atomicAdd(&lh[fkey(scores[LOFF[l] + i]) >> 21], 1u);
    __syncthreads();
    u32* h = hist3 + l * 2048;
    if (lh[t]) atomicAdd(&h[t], lh[t]);
    if (lh[t + 1024]) atomicAdd(&h[t + 1024], lh[t + 1024]);
}

// ---------------- K1b: coarse threshold per level ----------------
__global__ __launch_bounds__(1024) void k_thresh(const u32* __restrict__ hist3,
                                                 u32* __restrict__ tinfo) {
    __shared__ u32 scanbuf[2048];
    __shared__ u32 sv[2];
    int l = blockIdx.x;
    int t = threadIdx.x;
    thresh_scan(hist3 + l * 2048, scanbuf, 2048, (u32)KSEL[l], sv, t);
    if (t == 0) { tinfo[l * 2] = sv[0]; tinfo[l * 2 + 1] = sv[1]; }
}

// ---------------- K1c: classify; strict-greater -> sel, threshold-bin -> candidate buf ----------------
__global__ __launch_bounds__(1024) void k_gather(const float* __restrict__ scores,
                                                 const u32* __restrict__ tinfo,
                                                 u32* __restrict__ sel, u32* __restrict__ cgt,
                                                 u32* __restrict__ gcnt, u32* __restrict__ gidx,
                                                 u32* __restrict__ gkey) {
    int b = blockIdx.x;
    int l = (b < GBS[1]) ? 0 : (b < GBS[2]) ? 1 : (b < GBS[3]) ? 2 : (b < GBS[4]) ? 3 : 4;
    int i = (b - GBS[l]) * 1024 + threadIdx.x;
    if (i >= LCNT[l]) return;
    int off = LOFF[l], sb = SELB[l];
    if (l >= 3) { sel[sb + i] = (u32)(off + i); return; }  // take-all levels
    u32 ky = fkey(scores[off + i]);
    u32 b1 = tinfo[l * 2];
    u32 top = ky >> 21;
    if (top > b1) {
        u32 p = atomicAdd(&cgt[l], 1u);
        sel[sb + p] = (u32)(off + i);          // set membership only; order fixed by P later
    } else if (top == b1) {
        u32 e = atomicAdd(&gcnt[l], 1u);
        if (e < GCAP) { gidx[l * GCAP + e] = (u32)i; gkey[l * GCAP + e] = ky; }
    }
}

// ---------------- K1d: exact refine within threshold bin (mid 11 + low 10 bits) ----------------
__global__ __launch_bounds__(1024) void k_final(const u32* __restrict__ gidx,
                                                const u32* __restrict__ gkey,
                                                const u32* __restrict__ gcnt,
                                                const u32* __restrict__ tinfo,
                                                u32* __restrict__ sel) {
    __shared__ u32 hist[2048];
    __shared__ u32 scanbuf[2048];
    __shared__ u32 eqbuf[1024];
    __shared__ u32 sv[2];
    __shared__ u32 c2, ceq;
    int l = blockIdx.x;
    int t = threadIdx.x;
    int k = KSEL[l], sb = SELB[l], off = LOFF[l];
    u32 m = gcnt[l]; if (m > GCAP) m = GCAP;
    u32 b1 = tinfo[l * 2];
    u32 need = tinfo[l * 2 + 1];
    const u32* kb = gkey + l * GCAP;
    const u32* ib = gidx + l * GCAP;
    // mid 11 bits
    hist[t] = 0; hist[t + 1024] = 0; __syncthreads();
    for (u32 e = t; e < m; e += 1024) atomicAdd(&hist[(kb[e] >> 10) & 2047u], 1u);
    __syncthreads();
    thresh_scan(hist, scanbuf, 2048, need, sv, t);
    u32 b2 = sv[0], need2 = sv[1];
    __syncthreads();
    // low 10 bits
    hist[t] = 0; __syncthreads();
    for (u32 e = t; e < m; e += 1024) {
        u32 ky = kb[e];
        if (((ky >> 10) & 2047u) == b2) atomicAdd(&hist[ky & 1023u], 1u);
    }
    __syncthreads();
    thresh_scan(hist, scanbuf, 1024, need2, sv, t);
    u32 T = (b1 << 21) | (b2 << 10) | sv[0];
    u32 take = sv[1];
    if (t == 0) { c2 = 0; ceq = 0; }
    __syncthreads();
    u32 nGTbin = need - take;
    u32 base2 = (u32)sb + (u32)k - need;   // after strict-greater-bin entries
    for (u32 e = t; e < m; e += 1024) {
        u32 ky = kb[e];
        if (ky > T) { u32 p = atomicAdd(&c2, 1u); sel[base2 + p] = (u32)off + ib[e]; }
        else if (ky == T) { u32 q = atomicAdd(&ceq, 1u); if (q < 1024) eqbuf[q] = ib[e]; }
    }
    __syncthreads();
    if (t == 0) {
        int n = (ceq > 1024u) ? 1024 : (int)ceq;
        for (int a = 1; a < n; ++a) {  // ascending insertion sort; tie count tiny
            u32 v = eqbuf[a]; int bq = a - 1;
            while (bq >= 0 && eqbuf[bq] > v) { eqbuf[bq + 1] = eqbuf[bq]; --bq; }
            eqbuf[bq + 1] = v;
        }
        for (u32 q = 0; q < take; ++q) sel[base2 + nGTbin + q] = (u32)off + eqbuf[q];
    }
}

// ---------------- K2: decode selected boxes (exact reference op order) ----------------
__global__ void k_decode(const float* __restrict__ scores, const float4* __restrict__ deltas,
                         const float4* __restrict__ anchors, const u32* __restrict__ sel,
                         float4* __restrict__ candB, float* __restrict__ candS,
                         u32* __restrict__ candV, u32* __restrict__ candA) {
    int s = blockIdx.x * 256 + threadIdx.x;
    if (s >= K_TOT) return;
    u32 a = sel[s];
    float4 an = anchors[a];
    float4 dl = deltas[a];
    float sc = scores[a];
    float w = __fsub_rn(an.z, an.x), h = __fsub_rn(an.w, an.y);
    float cx = __fadd_rn(an.x, __fmul_rn(0.5f, w));
    float cy = __fadd_rn(an.y, __fmul_rn(0.5f, h));
    const float CLIPV = (float)4.1351665567423563;  // log(1000/16) as f32
    float dw = fminf(dl.z, CLIPV);
    float dh = fminf(dl.w, CLIPV);
    float px = __fadd_rn(cx, __fmul_rn(dl.x, w));
    float py = __fadd_rn(cy, __fmul_rn(dl.y, h));
    float pw = __fmul_rn((float)exp((double)dw), w);
    float ph = __fmul_rn((float)exp((double)dh), h);
    float x1 = __fsub_rn(px, __fmul_rn(0.5f, pw));
    float y1 = __fsub_rn(py, __fmul_rn(0.5f, ph));
    float x2 = __fadd_rn(px, __fmul_rn(0.5f, pw));
    float y2 = __fadd_rn(py, __fmul_rn(0.5f, ph));
    x1 = fminf(fmaxf(x1, 0.0f), IMGSZ);
    y1 = fminf(fmaxf(y1, 0.0f), IMGSZ);
    x2 = fminf(fmaxf(x2, 0.0f), IMGSZ);
    y2 = fminf(fmaxf(y2, 0.0f), IMGSZ);
    bool valid = (__fsub_rn(x2, x1) >= 0.001f) && (__fsub_rn(y2, y1) >= 0.001f);
    candB[s] = make_float4(x1, y1, x2, y2);
    candS[s] = sc;
    candV[s] = valid ? 1u : 0u;
    candA[s] = a;
}

// ---------------- K3a: within-level rank (tiled pairwise count) ----------------
__global__ __launch_bounds__(256) void k_rank_lvl(const float* __restrict__ candS,
                                                  const u32* __restrict__ candA,
                                                  u32* __restrict__ Praw) {
    __shared__ u64 tile[256];
    int l = blockIdx.z;
    int cnt = KSEL[l], base = SELB[l];
    int tx = blockIdx.x * 256;
    int ty = blockIdx.y * 256;
    if (tx >= cnt || ty >= cnt) return;
    int t = threadIdx.x;
    u64 Aj = ~0ull;  // sentinel: never < any real key
    if (tx + t < cnt) {
        int j = base + tx + t;
        Aj = ((u64)(~fkey(candS[j])) << 32) | (u64)candA[j];
    }
    tile[t] = Aj;
    __syncthreads();
    int si = ty + t;
    if (si >= cnt) return;
    int s = base + si;
    u64 A = ((u64)(~fkey(candS[s])) << 32) | (u64)candA[s];
    int r = 0;
#pragma unroll 8
    for (int q = 0; q < 256; ++q) r += (tile[q] < A);
    if (r) atomicAdd(&Praw[s], (u32)r);
}

// ---------------- K3b: global rank by (masked score desc, position asc) ----------------
__global__ __launch_bounds__(256) void k_rank_glob(const float* __restrict__ candS,
                                                   const u32* __restrict__ candV,
                                                   const u32* __restrict__ Praw,
                                                   u32* __restrict__ rank) {
    __shared__ u64 colB[256];
    int t = threadIdx.x;
    int cj = blockIdx.x * 256 + t;
    u64 B = ~0ull;
    if (cj < K_TOT) {
        u32 smk = candV[cj] ? fkey(candS[cj]) : 0x007FFFFFu;  // fkey(-inf)
        u32 Pj = (u32)SELB[lvl_of(cj)] + Praw[cj];
        B = ((u64)(~smk) << 32) | (u64)Pj;
    }
    colB[t] = B;
    __syncthreads();
    int s = blockIdx.y * 256 + t;
    if (s >= K_TOT) return;
    u32 smk = candV[s] ? fkey(candS[s]) : 0x007FFFFFu;
    u32 Ps = (u32)SELB[lvl_of(s)] + Praw[s];
    u64 myB = ((u64)(~smk) << 32) | (u64)Ps;
    int cnt = 0;
#pragma unroll 8
    for (int j = 0; j < 256; ++j) cnt += (colB[j] < myB);
    if (cnt) atomicAdd(&rank[s], (u32)cnt);
}

// ---------------- K4: scatter into sorted order ----------------
// Reference's fmask slice is all zeros -> NMS on raw clipped boxes (no level offsets).
__global__ void k_scatter(const float4* __restrict__ candB, const float* __restrict__ candS,
                          const u32* __restrict__ candV, const u32* __restrict__ rank,
                          float4* __restrict__ sB, float* __restrict__ sArea,
                          float* __restrict__ sS, u32* __restrict__ sV) {
    int s = blockIdx.x * 256 + threadIdx.x;
    if (s >= K_TOT) return;
    u32 r = rank[s];
    float4 b = candB[s];
    float area = __fmul_rn(__fsub_rn(b.z, b.x), __fsub_rn(b.w, b.y));
    sB[r] = b; sArea[r] = area; sS[r] = candS[s]; sV[r] = candV[s];
}

// ---------------- K5: suppression bits -> packed entry lists (+ vwords ballot) ----------------
// off-diag: bucketed by TARGET chunk, 16B entries {src_row, bits}  (pull model).
// diag (intra-chunk): 16B list entries {lane, bits} + dmask; full diag[] kept as fallback.
// vwords[wd]: ballot of sV over the diagonal wave (replaces separate k_vwords kernel).
__global__ __launch_bounds__(256) void k_mask(const float4* __restrict__ sB,
                                              const float* __restrict__ sArea,
                                              const u32* __restrict__ sV,
                                              u64* __restrict__ vwords,
                                              u64* __restrict__ diag, u32* __restrict__ ecnt,
                                              ulonglong2* __restrict__ epack,
                                              u32* __restrict__ dcnt, u64* __restrict__ dmask,
                                              ulonglong2* __restrict__ dpack) {
    __shared__ float4 cb[64];
    __shared__ float ca[64];
    int wd = blockIdx.x;   // target word (column chunk)
    int t = threadIdx.x;
    if (t < 64) {
        int j = wd * 64 + t;
        if (j < K_TOT) { cb[t] = sB[j]; ca[t] = sArea[j]; }
        else { cb[t] = make_float4(0.f, 0.f, 0.f, 0.f); ca[t] = 0.f; }
    }
    __syncthreads();
    int i = blockIdx.y * 256 + t;
    if (i >= K_TOT) return;
    int dwr = i >> 6;              // wave-uniform (i spans one aligned 64-row band per wave)
    if (wd < dwr) return;          // strictly upper-triangular
    float4 bi = sB[i];
    float ai = sArea[i];
    u64 bits = 0;
    int jbase = wd * 64;
    for (int j2 = 0; j2 < 64; ++j2) {
        int j = jbase + j2;
        if (j > i && j < K_TOT) {
            float4 bj = cb[j2];
            float ltx = fmaxf(bi.x, bj.x), lty = fmaxf(bi.y, bj.y);
            float rbx = fminf(bi.z, bj.z), rby = fminf(bi.w, bj.w);
            float wx = fmaxf(__fsub_rn(rbx, ltx), 0.0f);
            float wy = fmaxf(__fsub_rn(rby, lty), 0.0f);
            float inter = __fmul_rn(wx, wy);
            if (inter > 0.0f) {
                float uni = __fsub_rn(__fadd_rn(ai, ca[j2]), inter);
                float iou = inter / uni;  // IEEE f32 div, matches reference
                if (iou > 0.7f) bits |= (1ull << j2);
            }
        }
    }
    if (wd == dwr) {
        diag[i] = bits;  // always stored (overflow fallback)
        u64 vb = __ballot(sV[i] != 0u);          // wave-uniform branch: safe ballot
        if ((i & 63) == 0) vwords[wd] = vb;
        if (bits != 0ull) {
            u32 p = atomicAdd(&dcnt[dwr], 1u);
            if (p < DC) dpack[dwr * DC + p] = make_ulonglong2((u64)(i & 63), bits);
            atomicOr(&dmask[dwr], 1ull << (i & 63));
        }
    } else if (bits != 0ull) {
        u32 p = atomicAdd(&ecnt[wd], 1u);        // bucket by TARGET chunk (pull model)
        if (p < CAP) epack[wd * CAP + p] = make_ulonglong2((u64)i, bits);
    }
}

// ---------------- K6: sequential NMS scan (pull model) + fused top-1000 output ----------------
// Wave 0 runs the serial loop; aliveness of processed chunks lives in lane-distributed
// registers (lane l holds chunks l, l+64, l+128). Iteration c PULLS: each lane's staged
// entry {src_row, bits} checks src aliveness via ds_bpermute (no atomics, no ordering
// hazards), then a DPP OR-reduce forms the incoming suppression mask. All 16 waves stage
// LDS up front and emit the output at the end (k_out fused; no keepw global round-trip).
__global__ __launch_bounds__(1024) void k_scan(const u64* __restrict__ diag,
                                               const u64* __restrict__ vwords,
                                               const u32* __restrict__ ecnt,
                                               const ulonglong2* __restrict__ tpack,
                                               const u32* __restrict__ dcnt,
                                               const u64* __restrict__ dmask,
                                               const ulonglong2* __restrict__ dpack,
                                               const float4* __restrict__ sB,
                                               const float* __restrict__ sS,
                                               float* __restrict__ out) {
    __shared__ ulonglong2 sTpack[NCH * EC];   // 134 KB
    __shared__ ulonglong2 sDpack[NCH * DC];   // 16.8 KB
    __shared__ u64 sKeep[NCH];
    __shared__ u32 pc[NCH + 1];
    int t = threadIdx.x;
    int w = t >> 6, lane = t & 63;
    // tpack staging: wave w handles chunks w, w+16, ... (loads batched in flight)
    {
        ulonglong2 tmp[9];
        int nb = 0;
        for (int ch = w; ch < NCH; ch += 16) tmp[nb++] = tpack[(size_t)ch * CAP + lane];
        nb = 0;
        for (int ch = w; ch < NCH; ch += 16) sTpack[ch * EC + lane] = tmp[nb++];
    }
    // dpack staging: NCH*DC = 1048 entries
    {
        ulonglong2 a0, a1;
        bool p0 = t < NCH * DC, p1 = (t + 1024) < NCH * DC;
        if (p0) a0 = dpack[t];
        if (p1) a1 = dpack[t + 1024];
        if (p0) sDpack[t] = a0;
        if (p1) sDpack[t + 1024] = a1;
    }
    // per-chunk scalars into wave-0 registers (readlane-broadcast in the loop)
    u64 v0 = 0, v1 = 0, v2 = 0, m0 = 0, m1 = 0, m2 = 0;
    u32 c0 = 0, c1 = 0, c2 = 0, d0 = 0, d1 = 0, d2 = 0;
    if (w == 0) {
        int i0 = lane, i1 = lane + 64, i2 = lane + 128;
        bool p2 = (i2 < NCH);
        v0 = vwords[i0]; v1 = vwords[i1]; v2 = p2 ? vwords[i2] : 0;
        c0 = ecnt[i0]; c1 = ecnt[i1]; c2 = p2 ? ecnt[i2] : 0;
        d0 = dcnt[i0]; d1 = dcnt[i1]; d2 = p2 ? dcnt[i2] : 0;
        m0 = dmask[i0]; m1 = dmask[i1]; m2 = p2 ? dmask[i2] : 0;
        if (c0 > CAP) c0 = CAP;
        if (c1 > CAP) c1 = CAP;
        if (c2 > CAP) c2 = CAP;
    }
    __syncthreads();
    if (w == 0) {
        u64 k0 = 0, k1 = 0, k2 = 0;   // lane-distributed keep words
        ulonglong2 E = sTpack[lane];
        ulonglong2 DP = (lane < DC) ? sDpack[lane] : make_ulonglong2(~0ull, 0ull);
        u32 cnt = rdl32(c0, 0), dn = rdl32(d0, 0);
        u64 vw = rdlane64(v0, 0), dmw = rdlane64(m0, 0);
        for (int c = 0; c < NCH; ++c) {
            int cn = (c + 1 < NCH) ? (c + 1) : c;
            // prefetch next chunk's LDS entries + scalar broadcasts (off critical path)
            ulonglong2 En = sTpack[cn * EC + lane];
            ulonglong2 DPn = (lane < DC) ? sDpack[cn * DC + lane] : make_ulonglong2(~0ull, 0ull);
            u32 cntn, dnn; u64 vwn, dmn;
            if (cn < 64)       { cntn = rdl32(c0, cn);       dnn = rdl32(d0, cn);       vwn = rdlane64(v0, cn);       dmn = rdlane64(m0, cn); }
            else if (cn < 128) { cntn = rdl32(c1, cn - 64);  dnn = rdl32(d1, cn - 64);  vwn = rdlane64(v1, cn - 64);  dmn = rdlane64(m1, cn - 64); }
            else               { cntn = rdl32(c2, cn - 128); dnn = rdl32(d2, cn - 128); vwn = rdlane64(v2, cn - 128); dmn = rdlane64(m2, cn - 128); }
            // pull incoming suppression from alive earlier rows
            u64 incoming = 0;
            if (cnt) {
                u64 mbits = 0;
                {
                    u32 sidx = (u32)E.x & 0x3FFFu;
                    u64 kw = pullkeep(k0, k1, k2, sidx >> 6);
                    if (((u32)lane < cnt) && ((kw >> (sidx & 63u)) & 1ull)) mbits = E.y;
                }
                if (cnt > (u32)EC) {   // rare tail beyond LDS-staged entries (global)
                    for (u32 e = (u32)EC + (u32)lane; e < cnt; e += 64u) {
                        ulonglong2 Et = tpack[(size_t)c * CAP + e];
                        u32 sidx = (u32)Et.x & 0x3FFFu;
                        u64 kw = pullkeep(k0, k1, k2, sidx >> 6);
                        if ((kw >> (sidx & 63u)) & 1ull) mbits |= Et.y;
                    }
                }
                u32 lo = wor32((u32)mbits);
                u32 hi = wor32((u32)(mbits >> 32));
                incoming = ((u64)rdl32(hi, 63) << 32) | (u64)rdl32(lo, 63);
            }
            u64 alive = vw & ~incoming;
            if (dn) {
                if (dn <= (u32)DC) {
                    u64 dm = dmw & alive;          // rows dead on entry can never suppress
                    u32 ml = ((u32)lane < dn) ? (u32)DP.x : 0xFFu;
                    while (dm) {
                        int j = __builtin_ctzll(dm);
                        dm &= dm - 1;
                        if ((alive >> j) & 1ull) { // uniform branch
                            u64 selm = __ballot(ml == (u32)j);
                            int src = __builtin_ctzll(selm);
                            alive &= ~rdlane64(DP.y, src);
                        }
                    }
                } else {                            // overflow: read full diag words (rare)
                    int r = c * 64 + lane;
                    u64 D = (r < K_TOT) ? diag[r] : 0ull;
                    u64 nzd = __ballot(D != 0ull);
                    nzd &= alive;
                    while (nzd) {
                        int j = __builtin_ctzll(nzd);
                        nzd &= nzd - 1;
                        if ((alive >> j) & 1ull) alive &= ~rdlane64(D, j);
                    }
                }
            }
            if (lane == 0) sKeep[c] = alive;
            // publish alive into lane-distributed keep registers (c is uniform)
            if (c < 64)       { if (lane == c)       k0 = alive; }
            else if (c < 128) { if (lane == c - 64)  k1 = alive; }
            else              { if (lane == c - 128) k2 = alive; }
            E = En; DP = DPn; cnt = cntn; dn = dnn; vw = vwn; dmw = dmn;
        }
    }
    __syncthreads();
    // ---- fused output phase (all 1024 threads) ----
    if (t < NCH) pc[t + 1] = (u32)__popcll(sKeep[t]);
    if (t == 0) pc[0] = 0;
    __syncthreads();
    for (int ofs = 1; ofs < NCH; ofs <<= 1) {   // Hillis-Steele inclusive scan over pc[1..NCH]
        int i = t + 1;
        u32 v = 0;
        bool p = (t < NCH) && (i - ofs >= 1);
        if (p) v = pc[i - ofs];
        __syncthreads();
        if (p) pc[i] += v;
        __syncthreads();
    }
    u32 nk = pc[NCH];
    for (int i = t; i < K_TOT; i += 1024) {
        int wi = i >> 6, b = i & 63;
        u64 kw = sKeep[wi];
        u32 kb = pc[wi] + (u32)__popcll(kw & ((1ull << b) - 1ull));
        bool kp = (kw >> b) & 1ull;
        if (kp) {
            if (kb < 1000u) {
                float4 bx = sB[i];
                out[kb * 4 + 0] = bx.x; out[kb * 4 + 1] = bx.y;
                out[kb * 4 + 2] = bx.z; out[kb * 4 + 3] = bx.w;
                out[4000 + kb] = sS[i];
            }
        } else {
            u32 q = (u32)i - kb;
            u32 slot = nk + q;
            if (slot < 1000u) {
                float4 bx = sB[i];
                out[slot * 4 + 0] = bx.x; out[slot * 4 + 1] = bx.y;
                out[slot * 4 + 2] = bx.z; out[slot * 4 + 3] = bx.w;
                out[4000 + slot] = -INFINITY;
            }
        }
    }
}

// ---------------- workspace layout ----------------
static constexpr size_t al256(size_t x) { return (x + 255) & ~(size_t)255; }
static constexpr size_t KB4 = (size_t)K_TOT * 4;
static constexpr size_t KB16 = (size_t)K_TOT * 16;
// zeroed region:
static constexpr size_t O_RANK = 0;
static constexpr size_t O_PRAW = al256(O_RANK + KB4);
static constexpr size_t O_ECNT = al256(O_PRAW + KB4);
static constexpr size_t O_DCNT = al256(O_ECNT + (size_t)NCH * 4);
static constexpr size_t O_DMASK = al256(O_DCNT + (size_t)NCH * 4);
static constexpr size_t O_HIST = al256(O_DMASK + (size_t)NCH * 8);
static constexpr size_t O_CGT = al256(O_HIST + (size_t)3 * 2048 * 4);
static constexpr size_t O_GCNT = al256(O_CGT + 3 * 4);
static constexpr size_t MEMSET_BYTES = al256(O_GCNT + 3 * 4);
// non-zeroed region:
static constexpr size_t O_TINFO = MEMSET_BYTES;
static constexpr size_t O_SEL = al256(O_TINFO + 6 * 4);
static constexpr size_t O_GIDX = al256(O_SEL + KB4);
static constexpr size_t O_GKEY = al256(O_GIDX + (size_t)3 * GCAP * 4);
static constexpr size_t O_CANDB = al256(O_GKEY + (size_t)3 * GCAP * 4);
static constexpr size_t O_CANDS = al256(O_CANDB + KB16);
static constexpr size_t O_CANDV = al256(O_CANDS + KB4);
static constexpr size_t O_CANDA = al256(O_CANDV + KB4);
static constexpr size_t O_SB = al256(O_CANDA + KB4);
static constexpr size_t O_SAREA = al256(O_SB + KB16);
static constexpr size_t O_SS = al256(O_SAREA + KB4);
static constexpr size_t O_SV = al256(O_SS + KB4);
static constexpr size_t O_VW = al256(O_SV + KB4);
static constexpr size_t O_DIAG = al256(O_VW + (size_t)NCH * 8);
static constexpr size_t O_EPACK = al256(O_DIAG + (size_t)(NCH * 64) * 8);
static constexpr size_t O_DPACK = al256(O_EPACK + (size_t)NCH * CAP * 16);

extern "C" void kernel_launch(void* const* d_in, const int* in_sizes, int n_in,
                              void* d_out, int out_size, void* d_ws, size_t ws_size,
                              hipStream_t stream) {
    const float* scores = (const float*)d_in[0];
    const float4* deltas = (const float4*)d_in[1];
    const float4* anchors = (const float4*)d_in[2];
    float* out = (float*)d_out;
    char* ws = (char*)d_ws;

    u32* rank = (u32*)(ws + O_RANK);
    u32* Praw = (u32*)(ws + O_PRAW);
    u32* ecnt = (u32*)(ws + O_ECNT);
    u32* dcnt = (u32*)(ws + O_DCNT);
    u64* dmask = (u64*)(ws + O_DMASK);
    u32* hist3 = (u32*)(ws + O_HIST);
    u32* cgt = (u32*)(ws + O_CGT);
    u32* gcnt = (u32*)(ws + O_GCNT);
    u32* tinfo = (u32*)(ws + O_TINFO);
    u32* sel = (u32*)(ws + O_SEL);
    u32* gidx = (u32*)(ws + O_GIDX);
    u32* gkey = (u32*)(ws + O_GKEY);
    float4* candB = (float4*)(ws + O_CANDB);
    float* candS = (float*)(ws + O_CANDS);
    u32* candV = (u32*)(ws + O_CANDV);
    u32* candA = (u32*)(ws + O_CANDA);
    float4* sB = (float4*)(ws + O_SB);
    float* sArea = (float*)(ws + O_SAREA);
    float* sS = (float*)(ws + O_SS);
    u32* sV = (u32*)(ws + O_SV);
    u64* vwords = (u64*)(ws + O_VW);
    u64* diag = (u64*)(ws + O_DIAG);
    ulonglong2* epack = (ulonglong2*)(ws + O_EPACK);
    ulonglong2* dpack = (ulonglong2*)(ws + O_DPACK);

    hipMemsetAsync(ws, 0, MEMSET_BYTES, stream);

    const int NBLK = (K_TOT + 255) / 256;  // 33
    k_hist<<<156, 1024, 0, stream>>>(scores, hist3);
    k_thresh<<<3, 1024, 0, stream>>>(hist3, tinfo);
    k_gather<<<159, 1024, 0, stream>>>(scores, tinfo, sel, cgt, gcnt, gidx, gkey);
    k_final<<<3, 1024, 0, stream>>>(gidx, gkey, gcnt, tinfo, sel);
    k_decode<<<NBLK, 256, 0, stream>>>(scores, deltas, anchors, sel, candB, candS, candV, candA);
    k_rank_lvl<<<dim3(8, 8, 5), 256, 0, stream>>>(candS, candA, Praw);
    k_rank_glob<<<dim3(NBLK, NBLK), 256, 0, stream>>>(candS, candV, Praw, rank);
    k_scatter<<<NBLK, 256, 0, stream>>>(candB, candS, candV, rank, sB, sArea, sS, sV);
    k_mask<<<dim3(NCH, NBLK), 256, 0, stream>>>(sB, sArea, sV, vwords, diag, ecnt, epack, dcnt, dmask, dpack);
    k_scan<<<1, 1024, 0, stream>>>(diag, vwords, ecnt, epack, dcnt, dmask, dpack, sB, sS, out);
}

// Round 4
// 213.198 us; speedup vs baseline: 1.0698x; 1.0346x over previous
//
#include <hip/hip_runtime.h>
#include <math.h>

typedef unsigned int u32;
typedef unsigned long long u64;
typedef unsigned char u8;

#define K_TOT 8382
#define NCH 131      // 131 chunks of 64 rows
#define CAP 1024     // per-TARGET-chunk off-diag entry capacity (global)
#define EC 64        // per-target-chunk entries staged to LDS (1 per lane)
#define DC 8         // per-chunk intra-chunk (diag) suppressor list capacity
#define GCAP 32768   // per-level threshold-bin candidate capacity
#define IMGSZ 800.0f

__device__ __constant__ int LOFF[5] = {0, 120000, 150000, 157500, 159375};
__device__ __constant__ int LCNT[5] = {120000, 30000, 7500, 1875, 507};
__device__ __constant__ int KSEL[5] = {2000, 2000, 2000, 1875, 507};
__device__ __constant__ int SELB[5] = {0, 2000, 4000, 6000, 7875};
__device__ __constant__ int HBS[4] = {0, 118, 148, 156};    // k_hist block starts (levels 0..2)
__device__ __constant__ int GBS[6] = {0, 118, 148, 156, 158, 159};  // k_gather block starts

static __device__ __forceinline__ u32 fkey(float x) {
    u32 u = __float_as_uint(x);
    u32 m = (u32)(((int)u) >> 31) | 0x80000000u;
    return u ^ m;
}

static __device__ __forceinline__ int lvl_of(int s) {
    return (s < 2000) ? 0 : (s < 4000) ? 1 : (s < 6000) ? 2 : (s < 7875) ? 3 : 4;
}

// scalar-path readlanes (uniform lane index -> v_readlane)
static __device__ __forceinline__ u32 rdl32(u32 v, int j) {
    return (u32)__builtin_amdgcn_readlane((int)v, j);
}
static __device__ __forceinline__ u64 rdlane64(u64 v, int j) {
    u32 lo = (u32)__builtin_amdgcn_readlane((int)(u32)v, j);
    u32 hi = (u32)__builtin_amdgcn_readlane((int)(u32)(v >> 32), j);
    return ((u64)hi << 32) | (u64)lo;
}

// wave64 OR-reduce via DPP (row_shr 1/2/4/8 + bcast15 + bcast31); result in lane 63
static __device__ __forceinline__ u32 wor32(u32 x) {
    x |= (u32)__builtin_amdgcn_update_dpp(0, (int)x, 0x111, 0xf, 0xf, true);
    x |= (u32)__builtin_amdgcn_update_dpp(0, (int)x, 0x112, 0xf, 0xf, true);
    x |= (u32)__builtin_amdgcn_update_dpp(0, (int)x, 0x114, 0xf, 0xf, true);
    x |= (u32)__builtin_amdgcn_update_dpp(0, (int)x, 0x118, 0xf, 0xf, true);
    x |= (u32)__builtin_amdgcn_update_dpp(0, (int)x, 0x142, 0xa, 0xf, true);
    x |= (u32)__builtin_amdgcn_update_dpp(0, (int)x, 0x143, 0xc, 0xf, true);
    return x;
}

// fetch keep-word of chunk sch from lane-distributed registers (k0/k1/k2)
static __device__ __forceinline__ u64 pullkeep(u64 k0, u64 k1, u64 k2, u32 sch) {
    int bidx = (int)((sch & 63u) << 2);
    u32 a0l = (u32)__builtin_amdgcn_ds_bpermute(bidx, (int)(u32)k0);
    u32 a0h = (u32)__builtin_amdgcn_ds_bpermute(bidx, (int)(u32)(k0 >> 32));
    u32 a1l = (u32)__builtin_amdgcn_ds_bpermute(bidx, (int)(u32)k1);
    u32 a1h = (u32)__builtin_amdgcn_ds_bpermute(bidx, (int)(u32)(k1 >> 32));
    u32 a2l = (u32)__builtin_amdgcn_ds_bpermute(bidx, (int)(u32)k2);
    u32 a2h = (u32)__builtin_amdgcn_ds_bpermute(bidx, (int)(u32)(k2 >> 32));
    return (sch < 64) ? (((u64)a0h << 32) | (u64)a0l)
         : (sch < 128) ? (((u64)a1h << 32) | (u64)a1l)
                       : (((u64)a2h << 32) | (u64)a2l);
}

// Parallel reverse-inclusive scan over hist[0..m-1] (from top bin down);
// finds bin with suffix-cum >= need. Out: sv[0]=bin, sv[1]=remaining ties to take.
static __device__ __forceinline__ void thresh_scan(const u32* hist, u32* scanbuf, int m,
                                                   u32 need, u32* sv, int t) {
    for (int i = t; i < m; i += 1024) scanbuf[i] = hist[m - 1 - i];
    __syncthreads();
    for (int ofs = 1; ofs < m; ofs <<= 1) {
        int i0 = t, i1 = t + 1024;
        u32 a0 = 0, a1 = 0;
        if (i0 < m && i0 >= ofs) a0 = scanbuf[i0 - ofs];
        if (i1 < m && i1 >= ofs) a1 = scanbuf[i1 - ofs];
        __syncthreads();
        if (i0 < m && i0 >= ofs) scanbuf[i0] += a0;
        if (i1 < m && i1 >= ofs) scanbuf[i1] += a1;
        __syncthreads();
    }
    for (int i = t; i < m; i += 1024) {
        u32 inc = scanbuf[i];
        u32 exc = i ? scanbuf[i - 1] : 0;
        if (inc >= need && exc < need) { sv[0] = (u32)(m - 1 - i); sv[1] = need - exc; }
    }
    __syncthreads();
}

// ---------------- K1a: parallel coarse histogram (top 11 key bits), levels 0..2 ----------------
__global__ __launch_bounds__(1024) void k_hist(const float* __restrict__ scores,
                                               u32* __restrict__ hist3) {
    __shared__ u32 lh[2048];
    int t = threadIdx.x;
    lh[t] = 0; lh[t + 1024] = 0;
    __syncthreads();
    int b = blockIdx.x;
    int l = (b < HBS[1]) ? 0 : (b < HBS[2]) ? 1 : 2;
    int i = (b - HBS[l]) * 1024 + t;
    if (i < LCNT[l]) atomicAdd(&lh[fkey(scores[LOFF[l] + i]) >> 21], 1u);
    __syncthreads();
    u32* h = hist3 + l * 2048;
    if (lh[t]) atomicAdd(&h[t], lh[t]);
    if (lh[t + 1024]) atomicAdd(&h[t + 1024], lh[t + 1024]);
}

// ---------------- K1b: coarse threshold per level ----------------
__global__ __launch_bounds__(1024) void k_thresh(const u32* __restrict__ hist3,
                                                 u32* __restrict__ tinfo) {
    __shared__ u32 scanbuf[2048];
    __shared__ u32 sv[2];
    int l = blockIdx.x;
    int t = threadIdx.x;
    thresh_scan(hist3 + l * 2048, scanbuf, 2048, (u32)KSEL[l], sv, t);
    if (t == 0) { tinfo[l * 2] = sv[0]; tinfo[l * 2 + 1] = sv[1]; }
}

// ---------------- K1c: classify; strict-greater -> sel, threshold-bin -> candidate buf ----------------
__global__ __launch_bounds__(1024) void k_gather(const float* __restrict__ scores,
                                                 const u32* __restrict__ tinfo,
                                                 u32* __restrict__ sel, u32* __restrict__ cgt,
                                                 u32* __restrict__ gcnt, u32* __restrict__ gidx,
                                                 u32* __restrict__ gkey) {
    int b = blockIdx.x;
    int l = (b < GBS[1]) ? 0 : (b < GBS[2]) ? 1 : (b < GBS[3]) ? 2 : (b < GBS[4]) ? 3 : 4;
    int i = (b - GBS[l]) * 1024 + threadIdx.x;
    if (i >= LCNT[l]) return;
    int off = LOFF[l], sb = SELB[l];
    if (l >= 3) { sel[sb + i] = (u32)(off + i); return; }  // take-all levels
    u32 ky = fkey(scores[off + i]);
    u32 b1 = tinfo[l * 2];
    u32 top = ky >> 21;
    if (top > b1) {
        u32 p = atomicAdd(&cgt[l], 1u);
        sel[sb + p] = (u32)(off + i);          // set membership only; order fixed by P later
    } else if (top == b1) {
        u32 e = atomicAdd(&gcnt[l], 1u);
        if (e < GCAP) { gidx[l * GCAP + e] = (u32)i; gkey[l * GCAP + e] = ky; }
    }
}

// ---------------- K1d: exact refine within threshold bin (mid 11 + low 10 bits) ----------------
__global__ __launch_bounds__(1024) void k_final(const u32* __restrict__ gidx,
                                                const u32* __restrict__ gkey,
                                                const u32* __restrict__ gcnt,
                                                const u32* __restrict__ tinfo,
                                                u32* __restrict__ sel) {
    __shared__ u32 hist[2048];
    __shared__ u32 scanbuf[2048];
    __shared__ u32 eqbuf[1024];
    __shared__ u32 sv[2];
    __shared__ u32 c2, ceq;
    int l = blockIdx.x;
    int t = threadIdx.x;
    int k = KSEL[l], sb = SELB[l], off = LOFF[l];
    u32 m = gcnt[l]; if (m > GCAP) m = GCAP;
    u32 b1 = tinfo[l * 2];
    u32 need = tinfo[l * 2 + 1];
    const u32* kb = gkey + l * GCAP;
    const u32* ib = gidx + l * GCAP;
    // mid 11 bits
    hist[t] = 0; hist[t + 1024] = 0; __syncthreads();
    for (u32 e = t; e < m; e += 1024) atomicAdd(&hist[(kb[e] >> 10) & 2047u], 1u);
    __syncthreads();
    thresh_scan(hist, scanbuf, 2048, need, sv, t);
    u32 b2 = sv[0], need2 = sv[1];
    __syncthreads();
    // low 10 bits
    hist[t] = 0; __syncthreads();
    for (u32 e = t; e < m; e += 1024) {
        u32 ky = kb[e];
        if (((ky >> 10) & 2047u) == b2) atomicAdd(&hist[ky & 1023u], 1u);
    }
    __syncthreads();
    thresh_scan(hist, scanbuf, 1024, need2, sv, t);
    u32 T = (b1 << 21) | (b2 << 10) | sv[0];
    u32 take = sv[1];
    if (t == 0) { c2 = 0; ceq = 0; }
    __syncthreads();
    u32 nGTbin = need - take;
    u32 base2 = (u32)sb + (u32)k - need;   // after strict-greater-bin entries
    for (u32 e = t; e < m; e += 1024) {
        u32 ky = kb[e];
        if (ky > T) { u32 p = atomicAdd(&c2, 1u); sel[base2 + p] = (u32)off + ib[e]; }
        else if (ky == T) { u32 q = atomicAdd(&ceq, 1u); if (q < 1024) eqbuf[q] = ib[e]; }
    }
    __syncthreads();
    if (t == 0) {
        int n = (ceq > 1024u) ? 1024 : (int)ceq;
        for (int a = 1; a < n; ++a) {  // ascending insertion sort; tie count tiny
            u32 v = eqbuf[a]; int bq = a - 1;
            while (bq >= 0 && eqbuf[bq] > v) { eqbuf[bq + 1] = eqbuf[bq]; --bq; }
            eqbuf[bq + 1] = v;
        }
        for (u32 q = 0; q < take; ++q) sel[base2 + nGTbin + q] = (u32)off + eqbuf[q];
    }
}

// ---------------- K2: decode selected boxes (exact reference op order) ----------------
__global__ void k_decode(const float* __restrict__ scores, const float4* __restrict__ deltas,
                         const float4* __restrict__ anchors, const u32* __restrict__ sel,
                         float4* __restrict__ candB, float* __restrict__ candS,
                         u32* __restrict__ candV, u32* __restrict__ candA) {
    int s = blockIdx.x * 256 + threadIdx.x;
    if (s >= K_TOT) return;
    u32 a = sel[s];
    float4 an = anchors[a];
    float4 dl = deltas[a];
    float sc = scores[a];
    float w = __fsub_rn(an.z, an.x), h = __fsub_rn(an.w, an.y);
    float cx = __fadd_rn(an.x, __fmul_rn(0.5f, w));
    float cy = __fadd_rn(an.y, __fmul_rn(0.5f, h));
    const float CLIPV = (float)4.1351665567423563;  // log(1000/16) as f32
    float dw = fminf(dl.z, CLIPV);
    float dh = fminf(dl.w, CLIPV);
    float px = __fadd_rn(cx, __fmul_rn(dl.x, w));
    float py = __fadd_rn(cy, __fmul_rn(dl.y, h));
    float pw = __fmul_rn((float)exp((double)dw), w);
    float ph = __fmul_rn((float)exp((double)dh), h);
    float x1 = __fsub_rn(px, __fmul_rn(0.5f, pw));
    float y1 = __fsub_rn(py, __fmul_rn(0.5f, ph));
    float x2 = __fadd_rn(px, __fmul_rn(0.5f, pw));
    float y2 = __fadd_rn(py, __fmul_rn(0.5f, ph));
    x1 = fminf(fmaxf(x1, 0.0f), IMGSZ);
    y1 = fminf(fmaxf(y1, 0.0f), IMGSZ);
    x2 = fminf(fmaxf(x2, 0.0f), IMGSZ);
    y2 = fminf(fmaxf(y2, 0.0f), IMGSZ);
    bool valid = (__fsub_rn(x2, x1) >= 0.001f) && (__fsub_rn(y2, y1) >= 0.001f);
    candB[s] = make_float4(x1, y1, x2, y2);
    candS[s] = sc;
    candV[s] = valid ? 1u : 0u;
    candA[s] = a;
}

// ---------------- K3a: within-level rank (tiled pairwise count) ----------------
__global__ __launch_bounds__(256) void k_rank_lvl(const float* __restrict__ candS,
                                                  const u32* __restrict__ candA,
                                                  u32* __restrict__ Praw) {
    __shared__ u64 tile[256];
    int l = blockIdx.z;
    int cnt = KSEL[l], base = SELB[l];
    int tx = blockIdx.x * 256;
    int ty = blockIdx.y * 256;
    if (tx >= cnt || ty >= cnt) return;
    int t = threadIdx.x;
    u64 Aj = ~0ull;  // sentinel: never < any real key
    if (tx + t < cnt) {
        int j = base + tx + t;
        Aj = ((u64)(~fkey(candS[j])) << 32) | (u64)candA[j];
    }
    tile[t] = Aj;
    __syncthreads();
    int si = ty + t;
    if (si >= cnt) return;
    int s = base + si;
    u64 A = ((u64)(~fkey(candS[s])) << 32) | (u64)candA[s];
    int r = 0;
#pragma unroll 8
    for (int q = 0; q < 256; ++q) r += (tile[q] < A);
    if (r) atomicAdd(&Praw[s], (u32)r);
}

// ---------------- K3b: global rank by (masked score desc, position asc) ----------------
__global__ __launch_bounds__(256) void k_rank_glob(const float* __restrict__ candS,
                                                   const u32* __restrict__ candV,
                                                   const u32* __restrict__ Praw,
                                                   u32* __restrict__ rank) {
    __shared__ u64 colB[256];
    int t = threadIdx.x;
    int cj = blockIdx.x * 256 + t;
    u64 B = ~0ull;
    if (cj < K_TOT) {
        u32 smk = candV[cj] ? fkey(candS[cj]) : 0x007FFFFFu;  // fkey(-inf)
        u32 Pj = (u32)SELB[lvl_of(cj)] + Praw[cj];
        B = ((u64)(~smk) << 32) | (u64)Pj;
    }
    colB[t] = B;
    __syncthreads();
    int s = blockIdx.y * 256 + t;
    if (s >= K_TOT) return;
    u32 smk = candV[s] ? fkey(candS[s]) : 0x007FFFFFu;
    u32 Ps = (u32)SELB[lvl_of(s)] + Praw[s];
    u64 myB = ((u64)(~smk) << 32) | (u64)Ps;
    int cnt = 0;
#pragma unroll 8
    for (int j = 0; j < 256; ++j) cnt += (colB[j] < myB);
    if (cnt) atomicAdd(&rank[s], (u32)cnt);
}

// ---------------- K4: scatter into sorted order ----------------
// Reference's fmask slice is all zeros -> NMS on raw clipped boxes (no level offsets).
__global__ void k_scatter(const float4* __restrict__ candB, const float* __restrict__ candS,
                          const u32* __restrict__ candV, const u32* __restrict__ rank,
                          float4* __restrict__ sB, float* __restrict__ sArea,
                          float* __restrict__ sS, u32* __restrict__ sV) {
    int s = blockIdx.x * 256 + threadIdx.x;
    if (s >= K_TOT) return;
    u32 r = rank[s];
    float4 b = candB[s];
    float area = __fmul_rn(__fsub_rn(b.z, b.x), __fsub_rn(b.w, b.y));
    sB[r] = b; sArea[r] = area; sS[r] = candS[s]; sV[r] = candV[s];
}

// ---------------- K5: suppression bits -> packed entry lists (+ vwords ballot) ----------------
// off-diag: bucketed by TARGET chunk, 16B entries {src_row, bits}  (pull model).
// diag (intra-chunk): 16B list entries {lane, bits} + dmask; full diag[] kept as fallback.
// vwords[wd]: ballot of sV over the diagonal wave (replaces separate k_vwords kernel).
__global__ __launch_bounds__(256) void k_mask(const float4* __restrict__ sB,
                                              const float* __restrict__ sArea,
                                              const u32* __restrict__ sV,
                                              u64* __restrict__ vwords,
                                              u64* __restrict__ diag, u32* __restrict__ ecnt,
                                              ulonglong2* __restrict__ epack,
                                              u32* __restrict__ dcnt, u64* __restrict__ dmask,
                                              ulonglong2* __restrict__ dpack) {
    __shared__ float4 cb[64];
    __shared__ float ca[64];
    int wd = blockIdx.x;   // target word (column chunk)
    int t = threadIdx.x;
    if (t < 64) {
        int j = wd * 64 + t;
        if (j < K_TOT) { cb[t] = sB[j]; ca[t] = sArea[j]; }
        else { cb[t] = make_float4(0.f, 0.f, 0.f, 0.f); ca[t] = 0.f; }
    }
    __syncthreads();
    int i = blockIdx.y * 256 + t;
    if (i >= K_TOT) return;
    int dwr = i >> 6;              // wave-uniform (i spans one aligned 64-row band per wave)
    if (wd < dwr) return;          // strictly upper-triangular
    float4 bi = sB[i];
    float ai = sArea[i];
    u64 bits = 0;
    int jbase = wd * 64;
    for (int j2 = 0; j2 < 64; ++j2) {
        int j = jbase + j2;
        if (j > i && j < K_TOT) {
            float4 bj = cb[j2];
            float ltx = fmaxf(bi.x, bj.x), lty = fmaxf(bi.y, bj.y);
            float rbx = fminf(bi.z, bj.z), rby = fminf(bi.w, bj.w);
            float wx = fmaxf(__fsub_rn(rbx, ltx), 0.0f);
            float wy = fmaxf(__fsub_rn(rby, lty), 0.0f);
            float inter = __fmul_rn(wx, wy);
            if (inter > 0.0f) {
                float uni = __fsub_rn(__fadd_rn(ai, ca[j2]), inter);
                float iou = inter / uni;  // IEEE f32 div, matches reference
                if (iou > 0.7f) bits |= (1ull << j2);
            }
        }
    }
    if (wd == dwr) {
        diag[i] = bits;  // always stored (overflow fallback)
        u64 vb = __ballot(sV[i] != 0u);          // wave-uniform branch: safe ballot
        if ((i & 63) == 0) vwords[wd] = vb;
        if (bits != 0ull) {
            u32 p = atomicAdd(&dcnt[dwr], 1u);
            if (p < DC) dpack[dwr * DC + p] = make_ulonglong2((u64)(i & 63), bits);
            atomicOr(&dmask[dwr], 1ull << (i & 63));
        }
    } else if (bits != 0ull) {
        u32 p = atomicAdd(&ecnt[wd], 1u);        // bucket by TARGET chunk (pull model)
        if (p < CAP) epack[wd * CAP + p] = make_ulonglong2((u64)i, bits);
    }
}

// ---------------- K6: sequential NMS scan (pull model) + fused top-1000 output ----------------
// Wave 0 runs the serial loop; aliveness of processed chunks lives in lane-distributed
// registers (lane l holds chunks l, l+64, l+128). Iteration c PULLS: each lane's staged
// entry {src_row, bits} checks src aliveness via ds_bpermute (no atomics, no ordering
// hazards), then a DPP OR-reduce forms the incoming suppression mask. All 16 waves stage
// LDS up front and emit the output at the end (k_out fused; no keepw global round-trip).
// NOTE: all staging temporaries are STATICALLY NAMED (rule #20: runtime-indexed local
// arrays go to scratch — this was the round-3 regression: VGPR 52, WRITE_SIZE 150 KB).
__global__ __launch_bounds__(1024) void k_scan(const u64* __restrict__ diag,
                                               const u64* __restrict__ vwords,
                                               const u32* __restrict__ ecnt,
                                               const ulonglong2* __restrict__ tpack,
                                               const u32* __restrict__ dcnt,
                                               const u64* __restrict__ dmask,
                                               const ulonglong2* __restrict__ dpack,
                                               const float4* __restrict__ sB,
                                               const float* __restrict__ sS,
                                               float* __restrict__ out) {
    __shared__ ulonglong2 sTpack[NCH * EC];   // 134 KB
    __shared__ ulonglong2 sDpack[NCH * DC];   // 16.8 KB
    __shared__ u64 sKeep[NCH];
    __shared__ u32 pc[NCH + 1];
    int t = threadIdx.x;
    int w = t >> 6, lane = t & 63;
    // tpack staging: entries e = t + r*1024, e < NCH*EC (= 8384); fully static unroll.
    // global slot for entry e: chunk = e>>6 (stride CAP), lane slot = e&63.
    {
        int e0 = t, e1 = t + 1024, e2 = t + 2048, e3 = t + 3072, e4 = t + 4096;
        int e5 = t + 5120, e6 = t + 6144, e7 = t + 7168, e8 = t + 8192;
        bool p8 = e8 < NCH * EC;
        ulonglong2 a0 = tpack[(size_t)(e0 >> 6) * CAP + (e0 & 63)];
        ulonglong2 a1 = tpack[(size_t)(e1 >> 6) * CAP + (e1 & 63)];
        ulonglong2 a2 = tpack[(size_t)(e2 >> 6) * CAP + (e2 & 63)];
        ulonglong2 a3 = tpack[(size_t)(e3 >> 6) * CAP + (e3 & 63)];
        ulonglong2 a4 = tpack[(size_t)(e4 >> 6) * CAP + (e4 & 63)];
        ulonglong2 a5 = tpack[(size_t)(e5 >> 6) * CAP + (e5 & 63)];
        ulonglong2 a6 = tpack[(size_t)(e6 >> 6) * CAP + (e6 & 63)];
        ulonglong2 a7 = tpack[(size_t)(e7 >> 6) * CAP + (e7 & 63)];
        ulonglong2 a8 = make_ulonglong2(0ull, 0ull);
        if (p8) a8 = tpack[(size_t)(e8 >> 6) * CAP + (e8 & 63)];
        sTpack[e0] = a0; sTpack[e1] = a1; sTpack[e2] = a2; sTpack[e3] = a3;
        sTpack[e4] = a4; sTpack[e5] = a5; sTpack[e6] = a6; sTpack[e7] = a7;
        if (p8) sTpack[e8] = a8;
    }
    // dpack staging: NCH*DC = 1048 entries (statically named temporaries)
    {
        ulonglong2 a0, a1;
        bool p1 = (t + 1024) < NCH * DC;
        a0 = dpack[t];
        if (p1) a1 = dpack[t + 1024];
        sDpack[t] = a0;
        if (p1) sDpack[t + 1024] = a1;
    }
    // per-chunk scalars into wave-0 registers (readlane-broadcast in the loop)
    u64 v0 = 0, v1 = 0, v2 = 0, m0 = 0, m1 = 0, m2 = 0;
    u32 c0 = 0, c1 = 0, c2 = 0, d0 = 0, d1 = 0, d2 = 0;
    if (w == 0) {
        int i0 = lane, i1 = lane + 64, i2 = lane + 128;
        bool p2 = (i2 < NCH);
        v0 = vwords[i0]; v1 = vwords[i1]; v2 = p2 ? vwords[i2] : 0;
        c0 = ecnt[i0]; c1 = ecnt[i1]; c2 = p2 ? ecnt[i2] : 0;
        d0 = dcnt[i0]; d1 = dcnt[i1]; d2 = p2 ? dcnt[i2] : 0;
        m0 = dmask[i0]; m1 = dmask[i1]; m2 = p2 ? dmask[i2] : 0;
        if (c0 > CAP) c0 = CAP;
        if (c1 > CAP) c1 = CAP;
        if (c2 > CAP) c2 = CAP;
    }
    __syncthreads();
    if (w == 0) {
        u64 k0 = 0, k1 = 0, k2 = 0;   // lane-distributed keep words
        ulonglong2 E = sTpack[lane];
        ulonglong2 DP = (lane < DC) ? sDpack[lane] : make_ulonglong2(~0ull, 0ull);
        u32 cnt = rdl32(c0, 0), dn = rdl32(d0, 0);
        u64 vw = rdlane64(v0, 0), dmw = rdlane64(m0, 0);
        for (int c = 0; c < NCH; ++c) {
            int cn = (c + 1 < NCH) ? (c + 1) : c;
            // prefetch next chunk's LDS entries + scalar broadcasts (off critical path)
            ulonglong2 En = sTpack[cn * EC + lane];
            ulonglong2 DPn = (lane < DC) ? sDpack[cn * DC + lane] : make_ulonglong2(~0ull, 0ull);
            u32 cntn, dnn; u64 vwn, dmn;
            if (cn < 64)       { cntn = rdl32(c0, cn);       dnn = rdl32(d0, cn);       vwn = rdlane64(v0, cn);       dmn = rdlane64(m0, cn); }
            else if (cn < 128) { cntn = rdl32(c1, cn - 64);  dnn = rdl32(d1, cn - 64);  vwn = rdlane64(v1, cn - 64);  dmn = rdlane64(m1, cn - 64); }
            else               { cntn = rdl32(c2, cn - 128); dnn = rdl32(d2, cn - 128); vwn = rdlane64(v2, cn - 128); dmn = rdlane64(m2, cn - 128); }
            // pull incoming suppression from alive earlier rows
            u64 incoming = 0;
            if (cnt) {
                u64 mbits = 0;
                {
                    u32 sidx = (u32)E.x & 0x3FFFu;
                    u64 kw = pullkeep(k0, k1, k2, sidx >> 6);
                    if (((u32)lane < cnt) && ((kw >> (sidx & 63u)) & 1ull)) mbits = E.y;
                }
                if (cnt > (u32)EC) {   // rare tail beyond LDS-staged entries (global)
                    for (u32 e = (u32)EC + (u32)lane; e < cnt; e += 64u) {
                        ulonglong2 Et = tpack[(size_t)c * CAP + e];
                        u32 sidx = (u32)Et.x & 0x3FFFu;
                        u64 kw = pullkeep(k0, k1, k2, sidx >> 6);
                        if ((kw >> (sidx & 63u)) & 1ull) mbits |= Et.y;
                    }
                }
                u32 lo = wor32((u32)mbits);
                u32 hi = wor32((u32)(mbits >> 32));
                incoming = ((u64)rdl32(hi, 63) << 32) | (u64)rdl32(lo, 63);
            }
            u64 alive = vw & ~incoming;
            if (dn) {
                if (dn <= (u32)DC) {
                    u64 dm = dmw & alive;          // rows dead on entry can never suppress
                    u32 ml = ((u32)lane < dn) ? (u32)DP.x : 0xFFu;
                    while (dm) {
                        int j = __builtin_ctzll(dm);
                        dm &= dm - 1;
                        if ((alive >> j) & 1ull) { // uniform branch
                            u64 selm = __ballot(ml == (u32)j);
                            int src = __builtin_ctzll(selm);
                            alive &= ~rdlane64(DP.y, src);
                        }
                    }
                } else {                            // overflow: read full diag words (rare)
                    int r = c * 64 + lane;
                    u64 D = (r < K_TOT) ? diag[r] : 0ull;
                    u64 nzd = __ballot(D != 0ull);
                    nzd &= alive;
                    while (nzd) {
                        int j = __builtin_ctzll(nzd);
                        nzd &= nzd - 1;
                        if ((alive >> j) & 1ull) alive &= ~rdlane64(D, j);
                    }
                }
            }
            if (lane == 0) sKeep[c] = alive;
            // publish alive into lane-distributed keep registers (c is uniform)
            if (c < 64)       { if (lane == c)       k0 = alive; }
            else if (c < 128) { if (lane == c - 64)  k1 = alive; }
            else              { if (lane == c - 128) k2 = alive; }
            E = En; DP = DPn; cnt = cntn; dn = dnn; vw = vwn; dmw = dmn;
        }
    }
    __syncthreads();
    // ---- fused output phase (all 1024 threads) ----
    if (t < NCH) pc[t + 1] = (u32)__popcll(sKeep[t]);
    if (t == 0) pc[0] = 0;
    __syncthreads();
    for (int ofs = 1; ofs < NCH; ofs <<= 1) {   // Hillis-Steele inclusive scan over pc[1..NCH]
        int i = t + 1;
        u32 v = 0;
        bool p = (t < NCH) && (i - ofs >= 1);
        if (p) v = pc[i - ofs];
        __syncthreads();
        if (p) pc[i] += v;
        __syncthreads();
    }
    u32 nk = pc[NCH];
    for (int i = t; i < K_TOT; i += 1024) {
        int wi = i >> 6, b = i & 63;
        u64 kw = sKeep[wi];
        u32 kb = pc[wi] + (u32)__popcll(kw & ((1ull << b) - 1ull));
        bool kp = (kw >> b) & 1ull;
        if (kp) {
            if (kb < 1000u) {
                float4 bx = sB[i];
                out[kb * 4 + 0] = bx.x; out[kb * 4 + 1] = bx.y;
                out[kb * 4 + 2] = bx.z; out[kb * 4 + 3] = bx.w;
                out[4000 + kb] = sS[i];
            }
        } else {
            u32 q = (u32)i - kb;
            u32 slot = nk + q;
            if (slot < 1000u) {
                float4 bx = sB[i];
                out[slot * 4 + 0] = bx.x; out[slot * 4 + 1] = bx.y;
                out[slot * 4 + 2] = bx.z; out[slot * 4 + 3] = bx.w;
                out[4000 + slot] = -INFINITY;
            }
        }
    }
}

// ---------------- workspace layout ----------------
static constexpr size_t al256(size_t x) { return (x + 255) & ~(size_t)255; }
static constexpr size_t KB4 = (size_t)K_TOT * 4;
static constexpr size_t KB16 = (size_t)K_TOT * 16;
// zeroed region:
static constexpr size_t O_RANK = 0;
static constexpr size_t O_PRAW = al256(O_RANK + KB4);
static constexpr size_t O_ECNT = al256(O_PRAW + KB4);
static constexpr size_t O_DCNT = al256(O_ECNT + (size_t)NCH * 4);
static constexpr size_t O_DMASK = al256(O_DCNT + (size_t)NCH * 4);
static constexpr size_t O_HIST = al256(O_DMASK + (size_t)NCH * 8);
static constexpr size_t O_CGT = al256(O_HIST + (size_t)3 * 2048 * 4);
static constexpr size_t O_GCNT = al256(O_CGT + 3 * 4);
static constexpr size_t MEMSET_BYTES = al256(O_GCNT + 3 * 4);
// non-zeroed region:
static constexpr size_t O_TINFO = MEMSET_BYTES;
static constexpr size_t O_SEL = al256(O_TINFO + 6 * 4);
static constexpr size_t O_GIDX = al256(O_SEL + KB4);
static constexpr size_t O_GKEY = al256(O_GIDX + (size_t)3 * GCAP * 4);
static constexpr size_t O_CANDB = al256(O_GKEY + (size_t)3 * GCAP * 4);
static constexpr size_t O_CANDS = al256(O_CANDB + KB16);
static constexpr size_t O_CANDV = al256(O_CANDS + KB4);
static constexpr size_t O_CANDA = al256(O_CANDV + KB4);
static constexpr size_t O_SB = al256(O_CANDA + KB4);
static constexpr size_t O_SAREA = al256(O_SB + KB16);
static constexpr size_t O_SS = al256(O_SAREA + KB4);
static constexpr size_t O_SV = al256(O_SS + KB4);
static constexpr size_t O_VW = al256(O_SV + KB4);
static constexpr size_t O_DIAG = al256(O_VW + (size_t)NCH * 8);
static constexpr size_t O_EPACK = al256(O_DIAG + (size_t)(NCH * 64) * 8);
static constexpr size_t O_DPACK = al256(O_EPACK + (size_t)NCH * CAP * 16);

extern "C" void kernel_launch(void* const* d_in, const int* in_sizes, int n_in,
                              void* d_out, int out_size, void* d_ws, size_t ws_size,
                              hipStream_t stream) {
    const float* scores = (const float*)d_in[0];
    const float4* deltas = (const float4*)d_in[1];
    const float4* anchors = (const float4*)d_in[2];
    float* out = (float*)d_out;
    char* ws = (char*)d_ws;

    u32* rank = (u32*)(ws + O_RANK);
    u32* Praw = (u32*)(ws + O_PRAW);
    u32* ecnt = (u32*)(ws + O_ECNT);
    u32* dcnt = (u32*)(ws + O_DCNT);
    u64* dmask = (u64*)(ws + O_DMASK);
    u32* hist3 = (u32*)(ws + O_HIST);
    u32* cgt = (u32*)(ws + O_CGT);
    u32* gcnt = (u32*)(ws + O_GCNT);
    u32* tinfo = (u32*)(ws + O_TINFO);
    u32* sel = (u32*)(ws + O_SEL);
    u32* gidx = (u32*)(ws + O_GIDX);
    u32* gkey = (u32*)(ws + O_GKEY);
    float4* candB = (float4*)(ws + O_CANDB);
    float* candS = (float*)(ws + O_CANDS);
    u32* candV = (u32*)(ws + O_CANDV);
    u32* candA = (u32*)(ws + O_CANDA);
    float4* sB = (float4*)(ws + O_SB);
    float* sArea = (float*)(ws + O_SAREA);
    float* sS = (float*)(ws + O_SS);
    u32* sV = (u32*)(ws + O_SV);
    u64* vwords = (u64*)(ws + O_VW);
    u64* diag = (u64*)(ws + O_DIAG);
    ulonglong2* epack = (ulonglong2*)(ws + O_EPACK);
    ulonglong2* dpack = (ulonglong2*)(ws + O_DPACK);

    hipMemsetAsync(ws, 0, MEMSET_BYTES, stream);

    const int NBLK = (K_TOT + 255) / 256;  // 33
    k_hist<<<156, 1024, 0, stream>>>(scores, hist3);
    k_thresh<<<3, 1024, 0, stream>>>(hist3, tinfo);
    k_gather<<<159, 1024, 0, stream>>>(scores, tinfo, sel, cgt, gcnt, gidx, gkey);
    k_final<<<3, 1024, 0, stream>>>(gidx, gkey, gcnt, tinfo, sel);
    k_decode<<<NBLK, 256, 0, stream>>>(scores, deltas, anchors, sel, candB, candS, candV, candA);
    k_rank_lvl<<<dim3(8, 8, 5), 256, 0, stream>>>(candS, candA, Praw);
    k_rank_glob<<<dim3(NBLK, NBLK), 256, 0, stream>>>(candS, candV, Praw, rank);
    k_scatter<<<NBLK, 256, 0, stream>>>(candB, candS, candV, rank, sB, sArea, sS, sV);
    k_mask<<<dim3(NCH, NBLK), 256, 0, stream>>>(sB, sArea, sV, vwords, diag, ecnt, epack, dcnt, dmask, dpack);
    k_scan<<<1, 1024, 0, stream>>>(diag, vwords, ecnt, epack, dcnt, dmask, dpack, sB, sS, out);
}

// Round 5
// 212.939 us; speedup vs baseline: 1.0711x; 1.0012x over previous
//
#include <hip/hip_runtime.h>
#include <math.h>

typedef unsigned int u32;
typedef unsigned long long u64;
typedef unsigned char u8;

#define K_TOT 8382
#define NCH 131      // 131 chunks of 64 rows
#define CAP 1024     // per-TARGET-chunk off-diag entry capacity (global)
#define EC 64        // per-target-chunk entries staged to LDS (1 per lane)
#define GCAP 32768   // per-level threshold-bin candidate capacity
#define IMGSZ 800.0f

__device__ __constant__ int LOFF[5] = {0, 120000, 150000, 157500, 159375};
__device__ __constant__ int LCNT[5] = {120000, 30000, 7500, 1875, 507};
__device__ __constant__ int KSEL[5] = {2000, 2000, 2000, 1875, 507};
__device__ __constant__ int SELB[5] = {0, 2000, 4000, 6000, 7875};
__device__ __constant__ int HBS[4] = {0, 118, 148, 156};    // k_hist block starts (levels 0..2)
__device__ __constant__ int GBS[6] = {0, 118, 148, 156, 158, 159};  // k_gather block starts

static __device__ __forceinline__ u32 fkey(float x) {
    u32 u = __float_as_uint(x);
    u32 m = (u32)(((int)u) >> 31) | 0x80000000u;
    return u ^ m;
}

static __device__ __forceinline__ int lvl_of(int s) {
    return (s < 2000) ? 0 : (s < 4000) ? 1 : (s < 6000) ? 2 : (s < 7875) ? 3 : 4;
}

// scalar-path readlanes (uniform lane index -> v_readlane)
static __device__ __forceinline__ u32 rdl32(u32 v, int j) {
    return (u32)__builtin_amdgcn_readlane((int)v, j);
}
static __device__ __forceinline__ u64 rdlane64(u64 v, int j) {
    u32 lo = (u32)__builtin_amdgcn_readlane((int)(u32)v, j);
    u32 hi = (u32)__builtin_amdgcn_readlane((int)(u32)(v >> 32), j);
    return ((u64)hi << 32) | (u64)lo;
}

// wave64 OR-reduce via DPP (row_shr 1/2/4/8 + bcast15 + bcast31); result in lane 63
static __device__ __forceinline__ u32 wor32(u32 x) {
    x |= (u32)__builtin_amdgcn_update_dpp(0, (int)x, 0x111, 0xf, 0xf, true);
    x |= (u32)__builtin_amdgcn_update_dpp(0, (int)x, 0x112, 0xf, 0xf, true);
    x |= (u32)__builtin_amdgcn_update_dpp(0, (int)x, 0x114, 0xf, 0xf, true);
    x |= (u32)__builtin_amdgcn_update_dpp(0, (int)x, 0x118, 0xf, 0xf, true);
    x |= (u32)__builtin_amdgcn_update_dpp(0, (int)x, 0x142, 0xa, 0xf, true);
    x |= (u32)__builtin_amdgcn_update_dpp(0, (int)x, 0x143, 0xc, 0xf, true);
    return x;
}

// Parallel reverse-inclusive scan over hist[0..m-1] (from top bin down);
// finds bin with suffix-cum >= need. Out: sv[0]=bin, sv[1]=remaining ties to take.
static __device__ __forceinline__ void thresh_scan(const u32* hist, u32* scanbuf, int m,
                                                   u32 need, u32* sv, int t) {
    for (int i = t; i < m; i += 1024) scanbuf[i] = hist[m - 1 - i];
    __syncthreads();
    for (int ofs = 1; ofs < m; ofs <<= 1) {
        int i0 = t, i1 = t + 1024;
        u32 a0 = 0, a1 = 0;
        if (i0 < m && i0 >= ofs) a0 = scanbuf[i0 - ofs];
        if (i1 < m && i1 >= ofs) a1 = scanbuf[i1 - ofs];
        __syncthreads();
        if (i0 < m && i0 >= ofs) scanbuf[i0] += a0;
        if (i1 < m && i1 >= ofs) scanbuf[i1] += a1;
        __syncthreads();
    }
    for (int i = t; i < m; i += 1024) {
        u32 inc = scanbuf[i];
        u32 exc = i ? scanbuf[i - 1] : 0;
        if (inc >= need && exc < need) { sv[0] = (u32)(m - 1 - i); sv[1] = need - exc; }
    }
    __syncthreads();
}

// ---------------- K1a: parallel coarse histogram (top 11 key bits), levels 0..2 ----------------
__global__ __launch_bounds__(1024) void k_hist(const float* __restrict__ scores,
                                               u32* __restrict__ hist3) {
    __shared__ u32 lh[2048];
    int t = threadIdx.x;
    lh[t] = 0; lh[t + 1024] = 0;
    __syncthreads();
    int b = blockIdx.x;
    int l = (b < HBS[1]) ? 0 : (b < HBS[2]) ? 1 : 2;
    int i = (b - HBS[l]) * 1024 + t;
    if (i < LCNT[l]) atomicAdd(&lh[fkey(scores[LOFF[l] + i]) >> 21], 1u);
    __syncthreads();
    u32* h = hist3 + l * 2048;
    if (lh[t]) atomicAdd(&h[t], lh[t]);
    if (lh[t + 1024]) atomicAdd(&h[t + 1024], lh[t + 1024]);
}

// ---------------- K1b: coarse threshold per level ----------------
__global__ __launch_bounds__(1024) void k_thresh(const u32* __restrict__ hist3,
                                                 u32* __restrict__ tinfo) {
    __shared__ u32 scanbuf[2048];
    __shared__ u32 sv[2];
    int l = blockIdx.x;
    int t = threadIdx.x;
    thresh_scan(hist3 + l * 2048, scanbuf, 2048, (u32)KSEL[l], sv, t);
    if (t == 0) { tinfo[l * 2] = sv[0]; tinfo[l * 2 + 1] = sv[1]; }
}

// ---------------- K1c: classify; strict-greater -> sel, threshold-bin -> candidate buf ----------------
__global__ __launch_bounds__(1024) void k_gather(const float* __restrict__ scores,
                                                 const u32* __restrict__ tinfo,
                                                 u32* __restrict__ sel, u32* __restrict__ cgt,
                                                 u32* __restrict__ gcnt, u32* __restrict__ gidx,
                                                 u32* __restrict__ gkey) {
    int b = blockIdx.x;
    int l = (b < GBS[1]) ? 0 : (b < GBS[2]) ? 1 : (b < GBS[3]) ? 2 : (b < GBS[4]) ? 3 : 4;
    int i = (b - GBS[l]) * 1024 + threadIdx.x;
    if (i >= LCNT[l]) return;
    int off = LOFF[l], sb = SELB[l];
    if (l >= 3) { sel[sb + i] = (u32)(off + i); return; }  // take-all levels
    u32 ky = fkey(scores[off + i]);
    u32 b1 = tinfo[l * 2];
    u32 top = ky >> 21;
    if (top > b1) {
        u32 p = atomicAdd(&cgt[l], 1u);
        sel[sb + p] = (u32)(off + i);          // set membership only; order fixed by P later
    } else if (top == b1) {
        u32 e = atomicAdd(&gcnt[l], 1u);
        if (e < GCAP) { gidx[l * GCAP + e] = (u32)i; gkey[l * GCAP + e] = ky; }
    }
}

// ---------------- K1d: exact refine within threshold bin (mid 11 + low 10 bits) ----------------
__global__ __launch_bounds__(1024) void k_final(const u32* __restrict__ gidx,
                                                const u32* __restrict__ gkey,
                                                const u32* __restrict__ gcnt,
                                                const u32* __restrict__ tinfo,
                                                u32* __restrict__ sel) {
    __shared__ u32 hist[2048];
    __shared__ u32 scanbuf[2048];
    __shared__ u32 eqbuf[1024];
    __shared__ u32 sv[2];
    __shared__ u32 c2, ceq;
    int l = blockIdx.x;
    int t = threadIdx.x;
    int k = KSEL[l], sb = SELB[l], off = LOFF[l];
    u32 m = gcnt[l]; if (m > GCAP) m = GCAP;
    u32 b1 = tinfo[l * 2];
    u32 need = tinfo[l * 2 + 1];
    const u32* kb = gkey + l * GCAP;
    const u32* ib = gidx + l * GCAP;
    // mid 11 bits
    hist[t] = 0; hist[t + 1024] = 0; __syncthreads();
    for (u32 e = t; e < m; e += 1024) atomicAdd(&hist[(kb[e] >> 10) & 2047u], 1u);
    __syncthreads();
    thresh_scan(hist, scanbuf, 2048, need, sv, t);
    u32 b2 = sv[0], need2 = sv[1];
    __syncthreads();
    // low 10 bits
    hist[t] = 0; __syncthreads();
    for (u32 e = t; e < m; e += 1024) {
        u32 ky = kb[e];
        if (((ky >> 10) & 2047u) == b2) atomicAdd(&hist[ky & 1023u], 1u);
    }
    __syncthreads();
    thresh_scan(hist, scanbuf, 1024, need2, sv, t);
    u32 T = (b1 << 21) | (b2 << 10) | sv[0];
    u32 take = sv[1];
    if (t == 0) { c2 = 0; ceq = 0; }
    __syncthreads();
    u32 nGTbin = need - take;
    u32 base2 = (u32)sb + (u32)k - need;   // after strict-greater-bin entries
    for (u32 e = t; e < m; e += 1024) {
        u32 ky = kb[e];
        if (ky > T) { u32 p = atomicAdd(&c2, 1u); sel[base2 + p] = (u32)off + ib[e]; }
        else if (ky == T) { u32 q = atomicAdd(&ceq, 1u); if (q < 1024) eqbuf[q] = ib[e]; }
    }
    __syncthreads();
    if (t == 0) {
        int n = (ceq > 1024u) ? 1024 : (int)ceq;
        for (int a = 1; a < n; ++a) {  // ascending insertion sort; tie count tiny
            u32 v = eqbuf[a]; int bq = a - 1;
            while (bq >= 0 && eqbuf[bq] > v) { eqbuf[bq + 1] = eqbuf[bq]; --bq; }
            eqbuf[bq + 1] = v;
        }
        for (u32 q = 0; q < take; ++q) sel[base2 + nGTbin + q] = (u32)off + eqbuf[q];
    }
}

// ---------------- K2: decode selected boxes (exact reference op order) ----------------
__global__ void k_decode(const float* __restrict__ scores, const float4* __restrict__ deltas,
                         const float4* __restrict__ anchors, const u32* __restrict__ sel,
                         float4* __restrict__ candB, float* __restrict__ candS,
                         u32* __restrict__ candV, u32* __restrict__ candA) {
    int s = blockIdx.x * 256 + threadIdx.x;
    if (s >= K_TOT) return;
    u32 a = sel[s];
    float4 an = anchors[a];
    float4 dl = deltas[a];
    float sc = scores[a];
    float w = __fsub_rn(an.z, an.x), h = __fsub_rn(an.w, an.y);
    float cx = __fadd_rn(an.x, __fmul_rn(0.5f, w));
    float cy = __fadd_rn(an.y, __fmul_rn(0.5f, h));
    const float CLIPV = (float)4.1351665567423563;  // log(1000/16) as f32
    float dw = fminf(dl.z, CLIPV);
    float dh = fminf(dl.w, CLIPV);
    float px = __fadd_rn(cx, __fmul_rn(dl.x, w));
    float py = __fadd_rn(cy, __fmul_rn(dl.y, h));
    float pw = __fmul_rn((float)exp((double)dw), w);
    float ph = __fmul_rn((float)exp((double)dh), h);
    float x1 = __fsub_rn(px, __fmul_rn(0.5f, pw));
    float y1 = __fsub_rn(py, __fmul_rn(0.5f, ph));
    float x2 = __fadd_rn(px, __fmul_rn(0.5f, pw));
    float y2 = __fadd_rn(py, __fmul_rn(0.5f, ph));
    x1 = fminf(fmaxf(x1, 0.0f), IMGSZ);
    y1 = fminf(fmaxf(y1, 0.0f), IMGSZ);
    x2 = fminf(fmaxf(x2, 0.0f), IMGSZ);
    y2 = fminf(fmaxf(y2, 0.0f), IMGSZ);
    bool valid = (__fsub_rn(x2, x1) >= 0.001f) && (__fsub_rn(y2, y1) >= 0.001f);
    candB[s] = make_float4(x1, y1, x2, y2);
    candS[s] = sc;
    candV[s] = valid ? 1u : 0u;
    candA[s] = a;
}

// ---------------- K3a: within-level rank (tiled pairwise count) ----------------
__global__ __launch_bounds__(256) void k_rank_lvl(const float* __restrict__ candS,
                                                  const u32* __restrict__ candA,
                                                  u32* __restrict__ Praw) {
    __shared__ u64 tile[256];
    int l = blockIdx.z;
    int cnt = KSEL[l], base = SELB[l];
    int tx = blockIdx.x * 256;
    int ty = blockIdx.y * 256;
    if (tx >= cnt || ty >= cnt) return;
    int t = threadIdx.x;
    u64 Aj = ~0ull;  // sentinel: never < any real key
    if (tx + t < cnt) {
        int j = base + tx + t;
        Aj = ((u64)(~fkey(candS[j])) << 32) | (u64)candA[j];
    }
    tile[t] = Aj;
    __syncthreads();
    int si = ty + t;
    if (si >= cnt) return;
    int s = base + si;
    u64 A = ((u64)(~fkey(candS[s])) << 32) | (u64)candA[s];
    int r = 0;
#pragma unroll 8
    for (int q = 0; q < 256; ++q) r += (tile[q] < A);
    if (r) atomicAdd(&Praw[s], (u32)r);
}

// ---------------- K3b: global rank by (masked score desc, position asc) ----------------
__global__ __launch_bounds__(256) void k_rank_glob(const float* __restrict__ candS,
                                                   const u32* __restrict__ candV,
                                                   const u32* __restrict__ Praw,
                                                   u32* __restrict__ rank) {
    __shared__ u64 colB[256];
    int t = threadIdx.x;
    int cj = blockIdx.x * 256 + t;
    u64 B = ~0ull;
    if (cj < K_TOT) {
        u32 smk = candV[cj] ? fkey(candS[cj]) : 0x007FFFFFu;  // fkey(-inf)
        u32 Pj = (u32)SELB[lvl_of(cj)] + Praw[cj];
        B = ((u64)(~smk) << 32) | (u64)Pj;
    }
    colB[t] = B;
    __syncthreads();
    int s = blockIdx.y * 256 + t;
    if (s >= K_TOT) return;
    u32 smk = candV[s] ? fkey(candS[s]) : 0x007FFFFFu;
    u32 Ps = (u32)SELB[lvl_of(s)] + Praw[s];
    u64 myB = ((u64)(~smk) << 32) | (u64)Ps;
    int cnt = 0;
#pragma unroll 8
    for (int j = 0; j < 256; ++j) cnt += (colB[j] < myB);
    if (cnt) atomicAdd(&rank[s], (u32)cnt);
}

// ---------------- K4: scatter into sorted order ----------------
// Reference's fmask slice is all zeros -> NMS on raw clipped boxes (no level offsets).
__global__ void k_scatter(const float4* __restrict__ candB, const float* __restrict__ candS,
                          const u32* __restrict__ candV, const u32* __restrict__ rank,
                          float4* __restrict__ sB, float* __restrict__ sArea,
                          float* __restrict__ sS, u32* __restrict__ sV) {
    int s = blockIdx.x * 256 + threadIdx.x;
    if (s >= K_TOT) return;
    u32 r = rank[s];
    float4 b = candB[s];
    float area = __fmul_rn(__fsub_rn(b.z, b.x), __fsub_rn(b.w, b.y));
    sB[r] = b; sArea[r] = area; sS[r] = candS[s]; sV[r] = candV[s];
}

// ---------------- K5: suppression bits -> packed entry lists (+ vwords/dmask ballots) ----------------
// off-diag: bucketed by TARGET chunk, 16B entries {src_row, bits}  (pull model).
// diag (intra-chunk): full diag[] row words; dmask via wave ballot (no atomics).
__global__ __launch_bounds__(256) void k_mask(const float4* __restrict__ sB,
                                              const float* __restrict__ sArea,
                                              const u32* __restrict__ sV,
                                              u64* __restrict__ vwords,
                                              u64* __restrict__ diag, u32* __restrict__ ecnt,
                                              ulonglong2* __restrict__ epack,
                                              u64* __restrict__ dmask) {
    __shared__ float4 cb[64];
    __shared__ float ca[64];
    int wd = blockIdx.x;   // target word (column chunk)
    int t = threadIdx.x;
    if (t < 64) {
        int j = wd * 64 + t;
        if (j < K_TOT) { cb[t] = sB[j]; ca[t] = sArea[j]; }
        else { cb[t] = make_float4(0.f, 0.f, 0.f, 0.f); ca[t] = 0.f; }
    }
    __syncthreads();
    int i = blockIdx.y * 256 + t;
    if (i >= K_TOT) return;
    int dwr = i >> 6;              // wave-uniform (i spans one aligned 64-row band per wave)
    if (wd < dwr) return;          // strictly upper-triangular
    float4 bi = sB[i];
    float ai = sArea[i];
    u64 bits = 0;
    int jbase = wd * 64;
    for (int j2 = 0; j2 < 64; ++j2) {
        int j = jbase + j2;
        if (j > i && j < K_TOT) {
            float4 bj = cb[j2];
            float ltx = fmaxf(bi.x, bj.x), lty = fmaxf(bi.y, bj.y);
            float rbx = fminf(bi.z, bj.z), rby = fminf(bi.w, bj.w);
            float wx = fmaxf(__fsub_rn(rbx, ltx), 0.0f);
            float wy = fmaxf(__fsub_rn(rby, lty), 0.0f);
            float inter = __fmul_rn(wx, wy);
            if (inter > 0.0f) {
                float uni = __fsub_rn(__fadd_rn(ai, ca[j2]), inter);
                float iou = inter / uni;  // IEEE f32 div, matches reference
                if (iou > 0.7f) bits |= (1ull << j2);
            }
        }
    }
    if (wd == dwr) {
        diag[i] = bits;                          // per-row intra-chunk suppressor word
        u64 vb = __ballot(sV[i] != 0u);          // wave-uniform branch: safe ballots
        u64 db = __ballot(bits != 0ull);
        if ((i & 63) == 0) { vwords[wd] = vb; dmask[wd] = db; }
    } else if (bits != 0ull) {
        u32 p = atomicAdd(&ecnt[wd], 1u);        // bucket by TARGET chunk (pull model)
        if (p < CAP) epack[wd * CAP + p] = make_ulonglong2((u64)i, bits);
    }
}

// ---------------- K6: sequential NMS scan (pull, LDS keep-state) + fused output ----------------
// Chain design: the ONLY on-chain work per chunk is {alive = vw & ~inc -> intra-chunk dm
// loop (own-lane diag regs, readlane, no ballot) -> one wor32 OR-reduce for next chunk's
// incoming}. All DS/global traffic (entry prefetch, keep-state gather via lane-divergent
// ds_read, depth-2 diag global prefetch) is issued at iteration top and consumed late.
// Keep-state of finalized chunks lives in sKeepArr (LDS); same-wave DS ordering makes the
// gather safe without atomics. Entries with src chunk == c use the in-register `alive`.
__global__ __launch_bounds__(1024) void k_scan(const u64* __restrict__ diag,
                                               const u64* __restrict__ vwords,
                                               const u32* __restrict__ ecnt,
                                               const ulonglong2* __restrict__ tpack,
                                               const u64* __restrict__ dmask,
                                               const float4* __restrict__ sB,
                                               const float* __restrict__ sS,
                                               float* __restrict__ out) {
    __shared__ ulonglong2 sTpack[NCH * EC];   // 134 KB
    __shared__ u64 sKeepArr[NCH];
    __shared__ u32 pc[NCH + 1];
    int t = threadIdx.x;
    int w = t >> 6, lane = t & 63;
    // tpack staging: entries e = t + r*1024, e < NCH*EC (= 8384); fully static unroll
    // (rule #20: statically named temporaries only). chunk = e>>6 (stride CAP), slot = e&63.
    {
        int e0 = t, e1 = t + 1024, e2 = t + 2048, e3 = t + 3072, e4 = t + 4096;
        int e5 = t + 5120, e6 = t + 6144, e7 = t + 7168, e8 = t + 8192;
        bool p8 = e8 < NCH * EC;
        ulonglong2 a0 = tpack[(size_t)(e0 >> 6) * CAP + (e0 & 63)];
        ulonglong2 a1 = tpack[(size_t)(e1 >> 6) * CAP + (e1 & 63)];
        ulonglong2 a2 = tpack[(size_t)(e2 >> 6) * CAP + (e2 & 63)];
        ulonglong2 a3 = tpack[(size_t)(e3 >> 6) * CAP + (e3 & 63)];
        ulonglong2 a4 = tpack[(size_t)(e4 >> 6) * CAP + (e4 & 63)];
        ulonglong2 a5 = tpack[(size_t)(e5 >> 6) * CAP + (e5 & 63)];
        ulonglong2 a6 = tpack[(size_t)(e6 >> 6) * CAP + (e6 & 63)];
        ulonglong2 a7 = tpack[(size_t)(e7 >> 6) * CAP + (e7 & 63)];
        ulonglong2 a8 = make_ulonglong2(0ull, 0ull);
        if (p8) a8 = tpack[(size_t)(e8 >> 6) * CAP + (e8 & 63)];
        sTpack[e0] = a0; sTpack[e1] = a1; sTpack[e2] = a2; sTpack[e3] = a3;
        sTpack[e4] = a4; sTpack[e5] = a5; sTpack[e6] = a6; sTpack[e7] = a7;
        if (p8) sTpack[e8] = a8;
    }
    // per-chunk scalars into wave-0 registers (readlane-broadcast in the loop)
    u64 v0 = 0, v1 = 0, v2 = 0, m0 = 0, m1 = 0, m2 = 0;
    u32 c0 = 0, c1 = 0, c2 = 0;
    if (w == 0) {
        int i0 = lane, i1 = lane + 64, i2 = lane + 128;
        bool p2 = (i2 < NCH);
        v0 = vwords[i0]; v1 = vwords[i1]; v2 = p2 ? vwords[i2] : 0;
        c0 = ecnt[i0]; c1 = ecnt[i1]; c2 = p2 ? ecnt[i2] : 0;
        m0 = dmask[i0]; m1 = dmask[i1]; m2 = p2 ? dmask[i2] : 0;
        if (c0 > CAP) c0 = CAP;
        if (c1 > CAP) c1 = CAP;
        if (c2 > CAP) c2 = CAP;
    }
    __syncthreads();
    if (w == 0) {
        // prologue: entries targeting chunk 1; diag rows for chunks 0,1 (depth-2 prefetch)
        ulonglong2 Ea = sTpack[EC + lane];
        u64 Dcur = diag[lane];
        u64 Dnx  = diag[64 + lane];
        u64 vw = rdlane64(v0, 0), dmw = rdlane64(m0, 0);
        u64 inc = 0;                 // chunk 0 has no incoming entries
        u32 cntn = rdl32(c0, 1);     // ecnt for chunk 1 (entry gating for Ea)
        for (int c = 0; c < NCH; ++c) {
            int cn  = (c + 1 < NCH) ? (c + 1) : c;
            int cn2 = (c + 2 < NCH) ? (c + 2) : c;
            // ---- off-chain issues (consumed late) ----
            ulonglong2 Eb = sTpack[cn2 * EC + lane];          // entries targeting c+2
            u64 Dnn = diag[cn2 * 64 + lane];                  // diag prefetch depth-2
            u32 sidx = (u32)Ea.x;
            u32 sch = sidx >> 6;
            u64 Kw = sKeepArr[(sch < (u32)NCH) ? sch : 0];    // lane-divergent LDS gather
            // next-next scalars broadcast (register ops)
            u32 cntn2; u64 vwn, dmn;
            if (cn < 64)       { vwn = rdlane64(v0, cn);       dmn = rdlane64(m0, cn); }
            else if (cn < 128) { vwn = rdlane64(v1, cn - 64);  dmn = rdlane64(m1, cn - 64); }
            else               { vwn = rdlane64(v2, cn - 128); dmn = rdlane64(m2, cn - 128); }
            if (cn2 < 64)       cntn2 = rdl32(c0, cn2);
            else if (cn2 < 128) cntn2 = rdl32(c1, cn2 - 64);
            else                cntn2 = rdl32(c2, cn2 - 128);
            // ---- chain: resolve chunk c ----
            u64 alive = vw & ~inc;
            if (dmw) {
                u64 dm = dmw & alive;
                while (dm) {
                    int j = __builtin_ctzll(dm);
                    dm &= dm - 1;
                    if ((alive >> j) & 1ull) {
                        alive &= ~rdlane64(Dcur, j);
                        dm &= alive;              // pruned: suppressed rows can't suppress
                    }
                }
            }
            if (lane == 0) sKeepArr[c] = alive;   // publish (DS write, in-order vs gathers)
            // ---- incoming for chunk c+1: one combined wor32 (old via Kw, late via alive) ----
            u64 m = 0;
            if ((u32)lane < cntn) {
                u64 kw2 = (sch == (u32)c) ? alive : Kw;
                if ((kw2 >> (sidx & 63u)) & 1ull) m = Ea.y;
            }
            u32 lo = wor32((u32)m);
            u32 hi = wor32((u32)(m >> 32));
            u64 incn = ((u64)rdl32(hi, 63) << 32) | (u64)rdl32(lo, 63);
            if (cntn > (u32)EC) {                 // rare tail beyond LDS-staged entries
                u64 mt = 0;
                for (u32 e = (u32)EC + (u32)lane; e < cntn; e += 64u) {
                    ulonglong2 Et = tpack[(size_t)cn * CAP + e];
                    u32 si = (u32)Et.x;
                    u32 sc2 = si >> 6;
                    u64 kw3 = (sc2 == (u32)c) ? alive : sKeepArr[sc2];
                    if ((kw3 >> (si & 63u)) & 1ull) mt |= Et.y;
                }
                lo = wor32((u32)mt);
                hi = wor32((u32)(mt >> 32));
                incn |= ((u64)rdl32(hi, 63) << 32) | (u64)rdl32(lo, 63);
            }
            inc = incn;
            // rotate
            Ea = Eb; Dcur = Dnx; Dnx = Dnn;
            vw = vwn; dmw = dmn; cntn = cntn2;
        }
    }
    __syncthreads();
    // ---- fused output phase (all 1024 threads) ----
    if (t < NCH) pc[t + 1] = (u32)__popcll(sKeepArr[t]);
    if (t == 0) pc[0] = 0;
    __syncthreads();
    for (int ofs = 1; ofs < NCH; ofs <<= 1) {   // Hillis-Steele inclusive scan over pc[1..NCH]
        int i = t + 1;
        u32 v = 0;
        bool p = (t < NCH) && (i - ofs >= 1);
        if (p) v = pc[i - ofs];
        __syncthreads();
        if (p) pc[i] += v;
        __syncthreads();
    }
    u32 nk = pc[NCH];
    for (int i = t; i < K_TOT; i += 1024) {
        int wi = i >> 6, b = i & 63;
        u64 kw = sKeepArr[wi];
        u32 kb = pc[wi] + (u32)__popcll(kw & ((1ull << b) - 1ull));
        bool kp = (kw >> b) & 1ull;
        if (kp) {
            if (kb < 1000u) {
                float4 bx = sB[i];
                out[kb * 4 + 0] = bx.x; out[kb * 4 + 1] = bx.y;
                out[kb * 4 + 2] = bx.z; out[kb * 4 + 3] = bx.w;
                out[4000 + kb] = sS[i];
            }
        } else {
            u32 q = (u32)i - kb;
            u32 slot = nk + q;
            if (slot < 1000u) {
                float4 bx = sB[i];
                out[slot * 4 + 0] = bx.x; out[slot * 4 + 1] = bx.y;
                out[slot * 4 + 2] = bx.z; out[slot * 4 + 3] = bx.w;
                out[4000 + slot] = -INFINITY;
            }
        }
    }
}

// ---------------- workspace layout ----------------
static constexpr size_t al256(size_t x) { return (x + 255) & ~(size_t)255; }
static constexpr size_t KB4 = (size_t)K_TOT * 4;
static constexpr size_t KB16 = (size_t)K_TOT * 16;
// zeroed region:
static constexpr size_t O_RANK = 0;
static constexpr size_t O_PRAW = al256(O_RANK + KB4);
static constexpr size_t O_ECNT = al256(O_PRAW + KB4);
static constexpr size_t O_HIST = al256(O_ECNT + (size_t)NCH * 4);
static constexpr size_t O_CGT = al256(O_HIST + (size_t)3 * 2048 * 4);
static constexpr size_t O_GCNT = al256(O_CGT + 3 * 4);
static constexpr size_t MEMSET_BYTES = al256(O_GCNT + 3 * 4);
// non-zeroed region:
static constexpr size_t O_TINFO = MEMSET_BYTES;
static constexpr size_t O_SEL = al256(O_TINFO + 6 * 4);
static constexpr size_t O_GIDX = al256(O_SEL + KB4);
static constexpr size_t O_GKEY = al256(O_GIDX + (size_t)3 * GCAP * 4);
static constexpr size_t O_CANDB = al256(O_GKEY + (size_t)3 * GCAP * 4);
static constexpr size_t O_CANDS = al256(O_CANDB + KB16);
static constexpr size_t O_CANDV = al256(O_CANDS + KB4);
static constexpr size_t O_CANDA = al256(O_CANDV + KB4);
static constexpr size_t O_SB = al256(O_CANDA + KB4);
static constexpr size_t O_SAREA = al256(O_SB + KB16);
static constexpr size_t O_SS = al256(O_SAREA + KB4);
static constexpr size_t O_SV = al256(O_SS + KB4);
static constexpr size_t O_VW = al256(O_SV + KB4);
static constexpr size_t O_DMASK = al256(O_VW + (size_t)NCH * 8);
static constexpr size_t O_DIAG = al256(O_DMASK + (size_t)NCH * 8);
static constexpr size_t O_EPACK = al256(O_DIAG + (size_t)(NCH * 64) * 8);

extern "C" void kernel_launch(void* const* d_in, const int* in_sizes, int n_in,
                              void* d_out, int out_size, void* d_ws, size_t ws_size,
                              hipStream_t stream) {
    const float* scores = (const float*)d_in[0];
    const float4* deltas = (const float4*)d_in[1];
    const float4* anchors = (const float4*)d_in[2];
    float* out = (float*)d_out;
    char* ws = (char*)d_ws;

    u32* rank = (u32*)(ws + O_RANK);
    u32* Praw = (u32*)(ws + O_PRAW);
    u32* ecnt = (u32*)(ws + O_ECNT);
    u32* hist3 = (u32*)(ws + O_HIST);
    u32* cgt = (u32*)(ws + O_CGT);
    u32* gcnt = (u32*)(ws + O_GCNT);
    u32* tinfo = (u32*)(ws + O_TINFO);
    u32* sel = (u32*)(ws + O_SEL);
    u32* gidx = (u32*)(ws + O_GIDX);
    u32* gkey = (u32*)(ws + O_GKEY);
    float4* candB = (float4*)(ws + O_CANDB);
    float* candS = (float*)(ws + O_CANDS);
    u32* candV = (u32*)(ws + O_CANDV);
    u32* candA = (u32*)(ws + O_CANDA);
    float4* sB = (float4*)(ws + O_SB);
    float* sArea = (float*)(ws + O_SAREA);
    float* sS = (float*)(ws + O_SS);
    u32* sV = (u32*)(ws + O_SV);
    u64* vwords = (u64*)(ws + O_VW);
    u64* dmask = (u64*)(ws + O_DMASK);
    u64* diag = (u64*)(ws + O_DIAG);
    ulonglong2* epack = (ulonglong2*)(ws + O_EPACK);

    hipMemsetAsync(ws, 0, MEMSET_BYTES, stream);

    const int NBLK = (K_TOT + 255) / 256;  // 33
    k_hist<<<156, 1024, 0, stream>>>(scores, hist3);
    k_thresh<<<3, 1024, 0, stream>>>(hist3, tinfo);
    k_gather<<<159, 1024, 0, stream>>>(scores, tinfo, sel, cgt, gcnt, gidx, gkey);
    k_final<<<3, 1024, 0, stream>>>(gidx, gkey, gcnt, tinfo, sel);
    k_decode<<<NBLK, 256, 0, stream>>>(scores, deltas, anchors, sel, candB, candS, candV, candA);
    k_rank_lvl<<<dim3(8, 8, 5), 256, 0, stream>>>(candS, candA, Praw);
    k_rank_glob<<<dim3(NBLK, NBLK), 256, 0, stream>>>(candS, candV, Praw, rank);
    k_scatter<<<NBLK, 256, 0, stream>>>(candB, candS, candV, rank, sB, sArea, sS, sV);
    k_mask<<<dim3(NCH, NBLK), 256, 0, stream>>>(sB, sArea, sV, vwords, diag, ecnt, epack, dmask);
    k_scan<<<1, 1024, 0, stream>>>(diag, vwords, ecnt, epack, dmask, sB, sS, out);
}

// Round 6
// 210.343 us; speedup vs baseline: 1.0843x; 1.0123x over previous
//
#include <hip/hip_runtime.h>
#include <math.h>

typedef unsigned int u32;
typedef unsigned long long u64;
typedef unsigned char u8;

#define K_TOT 8382
#define NCH 131      // 131 chunks of 64 rows
#define CAP 1024     // per-TARGET-chunk off-diag entry capacity (global)
#define GCAP 32768   // per-level threshold-bin candidate capacity
#define IMGSZ 800.0f

__device__ __constant__ int LOFF[5] = {0, 120000, 150000, 157500, 159375};
__device__ __constant__ int LCNT[5] = {120000, 30000, 7500, 1875, 507};
__device__ __constant__ int KSEL[5] = {2000, 2000, 2000, 1875, 507};
__device__ __constant__ int SELB[5] = {0, 2000, 4000, 6000, 7875};
__device__ __constant__ int HBS[4] = {0, 118, 148, 156};    // k_hist block starts (levels 0..2)
__device__ __constant__ int GBS[6] = {0, 118, 148, 156, 158, 159};  // k_gather block starts

static __device__ __forceinline__ u32 fkey(float x) {
    u32 u = __float_as_uint(x);
    u32 m = (u32)(((int)u) >> 31) | 0x80000000u;
    return u ^ m;
}

static __device__ __forceinline__ int lvl_of(int s) {
    return (s < 2000) ? 0 : (s < 4000) ? 1 : (s < 6000) ? 2 : (s < 7875) ? 3 : 4;
}

// scalar-path readlanes (uniform lane index -> v_readlane)
static __device__ __forceinline__ u32 rdl32(u32 v, int j) {
    return (u32)__builtin_amdgcn_readlane((int)v, j);
}
static __device__ __forceinline__ u64 rdlane64(u64 v, int j) {
    u32 lo = (u32)__builtin_amdgcn_readlane((int)(u32)v, j);
    u32 hi = (u32)__builtin_amdgcn_readlane((int)(u32)(v >> 32), j);
    return ((u64)hi << 32) | (u64)lo;
}

// wave64 OR-reduce via DPP (row_shr 1/2/4/8 + bcast15 + bcast31); result in lane 63
static __device__ __forceinline__ u32 wor32(u32 x) {
    x |= (u32)__builtin_amdgcn_update_dpp(0, (int)x, 0x111, 0xf, 0xf, true);
    x |= (u32)__builtin_amdgcn_update_dpp(0, (int)x, 0x112, 0xf, 0xf, true);
    x |= (u32)__builtin_amdgcn_update_dpp(0, (int)x, 0x114, 0xf, 0xf, true);
    x |= (u32)__builtin_amdgcn_update_dpp(0, (int)x, 0x118, 0xf, 0xf, true);
    x |= (u32)__builtin_amdgcn_update_dpp(0, (int)x, 0x142, 0xa, 0xf, true);
    x |= (u32)__builtin_amdgcn_update_dpp(0, (int)x, 0x143, 0xc, 0xf, true);
    return x;
}

// Parallel reverse-inclusive scan over hist[0..m-1] (from top bin down);
// finds bin with suffix-cum >= need. Out: sv[0]=bin, sv[1]=remaining ties to take.
static __device__ __forceinline__ void thresh_scan(const u32* hist, u32* scanbuf, int m,
                                                   u32 need, u32* sv, int t) {
    for (int i = t; i < m; i += 1024) scanbuf[i] = hist[m - 1 - i];
    __syncthreads();
    for (int ofs = 1; ofs < m; ofs <<= 1) {
        int i0 = t, i1 = t + 1024;
        u32 a0 = 0, a1 = 0;
        if (i0 < m && i0 >= ofs) a0 = scanbuf[i0 - ofs];
        if (i1 < m && i1 >= ofs) a1 = scanbuf[i1 - ofs];
        __syncthreads();
        if (i0 < m && i0 >= ofs) scanbuf[i0] += a0;
        if (i1 < m && i1 >= ofs) scanbuf[i1] += a1;
        __syncthreads();
    }
    for (int i = t; i < m; i += 1024) {
        u32 inc = scanbuf[i];
        u32 exc = i ? scanbuf[i - 1] : 0;
        if (inc >= need && exc < need) { sv[0] = (u32)(m - 1 - i); sv[1] = need - exc; }
    }
    __syncthreads();
}

// ---------------- K1a: parallel coarse histogram (top 11 key bits), levels 0..2 ----------------
__global__ __launch_bounds__(1024) void k_hist(const float* __restrict__ scores,
                                               u32* __restrict__ hist3) {
    __shared__ u32 lh[2048];
    int t = threadIdx.x;
    lh[t] = 0; lh[t + 1024] = 0;
    __syncthreads();
    int b = blockIdx.x;
    int l = (b < HBS[1]) ? 0 : (b < HBS[2]) ? 1 : 2;
    int i = (b - HBS[l]) * 1024 + t;
    if (i < LCNT[l]) atomicAdd(&lh[fkey(scores[LOFF[l] + i]) >> 21], 1u);
    __syncthreads();
    u32* h = hist3 + l * 2048;
    if (lh[t]) atomicAdd(&h[t], lh[t]);
    if (lh[t + 1024]) atomicAdd(&h[t + 1024], lh[t + 1024]);
}

// ---------------- K1b: coarse threshold per level ----------------
__global__ __launch_bounds__(1024) void k_thresh(const u32* __restrict__ hist3,
                                                 u32* __restrict__ tinfo) {
    __shared__ u32 scanbuf[2048];
    __shared__ u32 sv[2];
    int l = blockIdx.x;
    int t = threadIdx.x;
    thresh_scan(hist3 + l * 2048, scanbuf, 2048, (u32)KSEL[l], sv, t);
    if (t == 0) { tinfo[l * 2] = sv[0]; tinfo[l * 2 + 1] = sv[1]; }
}

// ---------------- K1c: classify; strict-greater -> sel, threshold-bin -> candidate buf ----------------
__global__ __launch_bounds__(1024) void k_gather(const float* __restrict__ scores,
                                                 const u32* __restrict__ tinfo,
                                                 u32* __restrict__ sel, u32* __restrict__ cgt,
                                                 u32* __restrict__ gcnt, u32* __restrict__ gidx,
                                                 u32* __restrict__ gkey) {
    int b = blockIdx.x;
    int l = (b < GBS[1]) ? 0 : (b < GBS[2]) ? 1 : (b < GBS[3]) ? 2 : (b < GBS[4]) ? 3 : 4;
    int i = (b - GBS[l]) * 1024 + threadIdx.x;
    if (i >= LCNT[l]) return;
    int off = LOFF[l], sb = SELB[l];
    if (l >= 3) { sel[sb + i] = (u32)(off + i); return; }  // take-all levels
    u32 ky = fkey(scores[off + i]);
    u32 b1 = tinfo[l * 2];
    u32 top = ky >> 21;
    if (top > b1) {
        u32 p = atomicAdd(&cgt[l], 1u);
        sel[sb + p] = (u32)(off + i);          // set membership only; order fixed by P later
    } else if (top == b1) {
        u32 e = atomicAdd(&gcnt[l], 1u);
        if (e < GCAP) { gidx[l * GCAP + e] = (u32)i; gkey[l * GCAP + e] = ky; }
    }
}

// ---------------- K1d: exact refine within threshold bin (mid 11 + low 10 bits) ----------------
__global__ __launch_bounds__(1024) void k_final(const u32* __restrict__ gidx,
                                                const u32* __restrict__ gkey,
                                                const u32* __restrict__ gcnt,
                                                const u32* __restrict__ tinfo,
                                                u32* __restrict__ sel) {
    __shared__ u32 hist[2048];
    __shared__ u32 scanbuf[2048];
    __shared__ u32 eqbuf[1024];
    __shared__ u32 sv[2];
    __shared__ u32 c2, ceq;
    int l = blockIdx.x;
    int t = threadIdx.x;
    int k = KSEL[l], sb = SELB[l], off = LOFF[l];
    u32 m = gcnt[l]; if (m > GCAP) m = GCAP;
    u32 b1 = tinfo[l * 2];
    u32 need = tinfo[l * 2 + 1];
    const u32* kb = gkey + l * GCAP;
    const u32* ib = gidx + l * GCAP;
    // mid 11 bits
    hist[t] = 0; hist[t + 1024] = 0; __syncthreads();
    for (u32 e = t; e < m; e += 1024) atomicAdd(&hist[(kb[e] >> 10) & 2047u], 1u);
    __syncthreads();
    thresh_scan(hist, scanbuf, 2048, need, sv, t);
    u32 b2 = sv[0], need2 = sv[1];
    __syncthreads();
    // low 10 bits
    hist[t] = 0; __syncthreads();
    for (u32 e = t; e < m; e += 1024) {
        u32 ky = kb[e];
        if (((ky >> 10) & 2047u) == b2) atomicAdd(&hist[ky & 1023u], 1u);
    }
    __syncthreads();
    thresh_scan(hist, scanbuf, 1024, need2, sv, t);
    u32 T = (b1 << 21) | (b2 << 10) | sv[0];
    u32 take = sv[1];
    if (t == 0) { c2 = 0; ceq = 0; }
    __syncthreads();
    u32 nGTbin = need - take;
    u32 base2 = (u32)sb + (u32)k - need;   // after strict-greater-bin entries
    for (u32 e = t; e < m; e += 1024) {
        u32 ky = kb[e];
        if (ky > T) { u32 p = atomicAdd(&c2, 1u); sel[base2 + p] = (u32)off + ib[e]; }
        else if (ky == T) { u32 q = atomicAdd(&ceq, 1u); if (q < 1024) eqbuf[q] = ib[e]; }
    }
    __syncthreads();
    if (t == 0) {
        int n = (ceq > 1024u) ? 1024 : (int)ceq;
        for (int a = 1; a < n; ++a) {  // ascending insertion sort; tie count tiny
            u32 v = eqbuf[a]; int bq = a - 1;
            while (bq >= 0 && eqbuf[bq] > v) { eqbuf[bq + 1] = eqbuf[bq]; --bq; }
            eqbuf[bq + 1] = v;
        }
        for (u32 q = 0; q < take; ++q) sel[base2 + nGTbin + q] = (u32)off + eqbuf[q];
    }
}

// ---------------- K2: decode selected boxes (exact reference op order) ----------------
__global__ void k_decode(const float* __restrict__ scores, const float4* __restrict__ deltas,
                         const float4* __restrict__ anchors, const u32* __restrict__ sel,
                         float4* __restrict__ candB, float* __restrict__ candS,
                         u32* __restrict__ candV, u32* __restrict__ candA) {
    int s = blockIdx.x * 256 + threadIdx.x;
    if (s >= K_TOT) return;
    u32 a = sel[s];
    float4 an = anchors[a];
    float4 dl = deltas[a];
    float sc = scores[a];
    float w = __fsub_rn(an.z, an.x), h = __fsub_rn(an.w, an.y);
    float cx = __fadd_rn(an.x, __fmul_rn(0.5f, w));
    float cy = __fadd_rn(an.y, __fmul_rn(0.5f, h));
    const float CLIPV = (float)4.1351665567423563;  // log(1000/16) as f32
    float dw = fminf(dl.z, CLIPV);
    float dh = fminf(dl.w, CLIPV);
    float px = __fadd_rn(cx, __fmul_rn(dl.x, w));
    float py = __fadd_rn(cy, __fmul_rn(dl.y, h));
    float pw = __fmul_rn((float)exp((double)dw), w);
    float ph = __fmul_rn((float)exp((double)dh), h);
    float x1 = __fsub_rn(px, __fmul_rn(0.5f, pw));
    float y1 = __fsub_rn(py, __fmul_rn(0.5f, ph));
    float x2 = __fadd_rn(px, __fmul_rn(0.5f, pw));
    float y2 = __fadd_rn(py, __fmul_rn(0.5f, ph));
    x1 = fminf(fmaxf(x1, 0.0f), IMGSZ);
    y1 = fminf(fmaxf(y1, 0.0f), IMGSZ);
    x2 = fminf(fmaxf(x2, 0.0f), IMGSZ);
    y2 = fminf(fmaxf(y2, 0.0f), IMGSZ);
    bool valid = (__fsub_rn(x2, x1) >= 0.001f) && (__fsub_rn(y2, y1) >= 0.001f);
    candB[s] = make_float4(x1, y1, x2, y2);
    candS[s] = sc;
    candV[s] = valid ? 1u : 0u;
    candA[s] = a;
}

// ---------------- K3a: within-level rank (tiled pairwise count) ----------------
__global__ __launch_bounds__(256) void k_rank_lvl(const float* __restrict__ candS,
                                                  const u32* __restrict__ candA,
                                                  u32* __restrict__ Praw) {
    __shared__ u64 tile[256];
    int l = blockIdx.z;
    int cnt = KSEL[l], base = SELB[l];
    int tx = blockIdx.x * 256;
    int ty = blockIdx.y * 256;
    if (tx >= cnt || ty >= cnt) return;
    int t = threadIdx.x;
    u64 Aj = ~0ull;  // sentinel: never < any real key
    if (tx + t < cnt) {
        int j = base + tx + t;
        Aj = ((u64)(~fkey(candS[j])) << 32) | (u64)candA[j];
    }
    tile[t] = Aj;
    __syncthreads();
    int si = ty + t;
    if (si >= cnt) return;
    int s = base + si;
    u64 A = ((u64)(~fkey(candS[s])) << 32) | (u64)candA[s];
    int r = 0;
#pragma unroll 8
    for (int q = 0; q < 256; ++q) r += (tile[q] < A);
    if (r) atomicAdd(&Praw[s], (u32)r);
}

// ---------------- K3b: global rank by (masked score desc, position asc) ----------------
__global__ __launch_bounds__(256) void k_rank_glob(const float* __restrict__ candS,
                                                   const u32* __restrict__ candV,
                                                   const u32* __restrict__ Praw,
                                                   u32* __restrict__ rank) {
    __shared__ u64 colB[256];
    int t = threadIdx.x;
    int cj = blockIdx.x * 256 + t;
    u64 B = ~0ull;
    if (cj < K_TOT) {
        u32 smk = candV[cj] ? fkey(candS[cj]) : 0x007FFFFFu;  // fkey(-inf)
        u32 Pj = (u32)SELB[lvl_of(cj)] + Praw[cj];
        B = ((u64)(~smk) << 32) | (u64)Pj;
    }
    colB[t] = B;
    __syncthreads();
    int s = blockIdx.y * 256 + t;
    if (s >= K_TOT) return;
    u32 smk = candV[s] ? fkey(candS[s]) : 0x007FFFFFu;
    u32 Ps = (u32)SELB[lvl_of(s)] + Praw[s];
    u64 myB = ((u64)(~smk) << 32) | (u64)Ps;
    int cnt = 0;
#pragma unroll 8
    for (int j = 0; j < 256; ++j) cnt += (colB[j] < myB);
    if (cnt) atomicAdd(&rank[s], (u32)cnt);
}

// ---------------- K4: scatter into sorted order ----------------
// Reference's fmask slice is all zeros -> NMS on raw clipped boxes (no level offsets).
__global__ void k_scatter(const float4* __restrict__ candB, const float* __restrict__ candS,
                          const u32* __restrict__ candV, const u32* __restrict__ rank,
                          float4* __restrict__ sB, float* __restrict__ sArea,
                          float* __restrict__ sS, u32* __restrict__ sV) {
    int s = blockIdx.x * 256 + threadIdx.x;
    if (s >= K_TOT) return;
    u32 r = rank[s];
    float4 b = candB[s];
    float area = __fmul_rn(__fsub_rn(b.z, b.x), __fsub_rn(b.w, b.y));
    sB[r] = b; sArea[r] = area; sS[r] = candS[s]; sV[r] = candV[s];
}

// ---------------- K5: suppression bits -> packed entry lists (+ vwords/dmask ballots) ----------------
// off-diag: bucketed by TARGET chunk, 16B entries {src_row, bits}  (pull model).
// diag (intra-chunk): full diag[] row words; dmask via wave ballot (no atomics).
__global__ __launch_bounds__(256) void k_mask(const float4* __restrict__ sB,
                                              const float* __restrict__ sArea,
                                              const u32* __restrict__ sV,
                                              u64* __restrict__ vwords,
                                              u64* __restrict__ diag, u32* __restrict__ ecnt,
                                              ulonglong2* __restrict__ epack,
                                              u64* __restrict__ dmask) {
    __shared__ float4 cb[64];
    __shared__ float ca[64];
    int wd = blockIdx.x;   // target word (column chunk)
    int t = threadIdx.x;
    if (t < 64) {
        int j = wd * 64 + t;
        if (j < K_TOT) { cb[t] = sB[j]; ca[t] = sArea[j]; }
        else { cb[t] = make_float4(0.f, 0.f, 0.f, 0.f); ca[t] = 0.f; }
    }
    __syncthreads();
    int i = blockIdx.y * 256 + t;
    if (i >= K_TOT) return;
    int dwr = i >> 6;              // wave-uniform (i spans one aligned 64-row band per wave)
    if (wd < dwr) return;          // strictly upper-triangular
    float4 bi = sB[i];
    float ai = sArea[i];
    u64 bits = 0;
    int jbase = wd * 64;
    for (int j2 = 0; j2 < 64; ++j2) {
        int j = jbase + j2;
        if (j > i && j < K_TOT) {
            float4 bj = cb[j2];
            float ltx = fmaxf(bi.x, bj.x), lty = fmaxf(bi.y, bj.y);
            float rbx = fminf(bi.z, bj.z), rby = fminf(bi.w, bj.w);
            float wx = fmaxf(__fsub_rn(rbx, ltx), 0.0f);
            float wy = fmaxf(__fsub_rn(rby, lty), 0.0f);
            float inter = __fmul_rn(wx, wy);
            if (inter > 0.0f) {
                float uni = __fsub_rn(__fadd_rn(ai, ca[j2]), inter);
                float iou = inter / uni;  // IEEE f32 div, matches reference
                if (iou > 0.7f) bits |= (1ull << j2);
            }
        }
    }
    if (wd == dwr) {
        diag[i] = bits;                          // per-row intra-chunk suppressor word
        u64 vb = __ballot(sV[i] != 0u);          // wave-uniform branch: safe ballots
        u64 db = __ballot(bits != 0ull);
        if ((i & 63) == 0) { vwords[wd] = vb; dmask[wd] = db; }
    } else if (bits != 0ull) {
        u32 p = atomicAdd(&ecnt[wd], 1u);        // bucket by TARGET chunk (pull model)
        if (p < CAP) epack[wd * CAP + p] = make_ulonglong2((u64)i, bits);
    }
}

// ---------------- K6: 16-wave PIPELINED NMS scan (pull model) + fused output ----------------
// Wave w owns chunks w, w+16, ... Each wave pre-stages its chunk's entries/diag/scalars
// from GLOBAL (latency hidden by the wait), then spin-polls the LDS progress counter with
// acquire loads, folding each entry's source-aliveness as soon as that source resolves.
// When progress == c only {wor32 -> alive -> dm loop -> release-publish} remain. Exact:
// dependencies are strictly forward; result is timing-independent. Release/acquire
// (workgroup scope) orders sKeepArr writes vs. reads. No LDS staging phase at all.
__global__ __launch_bounds__(1024) void k_scan(const u64* __restrict__ diag,
                                               const u64* __restrict__ vwords,
                                               const u32* __restrict__ ecnt,
                                               const ulonglong2* __restrict__ tpack,
                                               const u64* __restrict__ dmask,
                                               const float4* __restrict__ sB,
                                               const float* __restrict__ sS,
                                               float* __restrict__ out) {
    __shared__ u64 sKeepArr[NCH];
    __shared__ u32 pc[NCH + 1];
    __shared__ u32 sProg;
    int t = threadIdx.x;
    int w = t >> 6, lane = t & 63;
    if (t == 0) sProg = 0;
    __syncthreads();
    for (int c = w; c < NCH; c += 16) {
        // ---- pre-stage from global (hidden under the pipeline wait) ----
        ulonglong2 E1 = tpack[(size_t)c * CAP + lane];
        ulonglong2 E2 = tpack[(size_t)c * CAP + 64 + lane];
        u64 Dc = diag[c * 64 + lane];
        u64 vw = vwords[c];
        u64 dmw = dmask[c];
        u32 cnt = ecnt[c]; if (cnt > CAP) cnt = CAP;
        u32 s1 = (u32)E1.x, s2 = (u32)E2.x;
        u32 sch1 = s1 >> 6, sch2 = s2 >> 6;
        u64 mbits = 0;
        bool done1 = ((u32)lane >= cnt);
        bool done2 = ((u32)(lane + 64) >= cnt);
        // ---- wait + opportunistic fold ----
        if (c > 0) {
            for (;;) {
                u32 p = __hip_atomic_load(&sProg, __ATOMIC_ACQUIRE, __HIP_MEMORY_SCOPE_WORKGROUP);
                if (!done1 && sch1 < p) {
                    u64 kw = sKeepArr[sch1];
                    if ((kw >> (s1 & 63u)) & 1ull) mbits |= E1.y;
                    done1 = true;
                }
                if (!done2 && sch2 < p) {
                    u64 kw = sKeepArr[sch2];
                    if ((kw >> (s2 & 63u)) & 1ull) mbits |= E2.y;
                    done2 = true;
                }
                if (p >= (u32)c) break;
            }
        }
        // ---- resolve chunk c ----
        u64 inc = 0;
        if (cnt) {
            if (cnt > 128u) {   // rare tail beyond the two prefetched entry banks
                for (u32 e = 128u + (u32)lane; e < cnt; e += 64u) {
                    ulonglong2 Et = tpack[(size_t)c * CAP + e];
                    u32 si = (u32)Et.x;
                    if ((sKeepArr[si >> 6] >> (si & 63u)) & 1ull) mbits |= Et.y;
                }
            }
            u32 lo = wor32((u32)mbits);
            u32 hi = wor32((u32)(mbits >> 32));
            inc = ((u64)rdl32(hi, 63) << 32) | (u64)rdl32(lo, 63);
        }
        u64 alive = vw & ~inc;
        if (dmw) {
            u64 dm = dmw & alive;
            while (dm) {
                int j = __builtin_ctzll(dm);
                dm &= dm - 1;
                if ((alive >> j) & 1ull) {
                    alive &= ~rdlane64(Dc, j);
                    dm &= alive;              // suppressed rows can't suppress
                }
            }
        }
        if (lane == 0) {
            sKeepArr[c] = alive;
            __hip_atomic_store(&sProg, (u32)(c + 1), __ATOMIC_RELEASE, __HIP_MEMORY_SCOPE_WORKGROUP);
        }
    }
    __syncthreads();
    // ---- fused output phase (all 1024 threads) ----
    if (t < NCH) pc[t + 1] = (u32)__popcll(sKeepArr[t]);
    if (t == 0) pc[0] = 0;
    __syncthreads();
    for (int ofs = 1; ofs < NCH; ofs <<= 1) {   // Hillis-Steele inclusive scan over pc[1..NCH]
        int i = t + 1;
        u32 v = 0;
        bool p = (t < NCH) && (i - ofs >= 1);
        if (p) v = pc[i - ofs];
        __syncthreads();
        if (p) pc[i] += v;
        __syncthreads();
    }
    u32 nk = pc[NCH];
    for (int i = t; i < K_TOT; i += 1024) {
        int wi = i >> 6, b = i & 63;
        u64 kw = sKeepArr[wi];
        u32 kb = pc[wi] + (u32)__popcll(kw & ((1ull << b) - 1ull));
        bool kp = (kw >> b) & 1ull;
        if (kp) {
            if (kb < 1000u) {
                float4 bx = sB[i];
                out[kb * 4 + 0] = bx.x; out[kb * 4 + 1] = bx.y;
                out[kb * 4 + 2] = bx.z; out[kb * 4 + 3] = bx.w;
                out[4000 + kb] = sS[i];
            }
        } else {
            u32 q = (u32)i - kb;
            u32 slot = nk + q;
            if (slot < 1000u) {
                float4 bx = sB[i];
                out[slot * 4 + 0] = bx.x; out[slot * 4 + 1] = bx.y;
                out[slot * 4 + 2] = bx.z; out[slot * 4 + 3] = bx.w;
                out[4000 + slot] = -INFINITY;
            }
        }
    }
}

// ---------------- workspace layout ----------------
static constexpr size_t al256(size_t x) { return (x + 255) & ~(size_t)255; }
static constexpr size_t KB4 = (size_t)K_TOT * 4;
static constexpr size_t KB16 = (size_t)K_TOT * 16;
// zeroed region:
static constexpr size_t O_RANK = 0;
static constexpr size_t O_PRAW = al256(O_RANK + KB4);
static constexpr size_t O_ECNT = al256(O_PRAW + KB4);
static constexpr size_t O_HIST = al256(O_ECNT + (size_t)NCH * 4);
static constexpr size_t O_CGT = al256(O_HIST + (size_t)3 * 2048 * 4);
static constexpr size_t O_GCNT = al256(O_CGT + 3 * 4);
static constexpr size_t MEMSET_BYTES = al256(O_GCNT + 3 * 4);
// non-zeroed region:
static constexpr size_t O_TINFO = MEMSET_BYTES;
static constexpr size_t O_SEL = al256(O_TINFO + 6 * 4);
static constexpr size_t O_GIDX = al256(O_SEL + KB4);
static constexpr size_t O_GKEY = al256(O_GIDX + (size_t)3 * GCAP * 4);
static constexpr size_t O_CANDB = al256(O_GKEY + (size_t)3 * GCAP * 4);
static constexpr size_t O_CANDS = al256(O_CANDB + KB16);
static constexpr size_t O_CANDV = al256(O_CANDS + KB4);
static constexpr size_t O_CANDA = al256(O_CANDV + KB4);
static constexpr size_t O_SB = al256(O_CANDA + KB4);
static constexpr size_t O_SAREA = al256(O_SB + KB16);
static constexpr size_t O_SS = al256(O_SAREA + KB4);
static constexpr size_t O_SV = al256(O_SS + KB4);
static constexpr size_t O_VW = al256(O_SV + KB4);
static constexpr size_t O_DMASK = al256(O_VW + (size_t)NCH * 8);
static constexpr size_t O_DIAG = al256(O_DMASK + (size_t)NCH * 8);
static constexpr size_t O_EPACK = al256(O_DIAG + (size_t)(NCH * 64) * 8);

extern "C" void kernel_launch(void* const* d_in, const int* in_sizes, int n_in,
                              void* d_out, int out_size, void* d_ws, size_t ws_size,
                              hipStream_t stream) {
    const float* scores = (const float*)d_in[0];
    const float4* deltas = (const float4*)d_in[1];
    const float4* anchors = (const float4*)d_in[2];
    float* out = (float*)d_out;
    char* ws = (char*)d_ws;

    u32* rank = (u32*)(ws + O_RANK);
    u32* Praw = (u32*)(ws + O_PRAW);
    u32* ecnt = (u32*)(ws + O_ECNT);
    u32* hist3 = (u32*)(ws + O_HIST);
    u32* cgt = (u32*)(ws + O_CGT);
    u32* gcnt = (u32*)(ws + O_GCNT);
    u32* tinfo = (u32*)(ws + O_TINFO);
    u32* sel = (u32*)(ws + O_SEL);
    u32* gidx = (u32*)(ws + O_GIDX);
    u32* gkey = (u32*)(ws + O_GKEY);
    float4* candB = (float4*)(ws + O_CANDB);
    float* candS = (float*)(ws + O_CANDS);
    u32* candV = (u32*)(ws + O_CANDV);
    u32* candA = (u32*)(ws + O_CANDA);
    float4* sB = (float4*)(ws + O_SB);
    float* sArea = (float*)(ws + O_SAREA);
    float* sS = (float*)(ws + O_SS);
    u32* sV = (u32*)(ws + O_SV);
    u64* vwords = (u64*)(ws + O_VW);
    u64* dmask = (u64*)(ws + O_DMASK);
    u64* diag = (u64*)(ws + O_DIAG);
    ulonglong2* epack = (ulonglong2*)(ws + O_EPACK);

    hipMemsetAsync(ws, 0, MEMSET_BYTES, stream);

    const int NBLK = (K_TOT + 255) / 256;  // 33
    k_hist<<<156, 1024, 0, stream>>>(scores, hist3);
    k_thresh<<<3, 1024, 0, stream>>>(hist3, tinfo);
    k_gather<<<159, 1024, 0, stream>>>(scores, tinfo, sel, cgt, gcnt, gidx, gkey);
    k_final<<<3, 1024, 0, stream>>>(gidx, gkey, gcnt, tinfo, sel);
    k_decode<<<NBLK, 256, 0, stream>>>(scores, deltas, anchors, sel, candB, candS, candV, candA);
    k_rank_lvl<<<dim3(8, 8, 5), 256, 0, stream>>>(candS, candA, Praw);
    k_rank_glob<<<dim3(NBLK, NBLK), 256, 0, stream>>>(candS, candV, Praw, rank);
    k_scatter<<<NBLK, 256, 0, stream>>>(candB, candS, candV, rank, sB, sArea, sS, sV);
    k_mask<<<dim3(NCH, NBLK), 256, 0, stream>>>(sB, sArea, sV, vwords, diag, ecnt, epack, dmask);
    k_scan<<<1, 1024, 0, stream>>>(diag, vwords, ecnt, epack, dmask, sB, sS, out);
}

// Round 7
// 209.188 us; speedup vs baseline: 1.0903x; 1.0055x over previous
//
#include <hip/hip_runtime.h>
#include <math.h>

typedef unsigned int u32;
typedef unsigned long long u64;
typedef unsigned char u8;

#define K_TOT 8382
#define NCH 131      // 131 chunks of 64 rows
#define CAP 1024     // per-TARGET-chunk off-diag entry capacity (global)
#define GCAP 32768   // per-level threshold-bin candidate capacity
#define IMGSZ 800.0f

__device__ __constant__ int LOFF[5] = {0, 120000, 150000, 157500, 159375};
__device__ __constant__ int LCNT[5] = {120000, 30000, 7500, 1875, 507};
__device__ __constant__ int KSEL[5] = {2000, 2000, 2000, 1875, 507};
__device__ __constant__ int SELB[5] = {0, 2000, 4000, 6000, 7875};
__device__ __constant__ int HBS[4] = {0, 118, 148, 156};    // k_hist block starts (levels 0..2)
__device__ __constant__ int GBS[6] = {0, 118, 148, 156, 158, 159};  // k_gather block starts

static __device__ __forceinline__ u32 fkey(float x) {
    u32 u = __float_as_uint(x);
    u32 m = (u32)(((int)u) >> 31) | 0x80000000u;
    return u ^ m;
}

static __device__ __forceinline__ int lvl_of(int s) {
    return (s < 2000) ? 0 : (s < 4000) ? 1 : (s < 6000) ? 2 : (s < 7875) ? 3 : 4;
}

// scalar-path readlanes (uniform lane index -> v_readlane)
static __device__ __forceinline__ u32 rdl32(u32 v, int j) {
    return (u32)__builtin_amdgcn_readlane((int)v, j);
}
static __device__ __forceinline__ u64 rdlane64(u64 v, int j) {
    u32 lo = (u32)__builtin_amdgcn_readlane((int)(u32)v, j);
    u32 hi = (u32)__builtin_amdgcn_readlane((int)(u32)(v >> 32), j);
    return ((u64)hi << 32) | (u64)lo;
}

// wave64 OR-reduce via DPP (row_shr 1/2/4/8 + bcast15 + bcast31); result in lane 63
static __device__ __forceinline__ u32 wor32(u32 x) {
    x |= (u32)__builtin_amdgcn_update_dpp(0, (int)x, 0x111, 0xf, 0xf, true);
    x |= (u32)__builtin_amdgcn_update_dpp(0, (int)x, 0x112, 0xf, 0xf, true);
    x |= (u32)__builtin_amdgcn_update_dpp(0, (int)x, 0x114, 0xf, 0xf, true);
    x |= (u32)__builtin_amdgcn_update_dpp(0, (int)x, 0x118, 0xf, 0xf, true);
    x |= (u32)__builtin_amdgcn_update_dpp(0, (int)x, 0x142, 0xa, 0xf, true);
    x |= (u32)__builtin_amdgcn_update_dpp(0, (int)x, 0x143, 0xc, 0xf, true);
    return x;
}

// Parallel reverse-inclusive scan over hist[0..m-1] (from top bin down);
// finds bin with suffix-cum >= need. Out: sv[0]=bin, sv[1]=remaining ties to take.
static __device__ __forceinline__ void thresh_scan(const u32* hist, u32* scanbuf, int m,
                                                   u32 need, u32* sv, int t) {
    for (int i = t; i < m; i += 1024) scanbuf[i] = hist[m - 1 - i];
    __syncthreads();
    for (int ofs = 1; ofs < m; ofs <<= 1) {
        int i0 = t, i1 = t + 1024;
        u32 a0 = 0, a1 = 0;
        if (i0 < m && i0 >= ofs) a0 = scanbuf[i0 - ofs];
        if (i1 < m && i1 >= ofs) a1 = scanbuf[i1 - ofs];
        __syncthreads();
        if (i0 < m && i0 >= ofs) scanbuf[i0] += a0;
        if (i1 < m && i1 >= ofs) scanbuf[i1] += a1;
        __syncthreads();
    }
    for (int i = t; i < m; i += 1024) {
        u32 inc = scanbuf[i];
        u32 exc = i ? scanbuf[i - 1] : 0;
        if (inc >= need && exc < need) { sv[0] = (u32)(m - 1 - i); sv[1] = need - exc; }
    }
    __syncthreads();
}

// ---------------- K1a: parallel coarse histogram (top 11 key bits), levels 0..2 ----------------
__global__ __launch_bounds__(1024) void k_hist(const float* __restrict__ scores,
                                               u32* __restrict__ hist3) {
    __shared__ u32 lh[2048];
    int t = threadIdx.x;
    lh[t] = 0; lh[t + 1024] = 0;
    __syncthreads();
    int b = blockIdx.x;
    int l = (b < HBS[1]) ? 0 : (b < HBS[2]) ? 1 : 2;
    int i = (b - HBS[l]) * 1024 + t;
    if (i < LCNT[l]) atomicAdd(&lh[fkey(scores[LOFF[l] + i]) >> 21], 1u);
    __syncthreads();
    u32* h = hist3 + l * 2048;
    if (lh[t]) atomicAdd(&h[t], lh[t]);
    if (lh[t + 1024]) atomicAdd(&h[t + 1024], lh[t + 1024]);
}

// ---------------- K1b: coarse threshold per level ----------------
__global__ __launch_bounds__(1024) void k_thresh(const u32* __restrict__ hist3,
                                                 u32* __restrict__ tinfo) {
    __shared__ u32 scanbuf[2048];
    __shared__ u32 sv[2];
    int l = blockIdx.x;
    int t = threadIdx.x;
    thresh_scan(hist3 + l * 2048, scanbuf, 2048, (u32)KSEL[l], sv, t);
    if (t == 0) { tinfo[l * 2] = sv[0]; tinfo[l * 2 + 1] = sv[1]; }
}

// ---------------- K1c: classify; strict-greater -> sel, threshold-bin -> candidate buf ----------------
__global__ __launch_bounds__(1024) void k_gather(const float* __restrict__ scores,
                                                 const u32* __restrict__ tinfo,
                                                 u32* __restrict__ sel, u32* __restrict__ cgt,
                                                 u32* __restrict__ gcnt, u32* __restrict__ gidx,
                                                 u32* __restrict__ gkey) {
    int b = blockIdx.x;
    int l = (b < GBS[1]) ? 0 : (b < GBS[2]) ? 1 : (b < GBS[3]) ? 2 : (b < GBS[4]) ? 3 : 4;
    int i = (b - GBS[l]) * 1024 + threadIdx.x;
    if (i >= LCNT[l]) return;
    int off = LOFF[l], sb = SELB[l];
    if (l >= 3) { sel[sb + i] = (u32)(off + i); return; }  // take-all levels
    u32 ky = fkey(scores[off + i]);
    u32 b1 = tinfo[l * 2];
    u32 top = ky >> 21;
    if (top > b1) {
        u32 p = atomicAdd(&cgt[l], 1u);
        sel[sb + p] = (u32)(off + i);          // set membership only; order fixed by P later
    } else if (top == b1) {
        u32 e = atomicAdd(&gcnt[l], 1u);
        if (e < GCAP) { gidx[l * GCAP + e] = (u32)i; gkey[l * GCAP + e] = ky; }
    }
}

// ---------------- K1d: exact refine within threshold bin (mid 11 + low 10 bits) ----------------
__global__ __launch_bounds__(1024) void k_final(const u32* __restrict__ gidx,
                                                const u32* __restrict__ gkey,
                                                const u32* __restrict__ gcnt,
                                                const u32* __restrict__ tinfo,
                                                u32* __restrict__ sel) {
    __shared__ u32 hist[2048];
    __shared__ u32 scanbuf[2048];
    __shared__ u32 eqbuf[1024];
    __shared__ u32 sv[2];
    __shared__ u32 c2, ceq;
    int l = blockIdx.x;
    int t = threadIdx.x;
    int k = KSEL[l], sb = SELB[l], off = LOFF[l];
    u32 m = gcnt[l]; if (m > GCAP) m = GCAP;
    u32 b1 = tinfo[l * 2];
    u32 need = tinfo[l * 2 + 1];
    const u32* kb = gkey + l * GCAP;
    const u32* ib = gidx + l * GCAP;
    // mid 11 bits
    hist[t] = 0; hist[t + 1024] = 0; __syncthreads();
    for (u32 e = t; e < m; e += 1024) atomicAdd(&hist[(kb[e] >> 10) & 2047u], 1u);
    __syncthreads();
    thresh_scan(hist, scanbuf, 2048, need, sv, t);
    u32 b2 = sv[0], need2 = sv[1];
    __syncthreads();
    // low 10 bits
    hist[t] = 0; __syncthreads();
    for (u32 e = t; e < m; e += 1024) {
        u32 ky = kb[e];
        if (((ky >> 10) & 2047u) == b2) atomicAdd(&hist[ky & 1023u], 1u);
    }
    __syncthreads();
    thresh_scan(hist, scanbuf, 1024, need2, sv, t);
    u32 T = (b1 << 21) | (b2 << 10) | sv[0];
    u32 take = sv[1];
    if (t == 0) { c2 = 0; ceq = 0; }
    __syncthreads();
    u32 nGTbin = need - take;
    u32 base2 = (u32)sb + (u32)k - need;   // after strict-greater-bin entries
    for (u32 e = t; e < m; e += 1024) {
        u32 ky = kb[e];
        if (ky > T) { u32 p = atomicAdd(&c2, 1u); sel[base2 + p] = (u32)off + ib[e]; }
        else if (ky == T) { u32 q = atomicAdd(&ceq, 1u); if (q < 1024) eqbuf[q] = ib[e]; }
    }
    __syncthreads();
    if (t == 0) {
        int n = (ceq > 1024u) ? 1024 : (int)ceq;
        for (int a = 1; a < n; ++a) {  // ascending insertion sort; tie count tiny
            u32 v = eqbuf[a]; int bq = a - 1;
            while (bq >= 0 && eqbuf[bq] > v) { eqbuf[bq + 1] = eqbuf[bq]; --bq; }
            eqbuf[bq + 1] = v;
        }
        for (u32 q = 0; q < take; ++q) sel[base2 + nGTbin + q] = (u32)off + eqbuf[q];
    }
}

// ---------------- K2: decode selected boxes (exact reference op order) ----------------
__global__ void k_decode(const float* __restrict__ scores, const float4* __restrict__ deltas,
                         const float4* __restrict__ anchors, const u32* __restrict__ sel,
                         float4* __restrict__ candB, float* __restrict__ candS,
                         u32* __restrict__ candV, u32* __restrict__ candA) {
    int s = blockIdx.x * 256 + threadIdx.x;
    if (s >= K_TOT) return;
    u32 a = sel[s];
    float4 an = anchors[a];
    float4 dl = deltas[a];
    float sc = scores[a];
    float w = __fsub_rn(an.z, an.x), h = __fsub_rn(an.w, an.y);
    float cx = __fadd_rn(an.x, __fmul_rn(0.5f, w));
    float cy = __fadd_rn(an.y, __fmul_rn(0.5f, h));
    const float CLIPV = (float)4.1351665567423563;  // log(1000/16) as f32
    float dw = fminf(dl.z, CLIPV);
    float dh = fminf(dl.w, CLIPV);
    float px = __fadd_rn(cx, __fmul_rn(dl.x, w));
    float py = __fadd_rn(cy, __fmul_rn(dl.y, h));
    float pw = __fmul_rn((float)exp((double)dw), w);
    float ph = __fmul_rn((float)exp((double)dh), h);
    float x1 = __fsub_rn(px, __fmul_rn(0.5f, pw));
    float y1 = __fsub_rn(py, __fmul_rn(0.5f, ph));
    float x2 = __fadd_rn(px, __fmul_rn(0.5f, pw));
    float y2 = __fadd_rn(py, __fmul_rn(0.5f, ph));
    x1 = fminf(fmaxf(x1, 0.0f), IMGSZ);
    y1 = fminf(fmaxf(y1, 0.0f), IMGSZ);
    x2 = fminf(fmaxf(x2, 0.0f), IMGSZ);
    y2 = fminf(fmaxf(y2, 0.0f), IMGSZ);
    bool valid = (__fsub_rn(x2, x1) >= 0.001f) && (__fsub_rn(y2, y1) >= 0.001f);
    candB[s] = make_float4(x1, y1, x2, y2);
    candS[s] = sc;
    candV[s] = valid ? 1u : 0u;
    candA[s] = a;
}

// ---------------- K3a: within-level rank (tiled pairwise count) ----------------
__global__ __launch_bounds__(256) void k_rank_lvl(const float* __restrict__ candS,
                                                  const u32* __restrict__ candA,
                                                  u32* __restrict__ Praw) {
    __shared__ u64 tile[256];
    int l = blockIdx.z;
    int cnt = KSEL[l], base = SELB[l];
    int tx = blockIdx.x * 256;
    int ty = blockIdx.y * 256;
    if (tx >= cnt || ty >= cnt) return;
    int t = threadIdx.x;
    u64 Aj = ~0ull;  // sentinel: never < any real key
    if (tx + t < cnt) {
        int j = base + tx + t;
        Aj = ((u64)(~fkey(candS[j])) << 32) | (u64)candA[j];
    }
    tile[t] = Aj;
    __syncthreads();
    int si = ty + t;
    if (si >= cnt) return;
    int s = base + si;
    u64 A = ((u64)(~fkey(candS[s])) << 32) | (u64)candA[s];
    int r = 0;
#pragma unroll 8
    for (int q = 0; q < 256; ++q) r += (tile[q] < A);
    if (r) atomicAdd(&Praw[s], (u32)r);
}

// ---------------- K3b: global rank by (masked score desc, position asc) ----------------
__global__ __launch_bounds__(256) void k_rank_glob(const float* __restrict__ candS,
                                                   const u32* __restrict__ candV,
                                                   const u32* __restrict__ Praw,
                                                   u32* __restrict__ rank) {
    __shared__ u64 colB[256];
    int t = threadIdx.x;
    int cj = blockIdx.x * 256 + t;
    u64 B = ~0ull;
    if (cj < K_TOT) {
        u32 smk = candV[cj] ? fkey(candS[cj]) : 0x007FFFFFu;  // fkey(-inf)
        u32 Pj = (u32)SELB[lvl_of(cj)] + Praw[cj];
        B = ((u64)(~smk) << 32) | (u64)Pj;
    }
    colB[t] = B;
    __syncthreads();
    int s = blockIdx.y * 256 + t;
    if (s >= K_TOT) return;
    u32 smk = candV[s] ? fkey(candS[s]) : 0x007FFFFFu;
    u32 Ps = (u32)SELB[lvl_of(s)] + Praw[s];
    u64 myB = ((u64)(~smk) << 32) | (u64)Ps;
    int cnt = 0;
#pragma unroll 8
    for (int j = 0; j < 256; ++j) cnt += (colB[j] < myB);
    if (cnt) atomicAdd(&rank[s], (u32)cnt);
}

// ---------------- K4: scatter into sorted order ----------------
// Reference's fmask slice is all zeros -> NMS on raw clipped boxes (no level offsets).
__global__ void k_scatter(const float4* __restrict__ candB, const float* __restrict__ candS,
                          const u32* __restrict__ candV, const u32* __restrict__ rank,
                          float4* __restrict__ sB, float* __restrict__ sArea,
                          float* __restrict__ sS, u32* __restrict__ sV) {
    int s = blockIdx.x * 256 + threadIdx.x;
    if (s >= K_TOT) return;
    u32 r = rank[s];
    float4 b = candB[s];
    float area = __fmul_rn(__fsub_rn(b.z, b.x), __fsub_rn(b.w, b.y));
    sB[r] = b; sArea[r] = area; sS[r] = candS[s]; sV[r] = candV[s];
}

// ---------------- K5: suppression bits -> packed entry lists (+ vwords/dmask ballots) ----------------
// off-diag: bucketed by TARGET chunk, 16B entries {src_row, bits}  (pull model).
// diag (intra-chunk): full diag[] row words; dmask via wave ballot (no atomics).
__global__ __launch_bounds__(256) void k_mask(const float4* __restrict__ sB,
                                              const float* __restrict__ sArea,
                                              const u32* __restrict__ sV,
                                              u64* __restrict__ vwords,
                                              u64* __restrict__ diag, u32* __restrict__ ecnt,
                                              ulonglong2* __restrict__ epack,
                                              u64* __restrict__ dmask) {
    __shared__ float4 cb[64];
    __shared__ float ca[64];
    int wd = blockIdx.x;   // target word (column chunk)
    int t = threadIdx.x;
    if (t < 64) {
        int j = wd * 64 + t;
        if (j < K_TOT) { cb[t] = sB[j]; ca[t] = sArea[j]; }
        else { cb[t] = make_float4(0.f, 0.f, 0.f, 0.f); ca[t] = 0.f; }
    }
    __syncthreads();
    int i = blockIdx.y * 256 + t;
    if (i >= K_TOT) return;
    int dwr = i >> 6;              // wave-uniform (i spans one aligned 64-row band per wave)
    if (wd < dwr) return;          // strictly upper-triangular
    float4 bi = sB[i];
    float ai = sArea[i];
    u64 bits = 0;
    int jbase = wd * 64;
    for (int j2 = 0; j2 < 64; ++j2) {
        int j = jbase + j2;
        if (j > i && j < K_TOT) {
            float4 bj = cb[j2];
            float ltx = fmaxf(bi.x, bj.x), lty = fmaxf(bi.y, bj.y);
            float rbx = fminf(bi.z, bj.z), rby = fminf(bi.w, bj.w);
            float wx = fmaxf(__fsub_rn(rbx, ltx), 0.0f);
            float wy = fmaxf(__fsub_rn(rby, lty), 0.0f);
            float inter = __fmul_rn(wx, wy);
            if (inter > 0.0f) {
                float uni = __fsub_rn(__fadd_rn(ai, ca[j2]), inter);
                float iou = inter / uni;  // IEEE f32 div, matches reference
                if (iou > 0.7f) bits |= (1ull << j2);
            }
        }
    }
    if (wd == dwr) {
        diag[i] = bits;                          // per-row intra-chunk suppressor word
        u64 vb = __ballot(sV[i] != 0u);          // wave-uniform branch: safe ballots
        u64 db = __ballot(bits != 0ull);
        if ((i & 63) == 0) { vwords[wd] = vb; dmask[wd] = db; }
    } else if (bits != 0ull) {
        u32 p = atomicAdd(&ecnt[wd], 1u);        // bucket by TARGET chunk (pull model)
        if (p < CAP) epack[wd * CAP + p] = make_ulonglong2((u64)i, bits);
    }
}

// ---------------- K6: 4-wave pipelined NMS scan (pull model) + fused output ----------------
// Round-6 lesson: with 16 waves, the resolving wave shared its SIMD with 3 actively
// spinning waves (1/4 issue rate) and the DS pipe was hammered by 15 pollers -> ~1080
// cy/chunk regardless of chain length. Fix: only waves 0..3 scan (1 wave/SIMD on
// round-robin mapping -> full issue rate for the resolver); waves 4..15 wait at the
// barrier (no instruction issue) and rejoin for the output phase. Far-from-turn scan
// waves back off with s_sleep to keep the DS pipe quiet. Fold logic identical to r6.
__global__ __launch_bounds__(1024) void k_scan(const u64* __restrict__ diag,
                                               const u64* __restrict__ vwords,
                                               const u32* __restrict__ ecnt,
                                               const ulonglong2* __restrict__ tpack,
                                               const u64* __restrict__ dmask,
                                               const float4* __restrict__ sB,
                                               const float* __restrict__ sS,
                                               float* __restrict__ out) {
    __shared__ u64 sKeepArr[NCH];
    __shared__ u32 pc[NCH + 1];
    __shared__ u32 sProg;
    int t = threadIdx.x;
    int w = t >> 6, lane = t & 63;
    if (t == 0) sProg = 0;
    __syncthreads();
    if (w < 4) {
        for (int c = w; c < NCH; c += 4) {
            // ---- pre-stage from global (hidden under the pipeline wait) ----
            ulonglong2 E1 = tpack[(size_t)c * CAP + lane];
            ulonglong2 E2 = tpack[(size_t)c * CAP + 64 + lane];
            u64 Dc = diag[c * 64 + lane];
            u64 vw = vwords[c];
            u64 dmw = dmask[c];
            u32 cnt = ecnt[c]; if (cnt > CAP) cnt = CAP;
            u32 s1 = (u32)E1.x, s2 = (u32)E2.x;
            u32 sch1 = s1 >> 6, sch2 = s2 >> 6;
            u64 mbits = 0;
            bool done1 = ((u32)lane >= cnt);
            bool done2 = ((u32)(lane + 64) >= cnt);
            // ---- wait + opportunistic fold (sleep while far from our turn) ----
            if (c > 0) {
                for (;;) {
                    u32 p = __hip_atomic_load(&sProg, __ATOMIC_ACQUIRE, __HIP_MEMORY_SCOPE_WORKGROUP);
                    if ((u32)c > p + 2u) { __builtin_amdgcn_s_sleep(2); continue; }
                    if (!done1 && sch1 < p) {
                        if ((sKeepArr[sch1] >> (s1 & 63u)) & 1ull) mbits |= E1.y;
                        done1 = true;
                    }
                    if (!done2 && sch2 < p) {
                        if ((sKeepArr[sch2] >> (s2 & 63u)) & 1ull) mbits |= E2.y;
                        done2 = true;
                    }
                    if (p >= (u32)c) break;
                }
            }
            // ---- resolve chunk c ----
            u64 inc = 0;
            if (cnt) {
                if (cnt > 128u) {   // rare tail beyond the two prefetched entry banks
                    for (u32 e = 128u + (u32)lane; e < cnt; e += 64u) {
                        ulonglong2 Et = tpack[(size_t)c * CAP + e];
                        u32 si = (u32)Et.x;
                        if ((sKeepArr[si >> 6] >> (si & 63u)) & 1ull) mbits |= Et.y;
                    }
                }
                u32 lo = wor32((u32)mbits);
                u32 hi = wor32((u32)(mbits >> 32));
                inc = ((u64)rdl32(hi, 63) << 32) | (u64)rdl32(lo, 63);
            }
            u64 alive = vw & ~inc;
            if (dmw) {
                u64 dm = dmw & alive;
                while (dm) {
                    int j = __builtin_ctzll(dm);
                    dm &= dm - 1;
                    if ((alive >> j) & 1ull) {
                        alive &= ~rdlane64(Dc, j);
                        dm &= alive;              // suppressed rows can't suppress
                    }
                }
            }
            if (lane == 0) {
                sKeepArr[c] = alive;
                __hip_atomic_store(&sProg, (u32)(c + 1), __ATOMIC_RELEASE, __HIP_MEMORY_SCOPE_WORKGROUP);
            }
        }
    }
    __syncthreads();
    // ---- fused output phase (all 1024 threads) ----
    if (t < NCH) pc[t + 1] = (u32)__popcll(sKeepArr[t]);
    if (t == 0) pc[0] = 0;
    __syncthreads();
    for (int ofs = 1; ofs < NCH; ofs <<= 1) {   // Hillis-Steele inclusive scan over pc[1..NCH]
        int i = t + 1;
        u32 v = 0;
        bool p = (t < NCH) && (i - ofs >= 1);
        if (p) v = pc[i - ofs];
        __syncthreads();
        if (p) pc[i] += v;
        __syncthreads();
    }
    u32 nk = pc[NCH];
    for (int i = t; i < K_TOT; i += 1024) {
        int wi = i >> 6, b = i & 63;
        u64 kw = sKeepArr[wi];
        u32 kb = pc[wi] + (u32)__popcll(kw & ((1ull << b) - 1ull));
        bool kp = (kw >> b) & 1ull;
        if (kp) {
            if (kb < 1000u) {
                float4 bx = sB[i];
                out[kb * 4 + 0] = bx.x; out[kb * 4 + 1] = bx.y;
                out[kb * 4 + 2] = bx.z; out[kb * 4 + 3] = bx.w;
                out[4000 + kb] = sS[i];
            }
        } else {
            u32 q = (u32)i - kb;
            u32 slot = nk + q;
            if (slot < 1000u) {
                float4 bx = sB[i];
                out[slot * 4 + 0] = bx.x; out[slot * 4 + 1] = bx.y;
                out[slot * 4 + 2] = bx.z; out[slot * 4 + 3] = bx.w;
                out[4000 + slot] = -INFINITY;
            }
        }
    }
}

// ---------------- workspace layout ----------------
static constexpr size_t al256(size_t x) { return (x + 255) & ~(size_t)255; }
static constexpr size_t KB4 = (size_t)K_TOT * 4;
static constexpr size_t KB16 = (size_t)K_TOT * 16;
// zeroed region:
static constexpr size_t O_RANK = 0;
static constexpr size_t O_PRAW = al256(O_RANK + KB4);
static constexpr size_t O_ECNT = al256(O_PRAW + KB4);
static constexpr size_t O_HIST = al256(O_ECNT + (size_t)NCH * 4);
static constexpr size_t O_CGT = al256(O_HIST + (size_t)3 * 2048 * 4);
static constexpr size_t O_GCNT = al256(O_CGT + 3 * 4);
static constexpr size_t MEMSET_BYTES = al256(O_GCNT + 3 * 4);
// non-zeroed region:
static constexpr size_t O_TINFO = MEMSET_BYTES;
static constexpr size_t O_SEL = al256(O_TINFO + 6 * 4);
static constexpr size_t O_GIDX = al256(O_SEL + KB4);
static constexpr size_t O_GKEY = al256(O_GIDX + (size_t)3 * GCAP * 4);
static constexpr size_t O_CANDB = al256(O_GKEY + (size_t)3 * GCAP * 4);
static constexpr size_t O_CANDS = al256(O_CANDB + KB16);
static constexpr size_t O_CANDV = al256(O_CANDS + KB4);
static constexpr size_t O_CANDA = al256(O_CANDV + KB4);
static constexpr size_t O_SB = al256(O_CANDA + KB4);
static constexpr size_t O_SAREA = al256(O_SB + KB16);
static constexpr size_t O_SS = al256(O_SAREA + KB4);
static constexpr size_t O_SV = al256(O_SS + KB4);
static constexpr size_t O_VW = al256(O_SV + KB4);
static constexpr size_t O_DMASK = al256(O_VW + (size_t)NCH * 8);
static constexpr size_t O_DIAG = al256(O_DMASK + (size_t)NCH * 8);
static constexpr size_t O_EPACK = al256(O_DIAG + (size_t)(NCH * 64) * 8);

extern "C" void kernel_launch(void* const* d_in, const int* in_sizes, int n_in,
                              void* d_out, int out_size, void* d_ws, size_t ws_size,
                              hipStream_t stream) {
    const float* scores = (const float*)d_in[0];
    const float4* deltas = (const float4*)d_in[1];
    const float4* anchors = (const float4*)d_in[2];
    float* out = (float*)d_out;
    char* ws = (char*)d_ws;

    u32* rank = (u32*)(ws + O_RANK);
    u32* Praw = (u32*)(ws + O_PRAW);
    u32* ecnt = (u32*)(ws + O_ECNT);
    u32* hist3 = (u32*)(ws + O_HIST);
    u32* cgt = (u32*)(ws + O_CGT);
    u32* gcnt = (u32*)(ws + O_GCNT);
    u32* tinfo = (u32*)(ws + O_TINFO);
    u32* sel = (u32*)(ws + O_SEL);
    u32* gidx = (u32*)(ws + O_GIDX);
    u32* gkey = (u32*)(ws + O_GKEY);
    float4* candB = (float4*)(ws + O_CANDB);
    float* candS = (float*)(ws + O_CANDS);
    u32* candV = (u32*)(ws + O_CANDV);
    u32* candA = (u32*)(ws + O_CANDA);
    float4* sB = (float4*)(ws + O_SB);
    float* sArea = (float*)(ws + O_SAREA);
    float* sS = (float*)(ws + O_SS);
    u32* sV = (u32*)(ws + O_SV);
    u64* vwords = (u64*)(ws + O_VW);
    u64* dmask = (u64*)(ws + O_DMASK);
    u64* diag = (u64*)(ws + O_DIAG);
    ulonglong2* epack = (ulonglong2*)(ws + O_EPACK);

    hipMemsetAsync(ws, 0, MEMSET_BYTES, stream);

    const int NBLK = (K_TOT + 255) / 256;  // 33
    k_hist<<<156, 1024, 0, stream>>>(scores, hist3);
    k_thresh<<<3, 1024, 0, stream>>>(hist3, tinfo);
    k_gather<<<159, 1024, 0, stream>>>(scores, tinfo, sel, cgt, gcnt, gidx, gkey);
    k_final<<<3, 1024, 0, stream>>>(gidx, gkey, gcnt, tinfo, sel);
    k_decode<<<NBLK, 256, 0, stream>>>(scores, deltas, anchors, sel, candB, candS, candV, candA);
    k_rank_lvl<<<dim3(8, 8, 5), 256, 0, stream>>>(candS, candA, Praw);
    k_rank_glob<<<dim3(NBLK, NBLK), 256, 0, stream>>>(candS, candV, Praw, rank);
    k_scatter<<<NBLK, 256, 0, stream>>>(candB, candS, candV, rank, sB, sArea, sS, sV);
    k_mask<<<dim3(NCH, NBLK), 256, 0, stream>>>(sB, sArea, sV, vwords, diag, ecnt, epack, dmask);
    k_scan<<<1, 1024, 0, stream>>>(diag, vwords, ecnt, epack, dmask, sB, sS, out);
}

// Round 8
// 194.620 us; speedup vs baseline: 1.1719x; 1.0748x over previous
//
#include <hip/hip_runtime.h>
#include <math.h>

typedef unsigned int u32;
typedef unsigned long long u64;
typedef unsigned char u8;

#define K_TOT 8382
#define NCH 131      // 131 words of 64 rows
#define SC 4         // words per super-chunk (256 rows)
#define NSC ((NCH + SC - 1) / SC)   // 33 serial steps
#define CAP 1024     // per-TARGET-word off-diag entry capacity (global)
#define GCAP 32768   // per-level threshold-bin candidate capacity
#define IMGSZ 800.0f

__device__ __constant__ int LOFF[5] = {0, 120000, 150000, 157500, 159375};
__device__ __constant__ int LCNT[5] = {120000, 30000, 7500, 1875, 507};
__device__ __constant__ int KSEL[5] = {2000, 2000, 2000, 1875, 507};
__device__ __constant__ int SELB[5] = {0, 2000, 4000, 6000, 7875};
__device__ __constant__ int HBS[4] = {0, 118, 148, 156};    // k_hist block starts (levels 0..2)
__device__ __constant__ int GBS[6] = {0, 118, 148, 156, 158, 159};  // k_gather block starts

static __device__ __forceinline__ u32 fkey(float x) {
    u32 u = __float_as_uint(x);
    u32 m = (u32)(((int)u) >> 31) | 0x80000000u;
    return u ^ m;
}

static __device__ __forceinline__ int lvl_of(int s) {
    return (s < 2000) ? 0 : (s < 4000) ? 1 : (s < 6000) ? 2 : (s < 7875) ? 3 : 4;
}

// scalar-path readlanes (uniform lane index -> v_readlane)
static __device__ __forceinline__ u32 rdl32(u32 v, int j) {
    return (u32)__builtin_amdgcn_readlane((int)v, j);
}
static __device__ __forceinline__ u64 rdlane64(u64 v, int j) {
    u32 lo = (u32)__builtin_amdgcn_readlane((int)(u32)v, j);
    u32 hi = (u32)__builtin_amdgcn_readlane((int)(u32)(v >> 32), j);
    return ((u64)hi << 32) | (u64)lo;
}

// wave64 OR-reduce via DPP (row_shr 1/2/4/8 + bcast15 + bcast31); result in lane 63
static __device__ __forceinline__ u32 wor32(u32 x) {
    x |= (u32)__builtin_amdgcn_update_dpp(0, (int)x, 0x111, 0xf, 0xf, true);
    x |= (u32)__builtin_amdgcn_update_dpp(0, (int)x, 0x112, 0xf, 0xf, true);
    x |= (u32)__builtin_amdgcn_update_dpp(0, (int)x, 0x114, 0xf, 0xf, true);
    x |= (u32)__builtin_amdgcn_update_dpp(0, (int)x, 0x118, 0xf, 0xf, true);
    x |= (u32)__builtin_amdgcn_update_dpp(0, (int)x, 0x142, 0xa, 0xf, true);
    x |= (u32)__builtin_amdgcn_update_dpp(0, (int)x, 0x143, 0xc, 0xf, true);
    return x;
}

// Parallel reverse-inclusive scan over hist[0..m-1] (from top bin down);
// finds bin with suffix-cum >= need. Out: sv[0]=bin, sv[1]=remaining ties to take.
static __device__ __forceinline__ void thresh_scan(const u32* hist, u32* scanbuf, int m,
                                                   u32 need, u32* sv, int t) {
    for (int i = t; i < m; i += 1024) scanbuf[i] = hist[m - 1 - i];
    __syncthreads();
    for (int ofs = 1; ofs < m; ofs <<= 1) {
        int i0 = t, i1 = t + 1024;
        u32 a0 = 0, a1 = 0;
        if (i0 < m && i0 >= ofs) a0 = scanbuf[i0 - ofs];
        if (i1 < m && i1 >= ofs) a1 = scanbuf[i1 - ofs];
        __syncthreads();
        if (i0 < m && i0 >= ofs) scanbuf[i0] += a0;
        if (i1 < m && i1 >= ofs) scanbuf[i1] += a1;
        __syncthreads();
    }
    for (int i = t; i < m; i += 1024) {
        u32 inc = scanbuf[i];
        u32 exc = i ? scanbuf[i - 1] : 0;
        if (inc >= need && exc < need) { sv[0] = (u32)(m - 1 - i); sv[1] = need - exc; }
    }
    __syncthreads();
}

// ---------------- K1a: parallel coarse histogram (top 11 key bits), levels 0..2 ----------------
__global__ __launch_bounds__(1024) void k_hist(const float* __restrict__ scores,
                                               u32* __restrict__ hist3) {
    __shared__ u32 lh[2048];
    int t = threadIdx.x;
    lh[t] = 0; lh[t + 1024] = 0;
    __syncthreads();
    int b = blockIdx.x;
    int l = (b < HBS[1]) ? 0 : (b < HBS[2]) ? 1 : 2;
    int i = (b - HBS[l]) * 1024 + t;
    if (i < LCNT[l]) atomicAdd(&lh[fkey(scores[LOFF[l] + i]) >> 21], 1u);
    __syncthreads();
    u32* h = hist3 + l * 2048;
    if (lh[t]) atomicAdd(&h[t], lh[t]);
    if (lh[t + 1024]) atomicAdd(&h[t + 1024], lh[t + 1024]);
}

// ---------------- K1b: coarse threshold per level ----------------
__global__ __launch_bounds__(1024) void k_thresh(const u32* __restrict__ hist3,
                                                 u32* __restrict__ tinfo) {
    __shared__ u32 scanbuf[2048];
    __shared__ u32 sv[2];
    int l = blockIdx.x;
    int t = threadIdx.x;
    thresh_scan(hist3 + l * 2048, scanbuf, 2048, (u32)KSEL[l], sv, t);
    if (t == 0) { tinfo[l * 2] = sv[0]; tinfo[l * 2 + 1] = sv[1]; }
}

// ---------------- K1c: classify; strict-greater -> sel, threshold-bin -> candidate buf ----------------
__global__ __launch_bounds__(1024) void k_gather(const float* __restrict__ scores,
                                                 const u32* __restrict__ tinfo,
                                                 u32* __restrict__ sel, u32* __restrict__ cgt,
                                                 u32* __restrict__ gcnt, u32* __restrict__ gidx,
                                                 u32* __restrict__ gkey) {
    int b = blockIdx.x;
    int l = (b < GBS[1]) ? 0 : (b < GBS[2]) ? 1 : (b < GBS[3]) ? 2 : (b < GBS[4]) ? 3 : 4;
    int i = (b - GBS[l]) * 1024 + threadIdx.x;
    if (i >= LCNT[l]) return;
    int off = LOFF[l], sb = SELB[l];
    if (l >= 3) { sel[sb + i] = (u32)(off + i); return; }  // take-all levels
    u32 ky = fkey(scores[off + i]);
    u32 b1 = tinfo[l * 2];
    u32 top = ky >> 21;
    if (top > b1) {
        u32 p = atomicAdd(&cgt[l], 1u);
        sel[sb + p] = (u32)(off + i);          // set membership only; order fixed by P later
    } else if (top == b1) {
        u32 e = atomicAdd(&gcnt[l], 1u);
        if (e < GCAP) { gidx[l * GCAP + e] = (u32)i; gkey[l * GCAP + e] = ky; }
    }
}

// ---------------- K1d: exact refine within threshold bin (mid 11 + low 10 bits) ----------------
__global__ __launch_bounds__(1024) void k_final(const u32* __restrict__ gidx,
                                                const u32* __restrict__ gkey,
                                                const u32* __restrict__ gcnt,
                                                const u32* __restrict__ tinfo,
                                                u32* __restrict__ sel) {
    __shared__ u32 hist[2048];
    __shared__ u32 scanbuf[2048];
    __shared__ u32 eqbuf[1024];
    __shared__ u32 sv[2];
    __shared__ u32 c2, ceq;
    int l = blockIdx.x;
    int t = threadIdx.x;
    int k = KSEL[l], sb = SELB[l], off = LOFF[l];
    u32 m = gcnt[l]; if (m > GCAP) m = GCAP;
    u32 b1 = tinfo[l * 2];
    u32 need = tinfo[l * 2 + 1];
    const u32* kb = gkey + l * GCAP;
    const u32* ib = gidx + l * GCAP;
    // mid 11 bits
    hist[t] = 0; hist[t + 1024] = 0; __syncthreads();
    for (u32 e = t; e < m; e += 1024) atomicAdd(&hist[(kb[e] >> 10) & 2047u], 1u);
    __syncthreads();
    thresh_scan(hist, scanbuf, 2048, need, sv, t);
    u32 b2 = sv[0], need2 = sv[1];
    __syncthreads();
    // low 10 bits
    hist[t] = 0; __syncthreads();
    for (u32 e = t; e < m; e += 1024) {
        u32 ky = kb[e];
        if (((ky >> 10) & 2047u) == b2) atomicAdd(&hist[ky & 1023u], 1u);
    }
    __syncthreads();
    thresh_scan(hist, scanbuf, 1024, need2, sv, t);
    u32 T = (b1 << 21) | (b2 << 10) | sv[0];
    u32 take = sv[1];
    if (t == 0) { c2 = 0; ceq = 0; }
    __syncthreads();
    u32 nGTbin = need - take;
    u32 base2 = (u32)sb + (u32)k - need;   // after strict-greater-bin entries
    for (u32 e = t; e < m; e += 1024) {
        u32 ky = kb[e];
        if (ky > T) { u32 p = atomicAdd(&c2, 1u); sel[base2 + p] = (u32)off + ib[e]; }
        else if (ky == T) { u32 q = atomicAdd(&ceq, 1u); if (q < 1024) eqbuf[q] = ib[e]; }
    }
    __syncthreads();
    if (t == 0) {
        int n = (ceq > 1024u) ? 1024 : (int)ceq;
        for (int a = 1; a < n; ++a) {  // ascending insertion sort; tie count tiny
            u32 v = eqbuf[a]; int bq = a - 1;
            while (bq >= 0 && eqbuf[bq] > v) { eqbuf[bq + 1] = eqbuf[bq]; --bq; }
            eqbuf[bq + 1] = v;
        }
        for (u32 q = 0; q < take; ++q) sel[base2 + nGTbin + q] = (u32)off + eqbuf[q];
    }
}

// ---------------- K2: decode selected boxes (exact reference op order) ----------------
__global__ void k_decode(const float* __restrict__ scores, const float4* __restrict__ deltas,
                         const float4* __restrict__ anchors, const u32* __restrict__ sel,
                         float4* __restrict__ candB, float* __restrict__ candS,
                         u32* __restrict__ candV, u32* __restrict__ candA) {
    int s = blockIdx.x * 256 + threadIdx.x;
    if (s >= K_TOT) return;
    u32 a = sel[s];
    float4 an = anchors[a];
    float4 dl = deltas[a];
    float sc = scores[a];
    float w = __fsub_rn(an.z, an.x), h = __fsub_rn(an.w, an.y);
    float cx = __fadd_rn(an.x, __fmul_rn(0.5f, w));
    float cy = __fadd_rn(an.y, __fmul_rn(0.5f, h));
    const float CLIPV = (float)4.1351665567423563;  // log(1000/16) as f32
    float dw = fminf(dl.z, CLIPV);
    float dh = fminf(dl.w, CLIPV);
    float px = __fadd_rn(cx, __fmul_rn(dl.x, w));
    float py = __fadd_rn(cy, __fmul_rn(dl.y, h));
    float pw = __fmul_rn((float)exp((double)dw), w);
    float ph = __fmul_rn((float)exp((double)dh), h);
    float x1 = __fsub_rn(px, __fmul_rn(0.5f, pw));
    float y1 = __fsub_rn(py, __fmul_rn(0.5f, ph));
    float x2 = __fadd_rn(px, __fmul_rn(0.5f, pw));
    float y2 = __fadd_rn(py, __fmul_rn(0.5f, ph));
    x1 = fminf(fmaxf(x1, 0.0f), IMGSZ);
    y1 = fminf(fmaxf(y1, 0.0f), IMGSZ);
    x2 = fminf(fmaxf(x2, 0.0f), IMGSZ);
    y2 = fminf(fmaxf(y2, 0.0f), IMGSZ);
    bool valid = (__fsub_rn(x2, x1) >= 0.001f) && (__fsub_rn(y2, y1) >= 0.001f);
    candB[s] = make_float4(x1, y1, x2, y2);
    candS[s] = sc;
    candV[s] = valid ? 1u : 0u;
    candA[s] = a;
}

// ---------------- K3a: within-level rank (tiled pairwise count) ----------------
__global__ __launch_bounds__(256) void k_rank_lvl(const float* __restrict__ candS,
                                                  const u32* __restrict__ candA,
                                                  u32* __restrict__ Praw) {
    __shared__ u64 tile[256];
    int l = blockIdx.z;
    int cnt = KSEL[l], base = SELB[l];
    int tx = blockIdx.x * 256;
    int ty = blockIdx.y * 256;
    if (tx >= cnt || ty >= cnt) return;
    int t = threadIdx.x;
    u64 Aj = ~0ull;  // sentinel: never < any real key
    if (tx + t < cnt) {
        int j = base + tx + t;
        Aj = ((u64)(~fkey(candS[j])) << 32) | (u64)candA[j];
    }
    tile[t] = Aj;
    __syncthreads();
    int si = ty + t;
    if (si >= cnt) return;
    int s = base + si;
    u64 A = ((u64)(~fkey(candS[s])) << 32) | (u64)candA[s];
    int r = 0;
#pragma unroll 8
    for (int q = 0; q < 256; ++q) r += (tile[q] < A);
    if (r) atomicAdd(&Praw[s], (u32)r);
}

// ---------------- K3b: global rank by (masked score desc, position asc) ----------------
__global__ __launch_bounds__(256) void k_rank_glob(const float* __restrict__ candS,
                                                   const u32* __restrict__ candV,
                                                   const u32* __restrict__ Praw,
                                                   u32* __restrict__ rank) {
    __shared__ u64 colB[256];
    int t = threadIdx.x;
    int cj = blockIdx.x * 256 + t;
    u64 B = ~0ull;
    if (cj < K_TOT) {
        u32 smk = candV[cj] ? fkey(candS[cj]) : 0x007FFFFFu;  // fkey(-inf)
        u32 Pj = (u32)SELB[lvl_of(cj)] + Praw[cj];
        B = ((u64)(~smk) << 32) | (u64)Pj;
    }
    colB[t] = B;
    __syncthreads();
    int s = blockIdx.y * 256 + t;
    if (s >= K_TOT) return;
    u32 smk = candV[s] ? fkey(candS[s]) : 0x007FFFFFu;
    u32 Ps = (u32)SELB[lvl_of(s)] + Praw[s];
    u64 myB = ((u64)(~smk) << 32) | (u64)Ps;
    int cnt = 0;
#pragma unroll 8
    for (int j = 0; j < 256; ++j) cnt += (colB[j] < myB);
    if (cnt) atomicAdd(&rank[s], (u32)cnt);
}

// ---------------- K4: scatter into sorted order ----------------
// Reference's fmask slice is all zeros -> NMS on raw clipped boxes (no level offsets).
__global__ void k_scatter(const float4* __restrict__ candB, const float* __restrict__ candS,
                          const u32* __restrict__ candV, const u32* __restrict__ rank,
                          float4* __restrict__ sB, float* __restrict__ sArea,
                          float* __restrict__ sS, u32* __restrict__ sV) {
    int s = blockIdx.x * 256 + threadIdx.x;
    if (s >= K_TOT) return;
    u32 r = rank[s];
    float4 b = candB[s];
    float area = __fmul_rn(__fsub_rn(b.z, b.x), __fsub_rn(b.w, b.y));
    sB[r] = b; sArea[r] = area; sS[r] = candS[s]; sV[r] = candV[s];
}

// ---------------- K5: suppression bits -> packed entry lists (+ vwords/dmask ballots) ----------------
// off-diag: bucketed by TARGET word, 16B entries {src_row, bits}  (pull model).
// diag (intra-word): full diag[] row words; dmask via wave ballot (no atomics).
__global__ __launch_bounds__(256) void k_mask(const float4* __restrict__ sB,
                                              const float* __restrict__ sArea,
                                              const u32* __restrict__ sV,
                                              u64* __restrict__ vwords,
                                              u64* __restrict__ diag, u32* __restrict__ ecnt,
                                              ulonglong2* __restrict__ epack,
                                              u64* __restrict__ dmask) {
    __shared__ float4 cb[64];
    __shared__ float ca[64];
    int wd = blockIdx.x;   // target word (column chunk)
    int t = threadIdx.x;
    if (t < 64) {
        int j = wd * 64 + t;
        if (j < K_TOT) { cb[t] = sB[j]; ca[t] = sArea[j]; }
        else { cb[t] = make_float4(0.f, 0.f, 0.f, 0.f); ca[t] = 0.f; }
    }
    __syncthreads();
    int i = blockIdx.y * 256 + t;
    if (i >= K_TOT) return;
    int dwr = i >> 6;              // wave-uniform (i spans one aligned 64-row band per wave)
    if (wd < dwr) return;          // strictly upper-triangular
    float4 bi = sB[i];
    float ai = sArea[i];
    u64 bits = 0;
    int jbase = wd * 64;
    for (int j2 = 0; j2 < 64; ++j2) {
        int j = jbase + j2;
        if (j > i && j < K_TOT) {
            float4 bj = cb[j2];
            float ltx = fmaxf(bi.x, bj.x), lty = fmaxf(bi.y, bj.y);
            float rbx = fminf(bi.z, bj.z), rby = fminf(bi.w, bj.w);
            float wx = fmaxf(__fsub_rn(rbx, ltx), 0.0f);
            float wy = fmaxf(__fsub_rn(rby, lty), 0.0f);
            float inter = __fmul_rn(wx, wy);
            if (inter > 0.0f) {
                float uni = __fsub_rn(__fadd_rn(ai, ca[j2]), inter);
                float iou = inter / uni;  // IEEE f32 div, matches reference
                if (iou > 0.7f) bits |= (1ull << j2);
            }
        }
    }
    if (wd == dwr) {
        diag[i] = bits;                          // per-row intra-word suppressor word
        u64 vb = __ballot(sV[i] != 0u);          // wave-uniform branch: safe ballots
        u64 db = __ballot(bits != 0ull);
        if ((i & 63) == 0) { vwords[wd] = vb; dmask[wd] = db; }
    } else if (bits != 0ull) {
        u32 p = atomicAdd(&ecnt[wd], 1u);        // bucket by TARGET word (pull model)
        if (p < CAP) epack[wd * CAP + p] = make_ulonglong2((u64)i, bits);
    }
}

// ---------------- K6: 4-wave pipelined NMS scan over 256-row SUPER-CHUNKS ----------------
// Rounds 1-7 lesson: per-handoff cost (~450ns) is a hard floor across 5 different
// structures — so cut the NUMBER of serial steps 131 -> 33. Wave w owns super-chunks
// w, w+4, ... Each step resolves 4 keep-words IN REGISTERS (intra-step deps are pure
// VALU selects: kw = h==w0 ? alive0 : ...), paying the cross-wave handoff once per 256
// rows. Entries/diag prestaged from global during the wait. Release/acquire on sProg
// (super-chunk units) orders sKeepArr writes vs reads; exact, timing-independent.
// Block = 512 threads (8 waves) so ~110 live VGPRs fit without scratch (rule #20).
__global__ __launch_bounds__(512) void k_scan(const u64* __restrict__ diag,
                                              const u64* __restrict__ vwords,
                                              const u32* __restrict__ ecnt,
                                              const ulonglong2* __restrict__ tpack,
                                              const u64* __restrict__ dmask,
                                              const float4* __restrict__ sB,
                                              const float* __restrict__ sS,
                                              float* __restrict__ out) {
    __shared__ u64 sKeepArr[NSC * SC];   // 132 (index 131 = pad, stays benign)
    __shared__ u32 pc[NCH + 1];
    __shared__ u32 sProg;                // super-chunk units
    int t = threadIdx.x;
    int w = t >> 6, lane = t & 63;
    if (t == 0) sProg = 0;
    if (t < NSC * SC) sKeepArr[t] = 0;
    __syncthreads();
    if (w < 4) {
        for (int C = w; C < NSC; C += 4) {
            int w0 = C * SC;
            int t0 = w0, t1 = w0 + 1, t2 = w0 + 2, t3 = w0 + 3;
            bool x1v = t1 < NCH, x2v = t2 < NCH, x3v = t3 < NCH;
            int q1 = x1v ? t1 : 0, q2 = x2v ? t2 : 0, q3 = x3v ? t3 : 0;
            // ---- pre-stage from global (hidden under the pipeline wait) ----
            u32 c0 = ecnt[t0], c1 = x1v ? ecnt[q1] : 0, c2 = x2v ? ecnt[q2] : 0, c3 = x3v ? ecnt[q3] : 0;
            if (c0 > CAP) c0 = CAP;
            if (c1 > CAP) c1 = CAP;
            if (c2 > CAP) c2 = CAP;
            if (c3 > CAP) c3 = CAP;
            u64 vw0 = vwords[t0];
            u64 vw1 = x1v ? vwords[q1] : 0;
            u64 vw2 = x2v ? vwords[q2] : 0;
            u64 vw3 = x3v ? vwords[q3] : 0;
            u64 dmw0 = dmask[t0];
            u64 dmw1 = x1v ? dmask[q1] : 0;
            u64 dmw2 = x2v ? dmask[q2] : 0;
            u64 dmw3 = x3v ? dmask[q3] : 0;
            u64 D0 = diag[t0 * 64 + lane];
            u64 D1 = diag[q1 * 64 + lane];
            u64 D2 = diag[q2 * 64 + lane];
            u64 D3 = diag[q3 * 64 + lane];
            ulonglong2 E00 = tpack[(size_t)t0 * CAP + lane];
            ulonglong2 E01 = tpack[(size_t)t0 * CAP + 64 + lane];
            ulonglong2 E10 = tpack[(size_t)q1 * CAP + lane];
            ulonglong2 E11 = tpack[(size_t)q1 * CAP + 64 + lane];
            ulonglong2 E20 = tpack[(size_t)q2 * CAP + lane];
            ulonglong2 E21 = tpack[(size_t)q2 * CAP + 64 + lane];
            ulonglong2 E30 = tpack[(size_t)q3 * CAP + lane];
            ulonglong2 E31 = tpack[(size_t)q3 * CAP + 64 + lane];
            u32 s00 = (u32)E00.x, s01 = (u32)E01.x, s10 = (u32)E10.x, s11 = (u32)E11.x;
            u32 s20 = (u32)E20.x, s21 = (u32)E21.x, s30 = (u32)E30.x, s31 = (u32)E31.x;
            u32 h00 = s00 >> 6, h01 = s01 >> 6, h10 = s10 >> 6, h11 = s11 >> 6;
            u32 h20 = s20 >> 6, h21 = s21 >> 6, h30 = s30 >> 6, h31 = s31 >> 6;
            // ---- wait for all earlier super-chunks (sleep while far from turn) ----
            if (C > 0) {
                for (;;) {
                    u32 p = __hip_atomic_load(&sProg, __ATOMIC_ACQUIRE, __HIP_MEMORY_SCOPE_WORKGROUP);
                    if (p >= (u32)C) break;
                    if ((u32)C > p + 1u) __builtin_amdgcn_s_sleep(2);
                }
            }
            // ---- external keep reads (clamped vs garbage lanes; intra-chunk overridden) ----
            u64 K00 = sKeepArr[h00 < (u32)NCH ? h00 : 0u];
            u64 K01 = sKeepArr[h01 < (u32)NCH ? h01 : 0u];
            u64 K10 = sKeepArr[h10 < (u32)NCH ? h10 : 0u];
            u64 K11 = sKeepArr[h11 < (u32)NCH ? h11 : 0u];
            u64 K20 = sKeepArr[h20 < (u32)NCH ? h20 : 0u];
            u64 K21 = sKeepArr[h21 < (u32)NCH ? h21 : 0u];
            u64 K30 = sKeepArr[h30 < (u32)NCH ? h30 : 0u];
            u64 K31 = sKeepArr[h31 < (u32)NCH ? h31 : 0u];
            // ---- word 0 (all sources external) ----
            u64 m = 0;
            if ((u32)lane < c0 && ((K00 >> (s00 & 63u)) & 1ull)) m = E00.y;
            if ((u32)(lane + 64) < c0 && ((K01 >> (s01 & 63u)) & 1ull)) m |= E01.y;
            if (c0 > 128u) {
                for (u32 e = 128u + (u32)lane; e < c0; e += 64u) {
                    ulonglong2 Et = tpack[(size_t)t0 * CAP + e];
                    u32 si = (u32)Et.x;
                    if ((sKeepArr[si >> 6] >> (si & 63u)) & 1ull) m |= Et.y;
                }
            }
            u32 lo = wor32((u32)m), hi = wor32((u32)(m >> 32));
            u64 inc = ((u64)rdl32(hi, 63) << 32) | (u64)rdl32(lo, 63);
            u64 alive0 = vw0 & ~inc;
            if (dmw0) {
                u64 d = dmw0 & alive0;
                while (d) {
                    int j = __builtin_ctzll(d);
                    d &= d - 1;
                    if ((alive0 >> j) & 1ull) { alive0 &= ~rdlane64(D0, j); d &= alive0; }
                }
            }
            // ---- word 1 (sources may include word 0 of this super-chunk) ----
            u64 kwA = (h10 == (u32)t0) ? alive0 : K10;
            u64 kwB = (h11 == (u32)t0) ? alive0 : K11;
            m = 0;
            if ((u32)lane < c1 && ((kwA >> (s10 & 63u)) & 1ull)) m = E10.y;
            if ((u32)(lane + 64) < c1 && ((kwB >> (s11 & 63u)) & 1ull)) m |= E11.y;
            if (c1 > 128u) {
                for (u32 e = 128u + (u32)lane; e < c1; e += 64u) {
                    ulonglong2 Et = tpack[(size_t)q1 * CAP + e];
                    u32 si = (u32)Et.x; u32 hh = si >> 6;
                    u64 kw = (hh == (u32)t0) ? alive0 : sKeepArr[hh];
                    if ((kw >> (si & 63u)) & 1ull) m |= Et.y;
                }
            }
            lo = wor32((u32)m); hi = wor32((u32)(m >> 32));
            inc = ((u64)rdl32(hi, 63) << 32) | (u64)rdl32(lo, 63);
            u64 alive1 = vw1 & ~inc;
            if (dmw1) {
                u64 d = dmw1 & alive1;
                while (d) {
                    int j = __builtin_ctzll(d);
                    d &= d - 1;
                    if ((alive1 >> j) & 1ull) { alive1 &= ~rdlane64(D1, j); d &= alive1; }
                }
            }
            // ---- word 2 ----
            kwA = (h20 == (u32)t0) ? alive0 : (h20 == (u32)t1) ? alive1 : K20;
            kwB = (h21 == (u32)t0) ? alive0 : (h21 == (u32)t1) ? alive1 : K21;
            m = 0;
            if ((u32)lane < c2 && ((kwA >> (s20 & 63u)) & 1ull)) m = E20.y;
            if ((u32)(lane + 64) < c2 && ((kwB >> (s21 & 63u)) & 1ull)) m |= E21.y;
            if (c2 > 128u) {
                for (u32 e = 128u + (u32)lane; e < c2; e += 64u) {
                    ulonglong2 Et = tpack[(size_t)q2 * CAP + e];
                    u32 si = (u32)Et.x; u32 hh = si >> 6;
                    u64 kw = (hh == (u32)t0) ? alive0 : (hh == (u32)t1) ? alive1 : sKeepArr[hh];
                    if ((kw >> (si & 63u)) & 1ull) m |= Et.y;
                }
            }
            lo = wor32((u32)m); hi = wor32((u32)(m >> 32));
            inc = ((u64)rdl32(hi, 63) << 32) | (u64)rdl32(lo, 63);
            u64 alive2 = vw2 & ~inc;
            if (dmw2) {
                u64 d = dmw2 & alive2;
                while (d) {
                    int j = __builtin_ctzll(d);
                    d &= d - 1;
                    if ((alive2 >> j) & 1ull) { alive2 &= ~rdlane64(D2, j); d &= alive2; }
                }
            }
            // ---- word 3 ----
            kwA = (h30 == (u32)t0) ? alive0 : (h30 == (u32)t1) ? alive1 : (h30 == (u32)t2) ? alive2 : K30;
            kwB = (h31 == (u32)t0) ? alive0 : (h31 == (u32)t1) ? alive1 : (h31 == (u32)t2) ? alive2 : K31;
            m = 0;
            if ((u32)lane < c3 && ((kwA >> (s30 & 63u)) & 1ull)) m = E30.y;
            if ((u32)(lane + 64) < c3 && ((kwB >> (s31 & 63u)) & 1ull)) m |= E31.y;
            if (c3 > 128u) {
                for (u32 e = 128u + (u32)lane; e < c3; e += 64u) {
                    ulonglong2 Et = tpack[(size_t)q3 * CAP + e];
                    u32 si = (u32)Et.x; u32 hh = si >> 6;
                    u64 kw = (hh == (u32)t0) ? alive0 : (hh == (u32)t1) ? alive1
                           : (hh == (u32)t2) ? alive2 : sKeepArr[hh];
                    if ((kw >> (si & 63u)) & 1ull) m |= Et.y;
                }
            }
            lo = wor32((u32)m); hi = wor32((u32)(m >> 32));
            inc = ((u64)rdl32(hi, 63) << 32) | (u64)rdl32(lo, 63);
            u64 alive3 = vw3 & ~inc;
            if (dmw3) {
                u64 d = dmw3 & alive3;
                while (d) {
                    int j = __builtin_ctzll(d);
                    d &= d - 1;
                    if ((alive3 >> j) & 1ull) { alive3 &= ~rdlane64(D3, j); d &= alive3; }
                }
            }
            // ---- publish 4 words + release ----
            if (lane == 0) {
                sKeepArr[t0] = alive0;
                sKeepArr[t1] = alive1;
                sKeepArr[t2] = alive2;
                sKeepArr[t3] = alive3;
                __hip_atomic_store(&sProg, (u32)(C + 1), __ATOMIC_RELEASE, __HIP_MEMORY_SCOPE_WORKGROUP);
            }
        }
    }
    __syncthreads();
    // ---- fused output phase (all 512 threads) ----
    if (t < NCH) pc[t + 1] = (u32)__popcll(sKeepArr[t]);
    if (t == 0) pc[0] = 0;
    __syncthreads();
    for (int ofs = 1; ofs < NCH; ofs <<= 1) {   // Hillis-Steele inclusive scan over pc[1..NCH]
        int i = t + 1;
        u32 v = 0;
        bool p = (t < NCH) && (i - ofs >= 1);
        if (p) v = pc[i - ofs];
        __syncthreads();
        if (p) pc[i] += v;
        __syncthreads();
    }
    u32 nk = pc[NCH];
    for (int i = t; i < K_TOT; i += 512) {
        int wi = i >> 6, b = i & 63;
        u64 kw = sKeepArr[wi];
        u32 kb = pc[wi] + (u32)__popcll(kw & ((1ull << b) - 1ull));
        bool kp = (kw >> b) & 1ull;
        if (kp) {
            if (kb < 1000u) {
                float4 bx = sB[i];
                out[kb * 4 + 0] = bx.x; out[kb * 4 + 1] = bx.y;
                out[kb * 4 + 2] = bx.z; out[kb * 4 + 3] = bx.w;
                out[4000 + kb] = sS[i];
            }
        } else {
            u32 q = (u32)i - kb;
            u32 slot = nk + q;
            if (slot < 1000u) {
                float4 bx = sB[i];
                out[slot * 4 + 0] = bx.x; out[slot * 4 + 1] = bx.y;
                out[slot * 4 + 2] = bx.z; out[slot * 4 + 3] = bx.w;
                out[4000 + slot] = -INFINITY;
            }
        }
    }
}

// ---------------- workspace layout ----------------
static constexpr size_t al256(size_t x) { return (x + 255) & ~(size_t)255; }
static constexpr size_t KB4 = (size_t)K_TOT * 4;
static constexpr size_t KB16 = (size_t)K_TOT * 16;
// zeroed region:
static constexpr size_t O_RANK = 0;
static constexpr size_t O_PRAW = al256(O_RANK + KB4);
static constexpr size_t O_ECNT = al256(O_PRAW + KB4);
static constexpr size_t O_HIST = al256(O_ECNT + (size_t)NCH * 4);
static constexpr size_t O_CGT = al256(O_HIST + (size_t)3 * 2048 * 4);
static constexpr size_t O_GCNT = al256(O_CGT + 3 * 4);
static constexpr size_t MEMSET_BYTES = al256(O_GCNT + 3 * 4);
// non-zeroed region:
static constexpr size_t O_TINFO = MEMSET_BYTES;
static constexpr size_t O_SEL = al256(O_TINFO + 6 * 4);
static constexpr size_t O_GIDX = al256(O_SEL + KB4);
static constexpr size_t O_GKEY = al256(O_GIDX + (size_t)3 * GCAP * 4);
static constexpr size_t O_CANDB = al256(O_GKEY + (size_t)3 * GCAP * 4);
static constexpr size_t O_CANDS = al256(O_CANDB + KB16);
static constexpr size_t O_CANDV = al256(O_CANDS + KB4);
static constexpr size_t O_CANDA = al256(O_CANDV + KB4);
static constexpr size_t O_SB = al256(O_CANDA + KB4);
static constexpr size_t O_SAREA = al256(O_SB + KB16);
static constexpr size_t O_SS = al256(O_SAREA + KB4);
static constexpr size_t O_SV = al256(O_SS + KB4);
static constexpr size_t O_VW = al256(O_SV + KB4);
static constexpr size_t O_DMASK = al256(O_VW + (size_t)NCH * 8);
static constexpr size_t O_DIAG = al256(O_DMASK + (size_t)NCH * 8);
static constexpr size_t O_EPACK = al256(O_DIAG + (size_t)(NCH * 64) * 8);

extern "C" void kernel_launch(void* const* d_in, const int* in_sizes, int n_in,
                              void* d_out, int out_size, void* d_ws, size_t ws_size,
                              hipStream_t stream) {
    const float* scores = (const float*)d_in[0];
    const float4* deltas = (const float4*)d_in[1];
    const float4* anchors = (const float4*)d_in[2];
    float* out = (float*)d_out;
    char* ws = (char*)d_ws;

    u32* rank = (u32*)(ws + O_RANK);
    u32* Praw = (u32*)(ws + O_PRAW);
    u32* ecnt = (u32*)(ws + O_ECNT);
    u32* hist3 = (u32*)(ws + O_HIST);
    u32* cgt = (u32*)(ws + O_CGT);
    u32* gcnt = (u32*)(ws + O_GCNT);
    u32* tinfo = (u32*)(ws + O_TINFO);
    u32* sel = (u32*)(ws + O_SEL);
    u32* gidx = (u32*)(ws + O_GIDX);
    u32* gkey = (u32*)(ws + O_GKEY);
    float4* candB = (float4*)(ws + O_CANDB);
    float* candS = (float*)(ws + O_CANDS);
    u32* candV = (u32*)(ws + O_CANDV);
    u32* candA = (u32*)(ws + O_CANDA);
    float4* sB = (float4*)(ws + O_SB);
    float* sArea = (float*)(ws + O_SAREA);
    float* sS = (float*)(ws + O_SS);
    u32* sV = (u32*)(ws + O_SV);
    u64* vwords = (u64*)(ws + O_VW);
    u64* dmask = (u64*)(ws + O_DMASK);
    u64* diag = (u64*)(ws + O_DIAG);
    ulonglong2* epack = (ulonglong2*)(ws + O_EPACK);

    hipMemsetAsync(ws, 0, MEMSET_BYTES, stream);

    const int NBLK = (K_TOT + 255) / 256;  // 33
    k_hist<<<156, 1024, 0, stream>>>(scores, hist3);
    k_thresh<<<3, 1024, 0, stream>>>(hist3, tinfo);
    k_gather<<<159, 1024, 0, stream>>>(scores, tinfo, sel, cgt, gcnt, gidx, gkey);
    k_final<<<3, 1024, 0, stream>>>(gidx, gkey, gcnt, tinfo, sel);
    k_decode<<<NBLK, 256, 0, stream>>>(scores, deltas, anchors, sel, candB, candS, candV, candA);
    k_rank_lvl<<<dim3(8, 8, 5), 256, 0, stream>>>(candS, candA, Praw);
    k_rank_glob<<<dim3(NBLK, NBLK), 256, 0, stream>>>(candS, candV, Praw, rank);
    k_scatter<<<NBLK, 256, 0, stream>>>(candB, candS, candV, rank, sB, sArea, sS, sV);
    k_mask<<<dim3(NCH, NBLK), 256, 0, stream>>>(sB, sArea, sV, vwords, diag, ecnt, epack, dmask);
    k_scan<<<1, 512, 0, stream>>>(diag, vwords, ecnt, epack, dmask, sB, sS, out);
}